// Round 5
// baseline (1174.584 us; speedup 1.0000x reference)
//
#include <hip/hip_runtime.h>
#include <hip/hip_bf16.h>
#include <math.h>

#define NNODES 50000
#define NEDGES 800000
#define INF    128
#define HIDD   32
#define HEADS  8
#define C1     256   // HEADS*HIDD
#define NCLS   40

typedef unsigned int  uint;
typedef unsigned short ushort;

__device__ __forceinline__ float bf2f(ushort v) {
  return __uint_as_float(((uint)v) << 16);
}
__device__ __forceinline__ ushort f2bf(float f) {
  __hip_bfloat16 b = __float2bfloat16(f);
  return *reinterpret_cast<ushort*>(&b);
}
// dtype-flagged scalar load: isf=1 -> f32 storage, else bf16 storage
__device__ __forceinline__ float ldv(const void* p, long i, int isf) {
  return isf ? ((const float*)p)[i] : bf2f(((const ushort*)p)[i]);
}

// ---------------- dtype detection: f32-as-bf16 has wild exponents ----------
__global__ void k_detect(const ushort* __restrict__ xr, int* __restrict__ flag) {
  __shared__ int cnt;
  const int t = threadIdx.x;
  if (t == 0) cnt = 0;
  __syncthreads();
  int c = 0;
  for (int i = t; i < 4096; i += 256) {
    const uint e = (xr[i] >> 7) & 0xFFu;  // bf16 exponent field
    if (e > 200u) c++;                    // impossible for real N(0,1) data
  }
  atomicAdd(&cnt, c);
  __syncthreads();
  if (t == 0) flag[0] = (cnt > 100) ? 1 : 0;  // 1 => inputs stored as float32
}

// ---------------- CSR build ----------------
__global__ void k_hist(const int* __restrict__ dst, int* __restrict__ deg) {
  int e = blockIdx.x * 256 + threadIdx.x;
  if (e < NEDGES) {
    int d = dst[e];
    if ((uint)d < (uint)NNODES) atomicAdd(&deg[d], 1);
  }
}

// single-block sequential-chunk scan: trivially correct
__global__ __launch_bounds__(1024) void k_scan(const int* __restrict__ deg,
                                               int* __restrict__ rowptr,
                                               int* __restrict__ woff) {
  __shared__ int s[1024];
  __shared__ int carry;
  const int t = threadIdx.x;
  if (t == 0) carry = 0;
  __syncthreads();
  for (int base = 0; base < NNODES; base += 1024) {
    const int i = base + t;
    const int v = (i < NNODES) ? deg[i] : 0;
    s[t] = v;
    __syncthreads();
    for (int off = 1; off < 1024; off <<= 1) {
      int u = (t >= off) ? s[t - off] : 0;
      __syncthreads();
      s[t] += u;
      __syncthreads();
    }
    if (i < NNODES) {
      const int r = carry + s[t] - v;  // exclusive prefix
      rowptr[i] = r;
      woff[i]   = r;
    }
    __syncthreads();
    if (t == 1023) carry += s[1023];
    __syncthreads();
  }
}

__global__ void k_scatter(const int* __restrict__ src, const int* __restrict__ dst,
                          int* __restrict__ woff, int* __restrict__ colsrc) {
  int e = blockIdx.x * 256 + threadIdx.x;
  if (e < NEDGES) {
    int d = dst[e];
    if ((uint)d < (uint)NNODES) {
      int pos = atomicAdd(&woff[d], 1);
      if ((uint)pos < (uint)NEDGES) colsrc[pos] = src[e];
    }
  }
}

// -------- naive GEMM1: h1[N,256](f32) = x[N,128] @ W1[128,256] -------------
__global__ __launch_bounds__(256) void k_gemm1n(const void* __restrict__ X,
                                                const void* __restrict__ W,
                                                const int* __restrict__ flag,
                                                float* __restrict__ H) {
  const int n = blockIdx.x;      // one block per node row
  const int c = threadIdx.x;     // one thread per output column
  const int isf = flag[0];
  float acc = 0.f;
  for (int k = 0; k < INF; ++k)
    acc += ldv(X, (long)n * INF + k, isf) * ldv(W, (long)k * C1 + c, isf);
  H[(size_t)n * C1 + c] = acc;
}

// -------- naive el/er layer 1: thread per (node, head) ---------------------
__global__ __launch_bounds__(256) void k_elr1n(const float* __restrict__ h1,
                                               const void* __restrict__ al,
                                               const void* __restrict__ ar,
                                               const int* __restrict__ flag,
                                               float* __restrict__ el,
                                               float* __restrict__ er) {
  const int g = blockIdx.x * 256 + threadIdx.x;
  if (g >= NNODES * HEADS) return;
  const int n = g >> 3, h = g & 7;
  const int isf = flag[0];
  float sl = 0.f, sr = 0.f;
  for (int d = 0; d < HIDD; ++d) {
    const float v = h1[(size_t)n * C1 + h * HIDD + d];
    sl += v * ldv(al, h * HIDD + d, isf);
    sr += v * ldv(ar, h * HIDD + d, isf);
  }
  el[g] = sl;
  er[g] = sr;
}

// -------- Agg layer 1 (block per node; fused softmax+gather+bias+ELU) ------
__global__ __launch_bounds__(256) void k_agg1(const int* __restrict__ rowptr,
                                              const int* __restrict__ deg,
                                              const int* __restrict__ colsrc,
                                              const float* __restrict__ h1,
                                              const float* __restrict__ el,
                                              const float* __restrict__ er,
                                              const void* __restrict__ b1r,
                                              const int* __restrict__ flag,
                                              ushort* __restrict__ out1b) {
  const int n = blockIdx.x;
  const int t = threadIdx.x;          // t = h*32 + d
  const int h = t >> 5;
  const int isf = flag[0];
  const float bv = ldv(b1r, t, isf);
  const int start = rowptr[n];
  int cnt = deg[n];
  if (cnt < 0) cnt = 0;
  if (cnt > NEDGES) cnt = NEDGES;
  const float ern = er[n * HEADS + h];
  float acc = 0.f, den = 0.f;
  for (int i = 0; i < cnt; ++i) {
    const int s = colsrc[start + i];
    if ((uint)s >= (uint)NNODES) continue;
    float sc = el[s * HEADS + h] + ern;
    sc = (sc >= 0.f) ? sc : 0.2f * sc;
    const float ex = __expf(sc);
    den += ex;
    acc += ex * h1[(size_t)s * C1 + t];
  }
  float o = acc / fmaxf(den, 1e-9f) + bv;
  o = (o > 0.f) ? o : expm1f(o);      // ELU
  out1b[(size_t)n * C1 + t] = f2bf(o);
}

// -------- naive GEMM2: h2[N,40](f32) = out1[N,256](bf16) @ W2[256,40] ------
__global__ __launch_bounds__(64) void k_gemm2n(const ushort* __restrict__ A,
                                               const void* __restrict__ W,
                                               const int* __restrict__ flag,
                                               float* __restrict__ H) {
  const int n = blockIdx.x;
  const int c = threadIdx.x;
  const int isf = flag[0];
  if (c >= NCLS) return;
  float acc = 0.f;
  for (int k = 0; k < C1; ++k)
    acc += bf2f(A[(size_t)n * C1 + k]) * ldv(W, (long)k * NCLS + c, isf);
  H[(size_t)n * NCLS + c] = acc;
}

// -------- naive el/er layer 2: thread per node -----------------------------
__global__ __launch_bounds__(256) void k_elr2n(const float* __restrict__ h2,
                                               const void* __restrict__ al,
                                               const void* __restrict__ ar,
                                               const int* __restrict__ flag,
                                               float* __restrict__ el,
                                               float* __restrict__ er) {
  const int n = blockIdx.x * 256 + threadIdx.x;
  if (n >= NNODES) return;
  const int isf = flag[0];
  float sl = 0.f, sr = 0.f;
  for (int d = 0; d < NCLS; ++d) {
    const float v = h2[(size_t)n * NCLS + d];
    sl += v * ldv(al, d, isf);
    sr += v * ldv(ar, d, isf);
  }
  el[n] = sl;
  er[n] = sr;
}

// -------- Agg layer 2 (wave per node) -> FLOAT32 output --------------------
__global__ __launch_bounds__(256) void k_agg2(const int* __restrict__ rowptr,
                                              const int* __restrict__ deg,
                                              const int* __restrict__ colsrc,
                                              const float* __restrict__ h2,
                                              const float* __restrict__ el,
                                              const float* __restrict__ er,
                                              const void* __restrict__ b2r,
                                              const int* __restrict__ flag,
                                              float* __restrict__ out) {
  const int t    = threadIdx.x;
  const int lane = t & 63;
  const int n    = blockIdx.x * 4 + (t >> 6);
  if (n >= NNODES) return;
  const int isf  = flag[0];
  const int start = rowptr[n];
  int cnt = deg[n];
  if (cnt < 0) cnt = 0;
  if (cnt > NEDGES) cnt = NEDGES;
  const float ern = er[n];
  float acc = 0.f, den = 0.f;
  for (int i = 0; i < cnt; ++i) {
    const int s = colsrc[start + i];
    if ((uint)s >= (uint)NNODES) continue;
    float sc = el[s] + ern;
    sc = (sc >= 0.f) ? sc : 0.2f * sc;
    const float ex = __expf(sc);
    den += ex;
    if (lane < NCLS) acc += ex * h2[(size_t)s * NCLS + lane];
  }
  if (lane < NCLS) {
    const float o = acc / fmaxf(den, 1e-9f) + ldv(b2r, lane, isf);
    out[(size_t)n * NCLS + lane] = o;   // FLOAT32 output (reference dtype)
  }
}

extern "C" void kernel_launch(void* const* d_in, const int* in_sizes, int n_in,
                              void* d_out, int out_size, void* d_ws, size_t ws_size,
                              hipStream_t stream) {
  // ---- size-driven input mapping: supports dict order AND name-sorted ----
  int ix = -1, iW1 = -1, iW2 = -1, e1 = -1, e2 = -1;
  int i256[3] = {-1, -1, -1}, n256 = 0;
  int i40[3]  = {-1, -1, -1}, n40 = 0;
  for (int i = 0; i < n_in; ++i) {
    switch (in_sizes[i]) {
      case 6400000: ix = i; break;
      case 800000:  if (e1 < 0) e1 = i; else e2 = i; break;
      case 32768:   iW1 = i; break;
      case 10240:   iW2 = i; break;
      case 256:     if (n256 < 3) i256[n256++] = i; break;
      case 40:      if (n40 < 3)  i40[n40++]  = i; break;
      default: break;
    }
  }
  bool mapped = (ix >= 0 && iW1 >= 0 && iW2 >= 0 && e2 >= 0 && n256 == 3 && n40 == 3);
  int isrc, idst;
  if (mapped) {
    // dict order: x first => src before dst. name-sorted: W1 first => dst before src.
    const bool dict_order = (in_sizes[0] == 6400000);
    isrc = dict_order ? e1 : e2;
    idst = dict_order ? e2 : e1;
  } else {  // fallback: documented dict order
    ix = 0; isrc = 1; idst = 2; iW1 = 3;
    i256[0] = 4; i256[1] = 5; i256[2] = 6;
    iW2 = 7; i40[0] = 8; i40[1] = 9; i40[2] = 10;
  }
  const void* X   = d_in[ix];
  const int*  src = (const int*)d_in[isrc];
  const int*  dst = (const int*)d_in[idst];
  const void* W1  = d_in[iW1];
  const void* al1 = d_in[i256[0]];
  const void* ar1 = d_in[i256[1]];
  const void* b1  = d_in[i256[2]];
  const void* W2  = d_in[iW2];
  const void* al2 = d_in[i40[0]];
  const void* ar2 = d_in[i40[1]];
  const void* b2  = d_in[i40[2]];

  char* ws = (char*)d_ws;
  size_t off = 0;
  auto alloc = [&](size_t bytes) -> void* {
    void* p = ws + off;
    off = (off + bytes + 255) & ~(size_t)255;
    return p;
  };
  int*    flag   = (int*)alloc(256);
  int*    deg    = (int*)alloc((size_t)NNODES * 4);
  int*    rowptr = (int*)alloc((size_t)NNODES * 4);
  int*    woff   = (int*)alloc((size_t)NNODES * 4);
  int*    colsrc = (int*)alloc((size_t)NEDGES * 4);
  float*  el1    = (float*)alloc((size_t)NNODES * HEADS * 4);
  float*  er1    = (float*)alloc((size_t)NNODES * HEADS * 4);
  float*  el2    = (float*)alloc((size_t)NNODES * 4);
  float*  er2    = (float*)alloc((size_t)NNODES * 4);
  float*  h1     = (float*)alloc((size_t)NNODES * C1 * 4);   // 51.2 MB
  ushort* out1b  = (ushort*)alloc((size_t)NNODES * C1 * 2);  // 25.6 MB
  float*  h2     = (float*)h1;  // h1 dead after k_agg1; reuse (8 MB)

  k_detect<<<1, 256, 0, stream>>>((const ushort*)X, flag);

  hipMemsetAsync(deg, 0, (size_t)NNODES * 4, stream);
  k_hist<<<(NEDGES + 255) / 256, 256, 0, stream>>>(dst, deg);
  k_scan<<<1, 1024, 0, stream>>>(deg, rowptr, woff);
  k_scatter<<<(NEDGES + 255) / 256, 256, 0, stream>>>(src, dst, woff, colsrc);

  k_gemm1n<<<NNODES, 256, 0, stream>>>(X, W1, flag, h1);
  k_elr1n<<<(NNODES * HEADS + 255) / 256, 256, 0, stream>>>(h1, al1, ar1, flag, el1, er1);
  k_agg1<<<NNODES, 256, 0, stream>>>(rowptr, deg, colsrc, h1, el1, er1, b1, flag, out1b);

  k_gemm2n<<<NNODES, 64, 0, stream>>>(out1b, W2, flag, h2);
  k_elr2n<<<(NNODES + 255) / 256, 256, 0, stream>>>(h2, al2, ar2, flag, el2, er2);
  k_agg2<<<(NNODES + 3) / 4, 256, 0, stream>>>(rowptr, deg, colsrc, h2, el2, er2, b2,
                                               flag, (float*)d_out);
}

// Round 6
// 598.519 us; speedup vs baseline: 1.9625x; 1.9625x over previous
//
#include <hip/hip_runtime.h>
#include <hip/hip_bf16.h>
#include <math.h>

#define NNODES 50000
#define NEDGES 800000
#define INF    128
#define HIDD   32
#define HEADS  8
#define C1     256   // HEADS*HIDD
#define NCLS   40

typedef unsigned int  uint;
typedef unsigned short ushort;

__device__ __forceinline__ float bf2f(ushort v) {
  return __uint_as_float(((uint)v) << 16);
}
__device__ __forceinline__ ushort f2bf(float f) {
  __hip_bfloat16 b = __float2bfloat16(f);
  return *reinterpret_cast<ushort*>(&b);
}
__device__ __forceinline__ float ldv(const void* p, long i, int isf) {
  return isf ? ((const float*)p)[i] : bf2f(((const ushort*)p)[i]);
}
// 8 bf16 (as uint4) -> 8 f32
__device__ __forceinline__ void bfx8(const uint4 u, float4& a, float4& b) {
  a.x = __uint_as_float(u.x << 16);
  a.y = __uint_as_float(u.x & 0xffff0000u);
  a.z = __uint_as_float(u.y << 16);
  a.w = __uint_as_float(u.y & 0xffff0000u);
  b.x = __uint_as_float(u.z << 16);
  b.y = __uint_as_float(u.z & 0xffff0000u);
  b.z = __uint_as_float(u.w << 16);
  b.w = __uint_as_float(u.w & 0xffff0000u);
}
// 4 bf16 (as uint2) -> 4 f32
__device__ __forceinline__ float4 bfx4(const uint2 u) {
  float4 v;
  v.x = __uint_as_float(u.x << 16);
  v.y = __uint_as_float(u.x & 0xffff0000u);
  v.z = __uint_as_float(u.y << 16);
  v.w = __uint_as_float(u.y & 0xffff0000u);
  return v;
}
__device__ __forceinline__ uint packbf2(float f0, float f1) {
  return (uint)f2bf(f0) | ((uint)f2bf(f1) << 16);
}

// ---------------- dtype detection: f32-as-bf16 has wild exponents ----------
__global__ void k_detect(const ushort* __restrict__ xr, int* __restrict__ flag) {
  __shared__ int cnt;
  const int t = threadIdx.x;
  if (t == 0) cnt = 0;
  __syncthreads();
  int c = 0;
  for (int i = t; i < 4096; i += 256) {
    const uint e = (xr[i] >> 7) & 0xFFu;
    if (e > 200u) c++;
  }
  atomicAdd(&cnt, c);
  __syncthreads();
  if (t == 0) flag[0] = (cnt > 100) ? 1 : 0;  // 1 => inputs stored as float32
}

// ---------------- CSR build ----------------
__global__ void k_hist(const int* __restrict__ dst, int* __restrict__ deg) {
  int e = blockIdx.x * 256 + threadIdx.x;
  if (e < NEDGES) {
    int d = dst[e];
    if ((uint)d < (uint)NNODES) atomicAdd(&deg[d], 1);
  }
}

__global__ __launch_bounds__(1024) void k_scan1(const int* __restrict__ deg,
                                                int* __restrict__ rowptr,
                                                int* __restrict__ bsum) {
  __shared__ int s[1024];
  int t = threadIdx.x;
  int i = blockIdx.x * 1024 + t;
  int v = (i < NNODES) ? deg[i] : 0;
  s[t] = v;
  __syncthreads();
  for (int off = 1; off < 1024; off <<= 1) {
    int u = (t >= off) ? s[t - off] : 0;
    __syncthreads();
    s[t] += u;
    __syncthreads();
  }
  if (i < NNODES) rowptr[i] = s[t] - v;   // exclusive
  if (t == 1023) bsum[blockIdx.x] = s[t]; // block total
}

__global__ void k_scan2(int* __restrict__ bsum, int* __restrict__ boff, int nb) {
  if (blockIdx.x == 0 && threadIdx.x == 0) {
    int run = 0;
    for (int b = 0; b < nb; ++b) { boff[b] = run; run += bsum[b]; }
  }
}

__global__ __launch_bounds__(1024) void k_scan3(int* __restrict__ rowptr,
                                                int* __restrict__ woff,
                                                const int* __restrict__ boff) {
  int i = blockIdx.x * 1024 + threadIdx.x;
  if (i < NNODES) {
    int r = rowptr[i] + boff[blockIdx.x];
    rowptr[i] = r;
    woff[i] = r;
  }
}

__global__ void k_scatter(const int* __restrict__ src, const int* __restrict__ dst,
                          int* __restrict__ woff, int* __restrict__ colsrc) {
  int e = blockIdx.x * 256 + threadIdx.x;
  if (e < NEDGES) {
    int d = dst[e];
    if ((uint)d < (uint)NNODES) {
      int pos = atomicAdd(&woff[d], 1);
      if ((uint)pos < (uint)NEDGES) colsrc[pos] = src[e];
    }
  }
}

// -------- tiled GEMM1: h1[N,256](bf16) = x[N,128] @ W1[128,256] ------------
__global__ __launch_bounds__(256) void k_gemm1(const void* __restrict__ Xr,
                                               const void* __restrict__ Wr,
                                               const int* __restrict__ flag,
                                               ushort* __restrict__ Hb) {
  __shared__ __align__(16) float As[32 * 132];  // [row][k], pitch 132
  __shared__ __align__(16) float Bs[32 * 260];  // [k][col], pitch 260
  const int tid = threadIdx.x;
  const int rt  = blockIdx.x * 32;
  const int isf = flag[0];

  { // stage A tile (32 rows x full K=128) -> f32
    const int r  = tid >> 4;          // 0..15
    const int c0 = (tid & 15) << 3;   // 0..120
#pragma unroll
    for (int p = 0; p < 2; ++p) {
      const int row  = r + (p << 4);
      const int grow = rt + row;
      float4 a = make_float4(0.f, 0.f, 0.f, 0.f);
      float4 b = make_float4(0.f, 0.f, 0.f, 0.f);
      if (grow < NNODES) {
        if (isf) {
          const float* Xf = (const float*)Xr;
          a = *reinterpret_cast<const float4*>(Xf + (size_t)grow * INF + c0);
          b = *reinterpret_cast<const float4*>(Xf + (size_t)grow * INF + c0 + 4);
        } else {
          const ushort* Xb = (const ushort*)Xr;
          uint4 u = *reinterpret_cast<const uint4*>(Xb + (size_t)grow * INF + c0);
          bfx8(u, a, b);
        }
      }
      *reinterpret_cast<float4*>(&As[row * 132 + c0])     = a;
      *reinterpret_cast<float4*>(&As[row * 132 + c0 + 4]) = b;
    }
  }

  const int cg = tid & 31;   // cols {4cg..4cg+3} and {128+4cg..128+4cg+3}
  const int rg = tid >> 5;   // rows rg*4..rg*4+3
  float acc[4][8];
#pragma unroll
  for (int i = 0; i < 4; ++i)
#pragma unroll
    for (int j = 0; j < 8; ++j) acc[i][j] = 0.f;

  for (int ch = 0; ch < 4; ++ch) {
    const int k0 = ch << 5;
    __syncthreads();
    { // stage B chunk (32 k-rows x 256 cols)
      const int kr = tid >> 5;          // 0..7
      const int c0 = (tid & 31) << 3;   // 0..248
#pragma unroll
      for (int p = 0; p < 4; ++p) {
        const int row = kr + (p << 3);
        float4 a, b;
        if (isf) {
          const float* Wf = (const float*)Wr;
          a = *reinterpret_cast<const float4*>(Wf + (size_t)(k0 + row) * C1 + c0);
          b = *reinterpret_cast<const float4*>(Wf + (size_t)(k0 + row) * C1 + c0 + 4);
        } else {
          const ushort* Wb = (const ushort*)Wr;
          uint4 u = *reinterpret_cast<const uint4*>(Wb + (size_t)(k0 + row) * C1 + c0);
          bfx8(u, a, b);
        }
        *reinterpret_cast<float4*>(&Bs[row * 260 + c0])     = a;
        *reinterpret_cast<float4*>(&Bs[row * 260 + c0 + 4]) = b;
      }
    }
    __syncthreads();
#pragma unroll 4
    for (int kk = 0; kk < 32; ++kk) {
      const int k = k0 + kk;
      float a[4];
#pragma unroll
      for (int i = 0; i < 4; ++i) a[i] = As[(rg * 4 + i) * 132 + k];
      float b[8];
      float4 b0 = *reinterpret_cast<const float4*>(&Bs[kk * 260 + (cg << 2)]);
      float4 b1 = *reinterpret_cast<const float4*>(&Bs[kk * 260 + 128 + (cg << 2)]);
      b[0] = b0.x; b[1] = b0.y; b[2] = b0.z; b[3] = b0.w;
      b[4] = b1.x; b[5] = b1.y; b[6] = b1.z; b[7] = b1.w;
#pragma unroll
      for (int i = 0; i < 4; ++i)
#pragma unroll
        for (int j = 0; j < 8; ++j) acc[i][j] += a[i] * b[j];
    }
  }

#pragma unroll
  for (int i = 0; i < 4; ++i) {
    const int row = rt + rg * 4 + i;
    if (row < NNODES) {
      uint2 v0, v1;
      v0.x = packbf2(acc[i][0], acc[i][1]);
      v0.y = packbf2(acc[i][2], acc[i][3]);
      v1.x = packbf2(acc[i][4], acc[i][5]);
      v1.y = packbf2(acc[i][6], acc[i][7]);
      *reinterpret_cast<uint2*>(&Hb[(size_t)row * C1 + (cg << 2)])       = v0;
      *reinterpret_cast<uint2*>(&Hb[(size_t)row * C1 + 128 + (cg << 2)]) = v1;
    }
  }
}

// ---------------- el/er layer 1 (h1 bf16, shuffle reduce) ------------------
__global__ __launch_bounds__(256) void k_elr1(const ushort* __restrict__ h1b,
                                              const void* __restrict__ alr,
                                              const void* __restrict__ arr,
                                              const int* __restrict__ flag,
                                              float* __restrict__ el,
                                              float* __restrict__ er) {
  const int n = blockIdx.x;
  const int t = threadIdx.x;          // t = h*32 + d
  const int isf = flag[0];
  const float av = ldv(alr, t, isf);
  const float rv = ldv(arr, t, isf);
  float v  = bf2f(h1b[(size_t)n * C1 + t]);
  float pl = v * av;
  float pr = v * rv;
#pragma unroll
  for (int k = 16; k >= 1; k >>= 1) {
    pl += __shfl_xor(pl, k, 64);
    pr += __shfl_xor(pr, k, 64);
  }
  if ((t & 31) == 0) {
    const int h = t >> 5;
    el[n * HEADS + h] = pl;
    er[n * HEADS + h] = pr;
  }
}

// -------- Agg layer 1: 128 threads/node, 2 cols/thread (uint bf16x2) -------
__global__ __launch_bounds__(256) void k_agg1(const int* __restrict__ rowptr,
                                              const int* __restrict__ deg,
                                              const int* __restrict__ colsrc,
                                              const ushort* __restrict__ h1b,
                                              const float* __restrict__ el,
                                              const float* __restrict__ er,
                                              const void* __restrict__ b1r,
                                              const int* __restrict__ flag,
                                              ushort* __restrict__ out1b) {
  const int n   = blockIdx.x * 2 + (threadIdx.x >> 7);
  if (n >= NNODES) return;
  const int t   = threadIdx.x & 127;  // 0..127
  const int c0  = t << 1;             // even col
  const int h   = t >> 4;             // c0>>5
  const int isf = flag[0];
  const float bv0 = ldv(b1r, c0, isf);
  const float bv1 = ldv(b1r, c0 + 1, isf);
  const int start = rowptr[n];
  int cnt = deg[n];
  if (cnt < 0) cnt = 0;
  if (cnt > NEDGES) cnt = NEDGES;
  const float ern = er[n * HEADS + h];
  float a0 = 0.f, a1 = 0.f, den = 0.f;
  for (int i = 0; i < cnt; ++i) {
    const int s = colsrc[start + i];
    if ((uint)s >= (uint)NNODES) continue;
    float sc = el[s * HEADS + h] + ern;
    sc = (sc >= 0.f) ? sc : 0.2f * sc;
    const float ex = __expf(sc);
    den += ex;
    const uint u = *reinterpret_cast<const uint*>(&h1b[(size_t)s * C1 + c0]);
    a0 += ex * __uint_as_float(u << 16);
    a1 += ex * __uint_as_float(u & 0xffff0000u);
  }
  const float inv = 1.f / fmaxf(den, 1e-9f);
  float o0 = a0 * inv + bv0;
  float o1 = a1 * inv + bv1;
  o0 = (o0 > 0.f) ? o0 : expm1f(o0);  // ELU
  o1 = (o1 > 0.f) ? o1 : expm1f(o1);
  *reinterpret_cast<uint*>(&out1b[(size_t)n * C1 + c0]) = packbf2(o0, o1);
}

// -------- tiled GEMM2: h2[N,40](f32) = out1[N,256](bf16) @ W2[256,40] ------
__global__ __launch_bounds__(256) void k_gemm2(const ushort* __restrict__ Ab,
                                               const void* __restrict__ Wr,
                                               const int* __restrict__ flag,
                                               float* __restrict__ H) {
  __shared__ __align__(16) float As[128 * 36];  // [row][k-chunk], pitch 36
  __shared__ __align__(16) float Bs[256 * 41];  // [k][col], pitch 41
  const int tid = threadIdx.x;
  const int rt  = blockIdx.x * 128;
  const int isf = flag[0];

  for (int i = tid; i < 256 * NCLS; i += 256)
    Bs[(i / NCLS) * 41 + (i % NCLS)] = ldv(Wr, i, isf);

  const int rq = tid >> 3;  // 0..31 -> rows rq*4..rq*4+3
  const int cq = tid & 7;   // cols cq*5..cq*5+4
  float acc[4][5];
#pragma unroll
  for (int i = 0; i < 4; ++i)
#pragma unroll
    for (int j = 0; j < 5; ++j) acc[i][j] = 0.f;

  for (int ch = 0; ch < 8; ++ch) {
    const int k0 = ch << 5;
    __syncthreads();
    { // stage A chunk: 128 rows x 32 k (bf16 -> f32)
      const int ar = tid >> 3;         // 0..31
      const int ac = (tid & 7) << 2;   // 0..28
#pragma unroll
      for (int p = 0; p < 4; ++p) {
        const int row  = ar + (p << 5);
        const int grow = rt + row;
        float4 v = make_float4(0.f, 0.f, 0.f, 0.f);
        if (grow < NNODES) {
          uint2 u = *reinterpret_cast<const uint2*>(Ab + (size_t)grow * C1 + k0 + ac);
          v = bfx4(u);
        }
        *reinterpret_cast<float4*>(&As[row * 36 + ac]) = v;
      }
    }
    __syncthreads();
#pragma unroll 4
    for (int kk = 0; kk < 32; ++kk) {
      float a[4], b[5];
#pragma unroll
      for (int i = 0; i < 4; ++i) a[i] = As[(rq * 4 + i) * 36 + kk];
#pragma unroll
      for (int j = 0; j < 5; ++j) b[j] = Bs[(k0 + kk) * 41 + cq * 5 + j];
#pragma unroll
      for (int i = 0; i < 4; ++i)
#pragma unroll
        for (int j = 0; j < 5; ++j) acc[i][j] += a[i] * b[j];
    }
  }

#pragma unroll
  for (int i = 0; i < 4; ++i) {
    const int row = rt + rq * 4 + i;
    if (row < NNODES) {
#pragma unroll
      for (int j = 0; j < 5; ++j)
        H[(size_t)row * NCLS + cq * 5 + j] = acc[i][j];
    }
  }
}

// ---------------- el/er layer 2 (H=1, D=40, shuffle reduce) ----------------
__global__ __launch_bounds__(256) void k_elr2(const float* __restrict__ h2,
                                              const void* __restrict__ alr,
                                              const void* __restrict__ arr,
                                              const int* __restrict__ flag,
                                              float* __restrict__ el,
                                              float* __restrict__ er) {
  const int t    = threadIdx.x;
  const int lane = t & 63;
  const int n    = blockIdx.x * 4 + (t >> 6);
  const int isf  = flag[0];
  float pl = 0.f, pr = 0.f;
  if (n < NNODES && lane < NCLS) {
    const float v = h2[(size_t)n * NCLS + lane];
    pl = v * ldv(alr, lane, isf);
    pr = v * ldv(arr, lane, isf);
  }
#pragma unroll
  for (int k = 32; k >= 1; k >>= 1) {
    pl += __shfl_xor(pl, k, 64);
    pr += __shfl_xor(pr, k, 64);
  }
  if (n < NNODES && lane == 0) { el[n] = pl; er[n] = pr; }
}

// -------- Agg layer 2 (wave per node) -> FLOAT32 output --------------------
__global__ __launch_bounds__(256) void k_agg2(const int* __restrict__ rowptr,
                                              const int* __restrict__ deg,
                                              const int* __restrict__ colsrc,
                                              const float* __restrict__ h2,
                                              const float* __restrict__ el,
                                              const float* __restrict__ er,
                                              const void* __restrict__ b2r,
                                              const int* __restrict__ flag,
                                              float* __restrict__ out) {
  const int t    = threadIdx.x;
  const int lane = t & 63;
  const int n    = blockIdx.x * 4 + (t >> 6);
  if (n >= NNODES) return;
  const int isf  = flag[0];
  const int start = rowptr[n];
  int cnt = deg[n];
  if (cnt < 0) cnt = 0;
  if (cnt > NEDGES) cnt = NEDGES;
  const float ern = er[n];
  float acc = 0.f, den = 0.f;
  for (int i = 0; i < cnt; ++i) {
    const int s = colsrc[start + i];
    if ((uint)s >= (uint)NNODES) continue;
    float sc = el[s] + ern;
    sc = (sc >= 0.f) ? sc : 0.2f * sc;
    const float ex = __expf(sc);
    den += ex;
    if (lane < NCLS) acc += ex * h2[(size_t)s * NCLS + lane];
  }
  if (lane < NCLS) {
    const float o = acc / fmaxf(den, 1e-9f) + ldv(b2r, lane, isf);
    out[(size_t)n * NCLS + lane] = o;
  }
}

extern "C" void kernel_launch(void* const* d_in, const int* in_sizes, int n_in,
                              void* d_out, int out_size, void* d_ws, size_t ws_size,
                              hipStream_t stream) {
  // ---- size-driven input mapping: supports dict order AND name-sorted ----
  int ix = -1, iW1 = -1, iW2 = -1, e1 = -1, e2 = -1;
  int i256[3] = {-1, -1, -1}, n256 = 0;
  int i40[3]  = {-1, -1, -1}, n40 = 0;
  for (int i = 0; i < n_in; ++i) {
    switch (in_sizes[i]) {
      case 6400000: ix = i; break;
      case 800000:  if (e1 < 0) e1 = i; else e2 = i; break;
      case 32768:   iW1 = i; break;
      case 10240:   iW2 = i; break;
      case 256:     if (n256 < 3) i256[n256++] = i; break;
      case 40:      if (n40 < 3)  i40[n40++]  = i; break;
      default: break;
    }
  }
  bool mapped = (ix >= 0 && iW1 >= 0 && iW2 >= 0 && e2 >= 0 && n256 == 3 && n40 == 3);
  int isrc, idst;
  if (mapped) {
    const bool dict_order = (in_sizes[0] == 6400000);
    isrc = dict_order ? e1 : e2;
    idst = dict_order ? e2 : e1;
  } else {
    ix = 0; isrc = 1; idst = 2; iW1 = 3;
    i256[0] = 4; i256[1] = 5; i256[2] = 6;
    iW2 = 7; i40[0] = 8; i40[1] = 9; i40[2] = 10;
  }
  const void* X   = d_in[ix];
  const int*  src = (const int*)d_in[isrc];
  const int*  dst = (const int*)d_in[idst];
  const void* W1  = d_in[iW1];
  const void* al1 = d_in[i256[0]];
  const void* ar1 = d_in[i256[1]];
  const void* b1  = d_in[i256[2]];
  const void* W2  = d_in[iW2];
  const void* al2 = d_in[i40[0]];
  const void* ar2 = d_in[i40[1]];
  const void* b2  = d_in[i40[2]];

  char* ws = (char*)d_ws;
  size_t off = 0;
  auto alloc = [&](size_t bytes) -> void* {
    void* p = ws + off;
    off = (off + bytes + 255) & ~(size_t)255;
    return p;
  };
  int*    flag   = (int*)alloc(256);
  int*    deg    = (int*)alloc((size_t)NNODES * 4);
  int*    rowptr = (int*)alloc((size_t)NNODES * 4);
  int*    woff   = (int*)alloc((size_t)NNODES * 4);
  int*    bsum   = (int*)alloc(256 * 4);
  int*    boff   = (int*)alloc(256 * 4);
  int*    colsrc = (int*)alloc((size_t)NEDGES * 4);
  float*  el1    = (float*)alloc((size_t)NNODES * HEADS * 4);
  float*  er1    = (float*)alloc((size_t)NNODES * HEADS * 4);
  float*  el2    = (float*)alloc((size_t)NNODES * 4);
  float*  er2    = (float*)alloc((size_t)NNODES * 4);
  ushort* h1b    = (ushort*)alloc((size_t)NNODES * C1 * 2);   // 25.6 MB
  ushort* out1b  = (ushort*)alloc((size_t)NNODES * C1 * 2);   // 25.6 MB
  float*  h2     = (float*)alloc((size_t)NNODES * NCLS * 4);  // 8 MB

  const int NSB = (NNODES + 1023) / 1024;

  k_detect<<<1, 256, 0, stream>>>((const ushort*)X, flag);

  hipMemsetAsync(deg, 0, (size_t)NNODES * 4, stream);
  k_hist<<<(NEDGES + 255) / 256, 256, 0, stream>>>(dst, deg);
  k_scan1<<<NSB, 1024, 0, stream>>>(deg, rowptr, bsum);
  k_scan2<<<1, 64, 0, stream>>>(bsum, boff, NSB);
  k_scan3<<<NSB, 1024, 0, stream>>>(rowptr, woff, boff);
  k_scatter<<<(NEDGES + 255) / 256, 256, 0, stream>>>(src, dst, woff, colsrc);

  k_gemm1<<<(NNODES + 31) / 32, 256, 0, stream>>>(X, W1, flag, h1b);
  k_elr1<<<NNODES, 256, 0, stream>>>(h1b, al1, ar1, flag, el1, er1);
  k_agg1<<<(NNODES + 1) / 2, 256, 0, stream>>>(rowptr, deg, colsrc, h1b, el1, er1, b1,
                                               flag, out1b);

  k_gemm2<<<(NNODES + 127) / 128, 256, 0, stream>>>(out1b, W2, flag, h2);
  k_elr2<<<(NNODES + 3) / 4, 256, 0, stream>>>(h2, al2, ar2, flag, el2, er2);
  k_agg2<<<(NNODES + 3) / 4, 256, 0, stream>>>(rowptr, deg, colsrc, h2, el2, er2, b2,
                                               flag, (float*)d_out);
}

// Round 7
// 451.956 us; speedup vs baseline: 2.5989x; 1.3243x over previous
//
#include <hip/hip_runtime.h>
#include <hip/hip_bf16.h>
#include <math.h>

#define NNODES 50000
#define NEDGES 800000
#define INF    128
#define HIDD   32
#define HEADS  8
#define C1     256   // HEADS*HIDD
#define NCLS   40

typedef unsigned int  uint;
typedef unsigned short ushort;

__device__ __forceinline__ float bf2f(ushort v) {
  return __uint_as_float(((uint)v) << 16);
}
__device__ __forceinline__ ushort f2bf(float f) {
  __hip_bfloat16 b = __float2bfloat16(f);
  return *reinterpret_cast<ushort*>(&b);
}
__device__ __forceinline__ float ldv(const void* p, long i, int isf) {
  return isf ? ((const float*)p)[i] : bf2f(((const ushort*)p)[i]);
}
// 8 bf16 (as uint4) -> 8 f32
__device__ __forceinline__ void bfx8(const uint4 u, float4& a, float4& b) {
  a.x = __uint_as_float(u.x << 16);
  a.y = __uint_as_float(u.x & 0xffff0000u);
  a.z = __uint_as_float(u.y << 16);
  a.w = __uint_as_float(u.y & 0xffff0000u);
  b.x = __uint_as_float(u.z << 16);
  b.y = __uint_as_float(u.z & 0xffff0000u);
  b.z = __uint_as_float(u.w << 16);
  b.w = __uint_as_float(u.w & 0xffff0000u);
}
// 4 bf16 (as uint2) -> 4 f32
__device__ __forceinline__ float4 bfx4(const uint2 u) {
  float4 v;
  v.x = __uint_as_float(u.x << 16);
  v.y = __uint_as_float(u.x & 0xffff0000u);
  v.z = __uint_as_float(u.y << 16);
  v.w = __uint_as_float(u.y & 0xffff0000u);
  return v;
}
__device__ __forceinline__ uint packbf2(float f0, float f1) {
  return (uint)f2bf(f0) | ((uint)f2bf(f1) << 16);
}
__device__ __forceinline__ float lrelu(float x) {
  return (x >= 0.f) ? x : 0.2f * x;
}

// ---------------- dtype detection: f32-as-bf16 has wild exponents ----------
__global__ void k_detect(const ushort* __restrict__ xr, int* __restrict__ flag) {
  __shared__ int cnt;
  const int t = threadIdx.x;
  if (t == 0) cnt = 0;
  __syncthreads();
  int c = 0;
  for (int i = t; i < 4096; i += 256) {
    const uint e = (xr[i] >> 7) & 0xFFu;
    if (e > 200u) c++;
  }
  atomicAdd(&cnt, c);
  __syncthreads();
  if (t == 0) flag[0] = (cnt > 100) ? 1 : 0;  // 1 => inputs stored as float32
}

// ---------------- CSR build ----------------
__global__ void k_hist(const int* __restrict__ dst, int* __restrict__ deg) {
  int e = blockIdx.x * 256 + threadIdx.x;
  if (e < NEDGES) {
    int d = dst[e];
    if ((uint)d < (uint)NNODES) atomicAdd(&deg[d], 1);
  }
}

__global__ __launch_bounds__(1024) void k_scan1(const int* __restrict__ deg,
                                                int* __restrict__ rowptr,
                                                int* __restrict__ bsum) {
  __shared__ int s[1024];
  int t = threadIdx.x;
  int i = blockIdx.x * 1024 + t;
  int v = (i < NNODES) ? deg[i] : 0;
  s[t] = v;
  __syncthreads();
  for (int off = 1; off < 1024; off <<= 1) {
    int u = (t >= off) ? s[t - off] : 0;
    __syncthreads();
    s[t] += u;
    __syncthreads();
  }
  if (i < NNODES) rowptr[i] = s[t] - v;   // exclusive
  if (t == 1023) bsum[blockIdx.x] = s[t]; // block total
}

__global__ void k_scan2(int* __restrict__ bsum, int* __restrict__ boff, int nb) {
  if (blockIdx.x == 0 && threadIdx.x == 0) {
    int run = 0;
    for (int b = 0; b < nb; ++b) { boff[b] = run; run += bsum[b]; }
  }
}

__global__ __launch_bounds__(1024) void k_scan3(int* __restrict__ rowptr,
                                                int* __restrict__ woff,
                                                const int* __restrict__ boff) {
  int i = blockIdx.x * 1024 + threadIdx.x;
  if (i < NNODES) {
    int r = rowptr[i] + boff[blockIdx.x];
    rowptr[i] = r;
    woff[i] = r;
  }
}

__global__ void k_scatter(const int* __restrict__ src, const int* __restrict__ dst,
                          int* __restrict__ woff, int* __restrict__ colsrc) {
  int e = blockIdx.x * 256 + threadIdx.x;
  if (e < NEDGES) {
    int d = dst[e];
    if ((uint)d < (uint)NNODES) {
      int pos = atomicAdd(&woff[d], 1);
      if ((uint)pos < (uint)NEDGES) colsrc[pos] = src[e];
    }
  }
}

// -------- tiled GEMM1: h1[N,256](bf16) = x[N,128] @ W1[128,256] ------------
__global__ __launch_bounds__(256) void k_gemm1(const void* __restrict__ Xr,
                                               const void* __restrict__ Wr,
                                               const int* __restrict__ flag,
                                               ushort* __restrict__ Hb) {
  __shared__ __align__(16) float As[32 * 132];  // [row][k], pitch 132
  __shared__ __align__(16) float Bs[32 * 260];  // [k][col], pitch 260
  const int tid = threadIdx.x;
  const int rt  = blockIdx.x * 32;
  const int isf = flag[0];

  { // stage A tile (32 rows x full K=128) -> f32
    const int r  = tid >> 4;          // 0..15
    const int c0 = (tid & 15) << 3;   // 0..120
#pragma unroll
    for (int p = 0; p < 2; ++p) {
      const int row  = r + (p << 4);
      const int grow = rt + row;
      float4 a = make_float4(0.f, 0.f, 0.f, 0.f);
      float4 b = make_float4(0.f, 0.f, 0.f, 0.f);
      if (grow < NNODES) {
        if (isf) {
          const float* Xf = (const float*)Xr;
          a = *reinterpret_cast<const float4*>(Xf + (size_t)grow * INF + c0);
          b = *reinterpret_cast<const float4*>(Xf + (size_t)grow * INF + c0 + 4);
        } else {
          const ushort* Xb = (const ushort*)Xr;
          uint4 u = *reinterpret_cast<const uint4*>(Xb + (size_t)grow * INF + c0);
          bfx8(u, a, b);
        }
      }
      *reinterpret_cast<float4*>(&As[row * 132 + c0])     = a;
      *reinterpret_cast<float4*>(&As[row * 132 + c0 + 4]) = b;
    }
  }

  const int cg = tid & 31;
  const int rg = tid >> 5;
  float acc[4][8];
#pragma unroll
  for (int i = 0; i < 4; ++i)
#pragma unroll
    for (int j = 0; j < 8; ++j) acc[i][j] = 0.f;

  for (int ch = 0; ch < 4; ++ch) {
    const int k0 = ch << 5;
    __syncthreads();
    {
      const int kr = tid >> 5;
      const int c0 = (tid & 31) << 3;
#pragma unroll
      for (int p = 0; p < 4; ++p) {
        const int row = kr + (p << 3);
        float4 a, b;
        if (isf) {
          const float* Wf = (const float*)Wr;
          a = *reinterpret_cast<const float4*>(Wf + (size_t)(k0 + row) * C1 + c0);
          b = *reinterpret_cast<const float4*>(Wf + (size_t)(k0 + row) * C1 + c0 + 4);
        } else {
          const ushort* Wb = (const ushort*)Wr;
          uint4 u = *reinterpret_cast<const uint4*>(Wb + (size_t)(k0 + row) * C1 + c0);
          bfx8(u, a, b);
        }
        *reinterpret_cast<float4*>(&Bs[row * 260 + c0])     = a;
        *reinterpret_cast<float4*>(&Bs[row * 260 + c0 + 4]) = b;
      }
    }
    __syncthreads();
#pragma unroll 4
    for (int kk = 0; kk < 32; ++kk) {
      const int k = k0 + kk;
      float a[4];
#pragma unroll
      for (int i = 0; i < 4; ++i) a[i] = As[(rg * 4 + i) * 132 + k];
      float b[8];
      float4 b0 = *reinterpret_cast<const float4*>(&Bs[kk * 260 + (cg << 2)]);
      float4 b1 = *reinterpret_cast<const float4*>(&Bs[kk * 260 + 128 + (cg << 2)]);
      b[0] = b0.x; b[1] = b0.y; b[2] = b0.z; b[3] = b0.w;
      b[4] = b1.x; b[5] = b1.y; b[6] = b1.z; b[7] = b1.w;
#pragma unroll
      for (int i = 0; i < 4; ++i)
#pragma unroll
        for (int j = 0; j < 8; ++j) acc[i][j] += a[i] * b[j];
    }
  }

#pragma unroll
  for (int i = 0; i < 4; ++i) {
    const int row = rt + rg * 4 + i;
    if (row < NNODES) {
      uint2 v0, v1;
      v0.x = packbf2(acc[i][0], acc[i][1]);
      v0.y = packbf2(acc[i][2], acc[i][3]);
      v1.x = packbf2(acc[i][4], acc[i][5]);
      v1.y = packbf2(acc[i][6], acc[i][7]);
      *reinterpret_cast<uint2*>(&Hb[(size_t)row * C1 + (cg << 2)])       = v0;
      *reinterpret_cast<uint2*>(&Hb[(size_t)row * C1 + 128 + (cg << 2)]) = v1;
    }
  }
}

// ---------------- el/er layer 1 (h1 bf16, shuffle reduce) ------------------
__global__ __launch_bounds__(256) void k_elr1(const ushort* __restrict__ h1b,
                                              const void* __restrict__ alr,
                                              const void* __restrict__ arr,
                                              const int* __restrict__ flag,
                                              float* __restrict__ el,
                                              float* __restrict__ er) {
  const int n = blockIdx.x;
  const int t = threadIdx.x;          // t = h*32 + d
  const int isf = flag[0];
  const float av = ldv(alr, t, isf);
  const float rv = ldv(arr, t, isf);
  float v  = bf2f(h1b[(size_t)n * C1 + t]);
  float pl = v * av;
  float pr = v * rv;
#pragma unroll
  for (int k = 16; k >= 1; k >>= 1) {
    pl += __shfl_xor(pl, k, 64);
    pr += __shfl_xor(pr, k, 64);
  }
  if ((t & 31) == 0) {
    const int h = t >> 5;
    el[n * HEADS + h] = pl;
    er[n * HEADS + h] = pr;
  }
}

// -------- Agg layer 1: 128 thr/node, 2 cols/thr, 4-way MLP unroll ----------
__global__ __launch_bounds__(256) void k_agg1(const int* __restrict__ rowptr,
                                              const int* __restrict__ deg,
                                              const int* __restrict__ colsrc,
                                              const ushort* __restrict__ h1b,
                                              const float* __restrict__ el,
                                              const float* __restrict__ er,
                                              const void* __restrict__ b1r,
                                              const int* __restrict__ flag,
                                              ushort* __restrict__ out1b) {
  const int n   = blockIdx.x * 2 + (threadIdx.x >> 7);
  if (n >= NNODES) return;
  const int t   = threadIdx.x & 127;  // 0..127
  const int c0  = t << 1;             // even col
  const int h   = t >> 4;             // c0>>5
  const int isf = flag[0];
  const float bv0 = ldv(b1r, c0, isf);
  const float bv1 = ldv(b1r, c0 + 1, isf);
  const int start = rowptr[n];
  int cnt = deg[n];
  if (cnt < 0) cnt = 0;
  if (cnt > NEDGES) cnt = NEDGES;
  const float ern = er[n * HEADS + h];
  float a0 = 0.f, a1 = 0.f, den = 0.f;
  int i = 0;
  for (; i + 4 <= cnt; i += 4) {
    // grouped independent loads: 4 indices -> 4 scores -> 4 rows in flight
    const int s0 = colsrc[start + i + 0];
    const int s1 = colsrc[start + i + 1];
    const int s2 = colsrc[start + i + 2];
    const int s3 = colsrc[start + i + 3];
    const float l0 = el[s0 * HEADS + h];
    const float l1 = el[s1 * HEADS + h];
    const float l2 = el[s2 * HEADS + h];
    const float l3 = el[s3 * HEADS + h];
    const uint u0 = *reinterpret_cast<const uint*>(&h1b[(size_t)s0 * C1 + c0]);
    const uint u1 = *reinterpret_cast<const uint*>(&h1b[(size_t)s1 * C1 + c0]);
    const uint u2 = *reinterpret_cast<const uint*>(&h1b[(size_t)s2 * C1 + c0]);
    const uint u3 = *reinterpret_cast<const uint*>(&h1b[(size_t)s3 * C1 + c0]);
    const float e0 = __expf(lrelu(l0 + ern));
    const float e1 = __expf(lrelu(l1 + ern));
    const float e2 = __expf(lrelu(l2 + ern));
    const float e3 = __expf(lrelu(l3 + ern));
    den += e0 + e1 + e2 + e3;
    a0 += e0 * __uint_as_float(u0 << 16);
    a1 += e0 * __uint_as_float(u0 & 0xffff0000u);
    a0 += e1 * __uint_as_float(u1 << 16);
    a1 += e1 * __uint_as_float(u1 & 0xffff0000u);
    a0 += e2 * __uint_as_float(u2 << 16);
    a1 += e2 * __uint_as_float(u2 & 0xffff0000u);
    a0 += e3 * __uint_as_float(u3 << 16);
    a1 += e3 * __uint_as_float(u3 & 0xffff0000u);
  }
  for (; i < cnt; ++i) {
    const int s = colsrc[start + i];
    const float ex = __expf(lrelu(el[s * HEADS + h] + ern));
    den += ex;
    const uint u = *reinterpret_cast<const uint*>(&h1b[(size_t)s * C1 + c0]);
    a0 += ex * __uint_as_float(u << 16);
    a1 += ex * __uint_as_float(u & 0xffff0000u);
  }
  const float inv = 1.f / fmaxf(den, 1e-9f);
  float o0 = a0 * inv + bv0;
  float o1 = a1 * inv + bv1;
  o0 = (o0 > 0.f) ? o0 : expm1f(o0);  // ELU
  o1 = (o1 > 0.f) ? o1 : expm1f(o1);
  *reinterpret_cast<uint*>(&out1b[(size_t)n * C1 + c0]) = packbf2(o0, o1);
}

// -------- tiled GEMM2: h2[N,40](bf16) = out1[N,256](bf16) @ W2[256,40] -----
__global__ __launch_bounds__(256) void k_gemm2(const ushort* __restrict__ Ab,
                                               const void* __restrict__ Wr,
                                               const int* __restrict__ flag,
                                               ushort* __restrict__ Hb) {
  __shared__ __align__(16) float As[128 * 36];  // [row][k-chunk], pitch 36
  __shared__ __align__(16) float Bs[256 * 41];  // [k][col], pitch 41
  const int tid = threadIdx.x;
  const int rt  = blockIdx.x * 128;
  const int isf = flag[0];

  for (int i = tid; i < 256 * NCLS; i += 256)
    Bs[(i / NCLS) * 41 + (i % NCLS)] = ldv(Wr, i, isf);

  const int rq = tid >> 3;  // rows rq*4..rq*4+3
  const int cq = tid & 7;   // cols cq*5..cq*5+4
  float acc[4][5];
#pragma unroll
  for (int i = 0; i < 4; ++i)
#pragma unroll
    for (int j = 0; j < 5; ++j) acc[i][j] = 0.f;

  for (int ch = 0; ch < 8; ++ch) {
    const int k0 = ch << 5;
    __syncthreads();
    {
      const int ar = tid >> 3;
      const int ac = (tid & 7) << 2;
#pragma unroll
      for (int p = 0; p < 4; ++p) {
        const int row  = ar + (p << 5);
        const int grow = rt + row;
        float4 v = make_float4(0.f, 0.f, 0.f, 0.f);
        if (grow < NNODES) {
          uint2 u = *reinterpret_cast<const uint2*>(Ab + (size_t)grow * C1 + k0 + ac);
          v = bfx4(u);
        }
        *reinterpret_cast<float4*>(&As[row * 36 + ac]) = v;
      }
    }
    __syncthreads();
#pragma unroll 4
    for (int kk = 0; kk < 32; ++kk) {
      float a[4], b[5];
#pragma unroll
      for (int i = 0; i < 4; ++i) a[i] = As[(rq * 4 + i) * 36 + kk];
#pragma unroll
      for (int j = 0; j < 5; ++j) b[j] = Bs[(k0 + kk) * 41 + cq * 5 + j];
#pragma unroll
      for (int i = 0; i < 4; ++i)
#pragma unroll
        for (int j = 0; j < 5; ++j) acc[i][j] += a[i] * b[j];
    }
  }

#pragma unroll
  for (int i = 0; i < 4; ++i) {
    const int row = rt + rq * 4 + i;
    if (row < NNODES) {
#pragma unroll
      for (int j = 0; j < 5; ++j)
        Hb[(size_t)row * NCLS + cq * 5 + j] = f2bf(acc[i][j]);
    }
  }
}

// ---------------- el/er layer 2 (h2 bf16, shuffle reduce) ------------------
__global__ __launch_bounds__(256) void k_elr2(const ushort* __restrict__ h2b,
                                              const void* __restrict__ alr,
                                              const void* __restrict__ arr,
                                              const int* __restrict__ flag,
                                              float* __restrict__ el,
                                              float* __restrict__ er) {
  const int t    = threadIdx.x;
  const int lane = t & 63;
  const int n    = blockIdx.x * 4 + (t >> 6);
  const int isf  = flag[0];
  float pl = 0.f, pr = 0.f;
  if (n < NNODES && lane < NCLS) {
    const float v = bf2f(h2b[(size_t)n * NCLS + lane]);
    pl = v * ldv(alr, lane, isf);
    pr = v * ldv(arr, lane, isf);
  }
#pragma unroll
  for (int k = 32; k >= 1; k >>= 1) {
    pl += __shfl_xor(pl, k, 64);
    pr += __shfl_xor(pr, k, 64);
  }
  if (n < NNODES && lane == 0) { el[n] = pl; er[n] = pr; }
}

// -------- Agg layer 2 (wave/node, h2 bf16, 4-way unroll) -> f32 out --------
__global__ __launch_bounds__(256) void k_agg2(const int* __restrict__ rowptr,
                                              const int* __restrict__ deg,
                                              const int* __restrict__ colsrc,
                                              const ushort* __restrict__ h2b,
                                              const float* __restrict__ el,
                                              const float* __restrict__ er,
                                              const void* __restrict__ b2r,
                                              const int* __restrict__ flag,
                                              float* __restrict__ out) {
  const int t    = threadIdx.x;
  const int lane = t & 63;
  const int n    = blockIdx.x * 4 + (t >> 6);
  if (n >= NNODES) return;
  const int isf  = flag[0];
  const int start = rowptr[n];
  int cnt = deg[n];
  if (cnt < 0) cnt = 0;
  if (cnt > NEDGES) cnt = NEDGES;
  const float ern = er[n];
  const bool act = lane < NCLS;
  float acc = 0.f, den = 0.f;
  int i = 0;
  for (; i + 4 <= cnt; i += 4) {
    const int s0 = colsrc[start + i + 0];
    const int s1 = colsrc[start + i + 1];
    const int s2 = colsrc[start + i + 2];
    const int s3 = colsrc[start + i + 3];
    const float l0 = el[s0];
    const float l1 = el[s1];
    const float l2 = el[s2];
    const float l3 = el[s3];
    const float v0 = act ? bf2f(h2b[(size_t)s0 * NCLS + lane]) : 0.f;
    const float v1 = act ? bf2f(h2b[(size_t)s1 * NCLS + lane]) : 0.f;
    const float v2 = act ? bf2f(h2b[(size_t)s2 * NCLS + lane]) : 0.f;
    const float v3 = act ? bf2f(h2b[(size_t)s3 * NCLS + lane]) : 0.f;
    const float e0 = __expf(lrelu(l0 + ern));
    const float e1 = __expf(lrelu(l1 + ern));
    const float e2 = __expf(lrelu(l2 + ern));
    const float e3 = __expf(lrelu(l3 + ern));
    den += e0 + e1 + e2 + e3;
    acc += e0 * v0 + e1 * v1 + e2 * v2 + e3 * v3;
  }
  for (; i < cnt; ++i) {
    const int s = colsrc[start + i];
    const float ex = __expf(lrelu(el[s] + ern));
    den += ex;
    if (act) acc += ex * bf2f(h2b[(size_t)s * NCLS + lane]);
  }
  if (act) {
    const float o = acc / fmaxf(den, 1e-9f) + ldv(b2r, lane, isf);
    out[(size_t)n * NCLS + lane] = o;
  }
}

extern "C" void kernel_launch(void* const* d_in, const int* in_sizes, int n_in,
                              void* d_out, int out_size, void* d_ws, size_t ws_size,
                              hipStream_t stream) {
  // ---- size-driven input mapping: supports dict order AND name-sorted ----
  int ix = -1, iW1 = -1, iW2 = -1, e1 = -1, e2 = -1;
  int i256[3] = {-1, -1, -1}, n256 = 0;
  int i40[3]  = {-1, -1, -1}, n40 = 0;
  for (int i = 0; i < n_in; ++i) {
    switch (in_sizes[i]) {
      case 6400000: ix = i; break;
      case 800000:  if (e1 < 0) e1 = i; else e2 = i; break;
      case 32768:   iW1 = i; break;
      case 10240:   iW2 = i; break;
      case 256:     if (n256 < 3) i256[n256++] = i; break;
      case 40:      if (n40 < 3)  i40[n40++]  = i; break;
      default: break;
    }
  }
  bool mapped = (ix >= 0 && iW1 >= 0 && iW2 >= 0 && e2 >= 0 && n256 == 3 && n40 == 3);
  int isrc, idst;
  if (mapped) {
    const bool dict_order = (in_sizes[0] == 6400000);
    isrc = dict_order ? e1 : e2;
    idst = dict_order ? e2 : e1;
  } else {
    ix = 0; isrc = 1; idst = 2; iW1 = 3;
    i256[0] = 4; i256[1] = 5; i256[2] = 6;
    iW2 = 7; i40[0] = 8; i40[1] = 9; i40[2] = 10;
  }
  const void* X   = d_in[ix];
  const int*  src = (const int*)d_in[isrc];
  const int*  dst = (const int*)d_in[idst];
  const void* W1  = d_in[iW1];
  const void* al1 = d_in[i256[0]];
  const void* ar1 = d_in[i256[1]];
  const void* b1  = d_in[i256[2]];
  const void* W2  = d_in[iW2];
  const void* al2 = d_in[i40[0]];
  const void* ar2 = d_in[i40[1]];
  const void* b2  = d_in[i40[2]];

  char* ws = (char*)d_ws;
  size_t off = 0;
  auto alloc = [&](size_t bytes) -> void* {
    void* p = ws + off;
    off = (off + bytes + 255) & ~(size_t)255;
    return p;
  };
  int*    flag   = (int*)alloc(256);
  int*    deg    = (int*)alloc((size_t)NNODES * 4);
  int*    rowptr = (int*)alloc((size_t)NNODES * 4);
  int*    woff   = (int*)alloc((size_t)NNODES * 4);
  int*    bsum   = (int*)alloc(256 * 4);
  int*    boff   = (int*)alloc(256 * 4);
  int*    colsrc = (int*)alloc((size_t)NEDGES * 4);
  float*  el1    = (float*)alloc((size_t)NNODES * HEADS * 4);
  float*  er1    = (float*)alloc((size_t)NNODES * HEADS * 4);
  float*  el2    = (float*)alloc((size_t)NNODES * 4);
  float*  er2    = (float*)alloc((size_t)NNODES * 4);
  ushort* h1b    = (ushort*)alloc((size_t)NNODES * C1 * 2);   // 25.6 MB
  ushort* out1b  = (ushort*)alloc((size_t)NNODES * C1 * 2);   // 25.6 MB
  ushort* h2b    = (ushort*)alloc((size_t)NNODES * NCLS * 2); // 4 MB

  const int NSB = (NNODES + 1023) / 1024;

  k_detect<<<1, 256, 0, stream>>>((const ushort*)X, flag);

  hipMemsetAsync(deg, 0, (size_t)NNODES * 4, stream);
  k_hist<<<(NEDGES + 255) / 256, 256, 0, stream>>>(dst, deg);
  k_scan1<<<NSB, 1024, 0, stream>>>(deg, rowptr, bsum);
  k_scan2<<<1, 64, 0, stream>>>(bsum, boff, NSB);
  k_scan3<<<NSB, 1024, 0, stream>>>(rowptr, woff, boff);
  k_scatter<<<(NEDGES + 255) / 256, 256, 0, stream>>>(src, dst, woff, colsrc);

  k_gemm1<<<(NNODES + 31) / 32, 256, 0, stream>>>(X, W1, flag, h1b);
  k_elr1<<<NNODES, 256, 0, stream>>>(h1b, al1, ar1, flag, el1, er1);
  k_agg1<<<(NNODES + 1) / 2, 256, 0, stream>>>(rowptr, deg, colsrc, h1b, el1, er1, b1,
                                               flag, out1b);

  k_gemm2<<<(NNODES + 127) / 128, 256, 0, stream>>>(out1b, W2, flag, h2b);
  k_elr2<<<(NNODES + 3) / 4, 256, 0, stream>>>(h2b, al2, ar2, flag, el2, er2);
  k_agg2<<<(NNODES + 3) / 4, 256, 0, stream>>>(rowptr, deg, colsrc, h2b, el2, er2, b2,
                                               flag, (float*)d_out);
}

// Round 8
// 443.627 us; speedup vs baseline: 2.6477x; 1.0188x over previous
//
#include <hip/hip_runtime.h>
#include <hip/hip_bf16.h>
#include <math.h>

#define NNODES 50000
#define NEDGES 800000
#define INF    128
#define HIDD   32
#define HEADS  8
#define C1     256   // HEADS*HIDD
#define NCLS   40

typedef unsigned int  uint;
typedef unsigned short ushort;
typedef __attribute__((ext_vector_type(8))) short short8v;   // 8 bf16 (4 VGPRs)
typedef __attribute__((ext_vector_type(4))) float f32x4;

__device__ __forceinline__ float bf2f(ushort v) {
  return __uint_as_float(((uint)v) << 16);
}
__device__ __forceinline__ ushort f2bf(float f) {
  __hip_bfloat16 b = __float2bfloat16(f);
  return *reinterpret_cast<ushort*>(&b);
}
__device__ __forceinline__ float ldv(const void* p, long i, int isf) {
  return isf ? ((const float*)p)[i] : bf2f(((const ushort*)p)[i]);
}
// 4 bf16 (as uint2) -> 4 f32
__device__ __forceinline__ float4 bfx4(const uint2 u) {
  float4 v;
  v.x = __uint_as_float(u.x << 16);
  v.y = __uint_as_float(u.x & 0xffff0000u);
  v.z = __uint_as_float(u.y << 16);
  v.w = __uint_as_float(u.y & 0xffff0000u);
  return v;
}
__device__ __forceinline__ uint packbf2(float f0, float f1) {
  return (uint)f2bf(f0) | ((uint)f2bf(f1) << 16);
}
__device__ __forceinline__ float lrelu(float x) {
  return (x >= 0.f) ? x : 0.2f * x;
}

// ---------------- dtype detection: f32-as-bf16 has wild exponents ----------
__global__ void k_detect(const ushort* __restrict__ xr, int* __restrict__ flag) {
  __shared__ int cnt;
  const int t = threadIdx.x;
  if (t == 0) cnt = 0;
  __syncthreads();
  int c = 0;
  for (int i = t; i < 4096; i += 256) {
    const uint e = (xr[i] >> 7) & 0xFFu;
    if (e > 200u) c++;
  }
  atomicAdd(&cnt, c);
  __syncthreads();
  if (t == 0) flag[0] = (cnt > 100) ? 1 : 0;  // 1 => inputs stored as float32
}

// ---------------- CSR build ----------------
__global__ void k_hist(const int* __restrict__ dst, int* __restrict__ deg) {
  int e = blockIdx.x * 256 + threadIdx.x;
  if (e < NEDGES) {
    int d = dst[e];
    if ((uint)d < (uint)NNODES) atomicAdd(&deg[d], 1);
  }
}

__global__ __launch_bounds__(1024) void k_scan1(const int* __restrict__ deg,
                                                int* __restrict__ rowptr,
                                                int* __restrict__ bsum) {
  __shared__ int s[1024];
  int t = threadIdx.x;
  int i = blockIdx.x * 1024 + t;
  int v = (i < NNODES) ? deg[i] : 0;
  s[t] = v;
  __syncthreads();
  for (int off = 1; off < 1024; off <<= 1) {
    int u = (t >= off) ? s[t - off] : 0;
    __syncthreads();
    s[t] += u;
    __syncthreads();
  }
  if (i < NNODES) rowptr[i] = s[t] - v;   // exclusive
  if (t == 1023) bsum[blockIdx.x] = s[t]; // block total
}

// one-wave shuffle scan over block sums (nb <= 64)
__global__ __launch_bounds__(64) void k_scan2(const int* __restrict__ bsum,
                                              int* __restrict__ boff, int nb) {
  const int lane = threadIdx.x;
  const int orig = (lane < nb) ? bsum[lane] : 0;
  int v = orig;
#pragma unroll
  for (int off = 1; off < 64; off <<= 1) {
    int u = __shfl_up(v, off, 64);
    if (lane >= off) v += u;
  }
  if (lane < nb) boff[lane] = v - orig;   // exclusive
}

__global__ __launch_bounds__(1024) void k_scan3(int* __restrict__ rowptr,
                                                int* __restrict__ woff,
                                                const int* __restrict__ boff) {
  int i = blockIdx.x * 1024 + threadIdx.x;
  if (i < NNODES) {
    int r = rowptr[i] + boff[blockIdx.x];
    rowptr[i] = r;
    woff[i] = r;
  }
}

__global__ void k_scatter(const int* __restrict__ src, const int* __restrict__ dst,
                          int* __restrict__ woff, int* __restrict__ colsrc,
                          int* __restrict__ coldst) {
  int e = blockIdx.x * 256 + threadIdx.x;
  if (e < NEDGES) {
    int d = dst[e];
    if ((uint)d < (uint)NNODES) {
      int pos = atomicAdd(&woff[d], 1);
      if ((uint)pos < (uint)NEDGES) {
        colsrc[pos] = src[e];
        coldst[pos] = d;
      }
    }
  }
}

// -------- prep: W1[128][256] -> w1tb[256][128] bf16 (transposed) -----------
__global__ __launch_bounds__(256) void k_prep(const void* __restrict__ Wr,
                                              const int* __restrict__ flag,
                                              ushort* __restrict__ w1tb) {
  const int k = blockIdx.x;      // 0..127
  const int n = threadIdx.x;     // 0..255
  const int isf = flag[0];
  w1tb[(size_t)n * INF + k] = f2bf(ldv(Wr, (long)k * C1 + n, isf));
}

// -------- MFMA GEMM1: h1[N,256](bf16) = x[N,128] @ W1[128,256] -------------
// block = 16 rows x 256 cols; 4 waves x 4 col-tiles x 4 k-steps of 16x16x32
__global__ __launch_bounds__(256) void k_gemm1m(const void* __restrict__ Xr,
                                                const ushort* __restrict__ w1tb,
                                                const int* __restrict__ flag,
                                                ushort* __restrict__ Hb) {
  __shared__ __align__(16) ushort xs[16 * 136];   // A tile, pitch 136 (16B-aligned rows)
  const int tid = threadIdx.x;
  const int rt  = blockIdx.x * 16;                // 50000 = 3125*16, exact
  const int isf = flag[0];

  { // stage A: 16 rows x 128 k -> bf16 LDS (8 elems/thread)
    const int r  = tid >> 4;          // 0..15
    const int c0 = (tid & 15) << 3;   // 0..120
    uint4 u;
    if (isf) {
      const float* Xf = (const float*)Xr;
      const float4 a = *reinterpret_cast<const float4*>(Xf + (size_t)(rt + r) * INF + c0);
      const float4 b = *reinterpret_cast<const float4*>(Xf + (size_t)(rt + r) * INF + c0 + 4);
      u.x = packbf2(a.x, a.y);
      u.y = packbf2(a.z, a.w);
      u.z = packbf2(b.x, b.y);
      u.w = packbf2(b.z, b.w);
    } else {
      const ushort* Xb = (const ushort*)Xr;
      u = *reinterpret_cast<const uint4*>(Xb + (size_t)(rt + r) * INF + c0);
    }
    *reinterpret_cast<uint4*>(&xs[r * 136 + c0]) = u;
  }
  __syncthreads();

  const int lane = tid & 63;
  const int wv   = tid >> 6;        // 0..3
  const int n0   = wv << 6;         // wave col base
  const int col  = lane & 15;
  const int quad = lane >> 4;

  f32x4 acc[4] = {{0.f, 0.f, 0.f, 0.f}, {0.f, 0.f, 0.f, 0.f},
                  {0.f, 0.f, 0.f, 0.f}, {0.f, 0.f, 0.f, 0.f}};

#pragma unroll
  for (int ks = 0; ks < 4; ++ks) {
    const int k0 = (ks << 5) + (quad << 3);   // kstep*32 + quad*8
    const short8v a = *reinterpret_cast<const short8v*>(&xs[col * 136 + k0]);
    const short8v b0 = *reinterpret_cast<const short8v*>(&w1tb[(size_t)(n0 +  0 + col) * INF + k0]);
    const short8v b1 = *reinterpret_cast<const short8v*>(&w1tb[(size_t)(n0 + 16 + col) * INF + k0]);
    const short8v b2 = *reinterpret_cast<const short8v*>(&w1tb[(size_t)(n0 + 32 + col) * INF + k0]);
    const short8v b3 = *reinterpret_cast<const short8v*>(&w1tb[(size_t)(n0 + 48 + col) * INF + k0]);
    acc[0] = __builtin_amdgcn_mfma_f32_16x16x32_bf16(a, b0, acc[0], 0, 0, 0);
    acc[1] = __builtin_amdgcn_mfma_f32_16x16x32_bf16(a, b1, acc[1], 0, 0, 0);
    acc[2] = __builtin_amdgcn_mfma_f32_16x16x32_bf16(a, b2, acc[2], 0, 0, 0);
    acc[3] = __builtin_amdgcn_mfma_f32_16x16x32_bf16(a, b3, acc[3], 0, 0, 0);
  }

  // C/D layout: col = lane&15, row = quad*4 + reg
#pragma unroll
  for (int ct = 0; ct < 4; ++ct) {
#pragma unroll
    for (int r = 0; r < 4; ++r) {
      const int row = rt + (quad << 2) + r;
      Hb[(size_t)row * C1 + n0 + (ct << 4) + col] = f2bf(acc[ct][r]);
    }
  }
}

// ---------------- el/er layer 1 (h1 bf16, shuffle reduce) ------------------
__global__ __launch_bounds__(256) void k_elr1(const ushort* __restrict__ h1b,
                                              const void* __restrict__ alr,
                                              const void* __restrict__ arr,
                                              const int* __restrict__ flag,
                                              float* __restrict__ el,
                                              float* __restrict__ er) {
  const int n = blockIdx.x;
  const int t = threadIdx.x;          // t = h*32 + d
  const int isf = flag[0];
  const float av = ldv(alr, t, isf);
  const float rv = ldv(arr, t, isf);
  float v  = bf2f(h1b[(size_t)n * C1 + t]);
  float pl = v * av;
  float pr = v * rv;
#pragma unroll
  for (int k = 16; k >= 1; k >>= 1) {
    pl += __shfl_xor(pl, k, 64);
    pr += __shfl_xor(pr, k, 64);
  }
  if ((t & 31) == 0) {
    const int h = t >> 5;
    el[n * HEADS + h] = pl;
    er[n * HEADS + h] = pr;
  }
}

// -------- edge-parallel scores layer 1: esc1[slot*8+h] ---------------------
__global__ __launch_bounds__(256) void k_esc1(const int* __restrict__ colsrc,
                                              const int* __restrict__ coldst,
                                              const float* __restrict__ el,
                                              const float* __restrict__ er,
                                              float* __restrict__ esc) {
  const int g = blockIdx.x * 256 + threadIdx.x;   // g = slot*8 + h
  if (g >= NEDGES * HEADS) return;
  const int slot = g >> 3, h = g & 7;
  const int s = colsrc[slot];
  const int d = coldst[slot];
  esc[g] = __expf(lrelu(el[s * HEADS + h] + er[d * HEADS + h]));
}

// -------- Agg layer 1: 128 thr/node, 2 cols/thr, precomputed scores --------
__global__ __launch_bounds__(256) void k_agg1(const int* __restrict__ rowptr,
                                              const int* __restrict__ deg,
                                              const int* __restrict__ colsrc,
                                              const float* __restrict__ esc,
                                              const ushort* __restrict__ h1b,
                                              const void* __restrict__ b1r,
                                              const int* __restrict__ flag,
                                              ushort* __restrict__ out1b) {
  const int n   = blockIdx.x * 2 + (threadIdx.x >> 7);
  if (n >= NNODES) return;
  const int t   = threadIdx.x & 127;  // 0..127
  const int c0  = t << 1;             // even col
  const int h   = t >> 4;             // c0>>5
  const int isf = flag[0];
  const float bv0 = ldv(b1r, c0, isf);
  const float bv1 = ldv(b1r, c0 + 1, isf);
  const int start = rowptr[n];
  const int cnt   = deg[n];
  const float* ep = esc + (size_t)start * HEADS + h;
  float a0 = 0.f, a1 = 0.f, den = 0.f;
  int i = 0;
  for (; i + 4 <= cnt; i += 4) {
    const int s0 = colsrc[start + i + 0];
    const int s1 = colsrc[start + i + 1];
    const int s2 = colsrc[start + i + 2];
    const int s3 = colsrc[start + i + 3];
    const float e0 = ep[(i + 0) * HEADS];
    const float e1 = ep[(i + 1) * HEADS];
    const float e2 = ep[(i + 2) * HEADS];
    const float e3 = ep[(i + 3) * HEADS];
    const uint u0 = *reinterpret_cast<const uint*>(&h1b[(size_t)s0 * C1 + c0]);
    const uint u1 = *reinterpret_cast<const uint*>(&h1b[(size_t)s1 * C1 + c0]);
    const uint u2 = *reinterpret_cast<const uint*>(&h1b[(size_t)s2 * C1 + c0]);
    const uint u3 = *reinterpret_cast<const uint*>(&h1b[(size_t)s3 * C1 + c0]);
    den += e0 + e1 + e2 + e3;
    a0 += e0 * __uint_as_float(u0 << 16);
    a1 += e0 * __uint_as_float(u0 & 0xffff0000u);
    a0 += e1 * __uint_as_float(u1 << 16);
    a1 += e1 * __uint_as_float(u1 & 0xffff0000u);
    a0 += e2 * __uint_as_float(u2 << 16);
    a1 += e2 * __uint_as_float(u2 & 0xffff0000u);
    a0 += e3 * __uint_as_float(u3 << 16);
    a1 += e3 * __uint_as_float(u3 & 0xffff0000u);
  }
  for (; i < cnt; ++i) {
    const int s = colsrc[start + i];
    const float ex = ep[i * HEADS];
    den += ex;
    const uint u = *reinterpret_cast<const uint*>(&h1b[(size_t)s * C1 + c0]);
    a0 += ex * __uint_as_float(u << 16);
    a1 += ex * __uint_as_float(u & 0xffff0000u);
  }
  const float inv = 1.f / fmaxf(den, 1e-9f);
  float o0 = a0 * inv + bv0;
  float o1 = a1 * inv + bv1;
  o0 = (o0 > 0.f) ? o0 : expm1f(o0);  // ELU
  o1 = (o1 > 0.f) ? o1 : expm1f(o1);
  *reinterpret_cast<uint*>(&out1b[(size_t)n * C1 + c0]) = packbf2(o0, o1);
}

// -------- tiled GEMM2: h2[N,40](bf16) = out1[N,256](bf16) @ W2[256,40] -----
__global__ __launch_bounds__(256) void k_gemm2(const ushort* __restrict__ Ab,
                                               const void* __restrict__ Wr,
                                               const int* __restrict__ flag,
                                               ushort* __restrict__ Hb) {
  __shared__ __align__(16) float As[128 * 36];
  __shared__ __align__(16) float Bs[256 * 41];
  const int tid = threadIdx.x;
  const int rt  = blockIdx.x * 128;
  const int isf = flag[0];

  for (int i = tid; i < 256 * NCLS; i += 256)
    Bs[(i / NCLS) * 41 + (i % NCLS)] = ldv(Wr, i, isf);

  const int rq = tid >> 3;
  const int cq = tid & 7;
  float acc[4][5];
#pragma unroll
  for (int i = 0; i < 4; ++i)
#pragma unroll
    for (int j = 0; j < 5; ++j) acc[i][j] = 0.f;

  for (int ch = 0; ch < 8; ++ch) {
    const int k0 = ch << 5;
    __syncthreads();
    {
      const int ar = tid >> 3;
      const int ac = (tid & 7) << 2;
#pragma unroll
      for (int p = 0; p < 4; ++p) {
        const int row  = ar + (p << 5);
        const int grow = rt + row;
        float4 v = make_float4(0.f, 0.f, 0.f, 0.f);
        if (grow < NNODES) {
          uint2 u = *reinterpret_cast<const uint2*>(Ab + (size_t)grow * C1 + k0 + ac);
          v = bfx4(u);
        }
        *reinterpret_cast<float4*>(&As[row * 36 + ac]) = v;
      }
    }
    __syncthreads();
#pragma unroll 4
    for (int kk = 0; kk < 32; ++kk) {
      float a[4], b[5];
#pragma unroll
      for (int i = 0; i < 4; ++i) a[i] = As[(rq * 4 + i) * 36 + kk];
#pragma unroll
      for (int j = 0; j < 5; ++j) b[j] = Bs[(k0 + kk) * 41 + cq * 5 + j];
#pragma unroll
      for (int i = 0; i < 4; ++i)
#pragma unroll
        for (int j = 0; j < 5; ++j) acc[i][j] += a[i] * b[j];
    }
  }

#pragma unroll
  for (int i = 0; i < 4; ++i) {
    const int row = rt + rq * 4 + i;
    if (row < NNODES) {
#pragma unroll
      for (int j = 0; j < 5; ++j)
        Hb[(size_t)row * NCLS + cq * 5 + j] = f2bf(acc[i][j]);
    }
  }
}

// ---------------- el/er layer 2 (h2 bf16, shuffle reduce) ------------------
__global__ __launch_bounds__(256) void k_elr2(const ushort* __restrict__ h2b,
                                              const void* __restrict__ alr,
                                              const void* __restrict__ arr,
                                              const int* __restrict__ flag,
                                              float* __restrict__ el,
                                              float* __restrict__ er) {
  const int t    = threadIdx.x;
  const int lane = t & 63;
  const int n    = blockIdx.x * 4 + (t >> 6);
  const int isf  = flag[0];
  float pl = 0.f, pr = 0.f;
  if (n < NNODES && lane < NCLS) {
    const float v = bf2f(h2b[(size_t)n * NCLS + lane]);
    pl = v * ldv(alr, lane, isf);
    pr = v * ldv(arr, lane, isf);
  }
#pragma unroll
  for (int k = 32; k >= 1; k >>= 1) {
    pl += __shfl_xor(pl, k, 64);
    pr += __shfl_xor(pr, k, 64);
  }
  if (n < NNODES && lane == 0) { el[n] = pl; er[n] = pr; }
}

// -------- edge-parallel scores layer 2: esc2[slot] -------------------------
__global__ __launch_bounds__(256) void k_esc2(const int* __restrict__ colsrc,
                                              const int* __restrict__ coldst,
                                              const float* __restrict__ el,
                                              const float* __restrict__ er,
                                              float* __restrict__ esc) {
  const int slot = blockIdx.x * 256 + threadIdx.x;
  if (slot >= NEDGES) return;
  esc[slot] = __expf(lrelu(el[colsrc[slot]] + er[coldst[slot]]));
}

// -------- Agg layer 2 (wave/node, precomputed scores) -> f32 out -----------
__global__ __launch_bounds__(256) void k_agg2(const int* __restrict__ rowptr,
                                              const int* __restrict__ deg,
                                              const int* __restrict__ colsrc,
                                              const float* __restrict__ esc,
                                              const ushort* __restrict__ h2b,
                                              const void* __restrict__ b2r,
                                              const int* __restrict__ flag,
                                              float* __restrict__ out) {
  const int t    = threadIdx.x;
  const int lane = t & 63;
  const int n    = blockIdx.x * 4 + (t >> 6);
  if (n >= NNODES) return;
  const int isf  = flag[0];
  const int start = rowptr[n];
  const int cnt   = deg[n];
  const bool act = lane < NCLS;
  float acc = 0.f, den = 0.f;
  int i = 0;
  for (; i + 4 <= cnt; i += 4) {
    const int s0 = colsrc[start + i + 0];
    const int s1 = colsrc[start + i + 1];
    const int s2 = colsrc[start + i + 2];
    const int s3 = colsrc[start + i + 3];
    const float e0 = esc[start + i + 0];
    const float e1 = esc[start + i + 1];
    const float e2 = esc[start + i + 2];
    const float e3 = esc[start + i + 3];
    const float v0 = act ? bf2f(h2b[(size_t)s0 * NCLS + lane]) : 0.f;
    const float v1 = act ? bf2f(h2b[(size_t)s1 * NCLS + lane]) : 0.f;
    const float v2 = act ? bf2f(h2b[(size_t)s2 * NCLS + lane]) : 0.f;
    const float v3 = act ? bf2f(h2b[(size_t)s3 * NCLS + lane]) : 0.f;
    den += e0 + e1 + e2 + e3;
    acc += e0 * v0 + e1 * v1 + e2 * v2 + e3 * v3;
  }
  for (; i < cnt; ++i) {
    const int s = colsrc[start + i];
    const float ex = esc[start + i];
    den += ex;
    if (act) acc += ex * bf2f(h2b[(size_t)s * NCLS + lane]);
  }
  if (act) {
    const float o = acc / fmaxf(den, 1e-9f) + ldv(b2r, lane, isf);
    out[(size_t)n * NCLS + lane] = o;
  }
}

extern "C" void kernel_launch(void* const* d_in, const int* in_sizes, int n_in,
                              void* d_out, int out_size, void* d_ws, size_t ws_size,
                              hipStream_t stream) {
  // ---- size-driven input mapping: supports dict order AND name-sorted ----
  int ix = -1, iW1 = -1, iW2 = -1, e1 = -1, e2 = -1;
  int i256[3] = {-1, -1, -1}, n256 = 0;
  int i40[3]  = {-1, -1, -1}, n40 = 0;
  for (int i = 0; i < n_in; ++i) {
    switch (in_sizes[i]) {
      case 6400000: ix = i; break;
      case 800000:  if (e1 < 0) e1 = i; else e2 = i; break;
      case 32768:   iW1 = i; break;
      case 10240:   iW2 = i; break;
      case 256:     if (n256 < 3) i256[n256++] = i; break;
      case 40:      if (n40 < 3)  i40[n40++]  = i; break;
      default: break;
    }
  }
  bool mapped = (ix >= 0 && iW1 >= 0 && iW2 >= 0 && e2 >= 0 && n256 == 3 && n40 == 3);
  int isrc, idst;
  if (mapped) {
    const bool dict_order = (in_sizes[0] == 6400000);
    isrc = dict_order ? e1 : e2;
    idst = dict_order ? e2 : e1;
  } else {
    ix = 0; isrc = 1; idst = 2; iW1 = 3;
    i256[0] = 4; i256[1] = 5; i256[2] = 6;
    iW2 = 7; i40[0] = 8; i40[1] = 9; i40[2] = 10;
  }
  const void* X   = d_in[ix];
  const int*  src = (const int*)d_in[isrc];
  const int*  dst = (const int*)d_in[idst];
  const void* W1  = d_in[iW1];
  const void* al1 = d_in[i256[0]];
  const void* ar1 = d_in[i256[1]];
  const void* b1  = d_in[i256[2]];
  const void* W2  = d_in[iW2];
  const void* al2 = d_in[i40[0]];
  const void* ar2 = d_in[i40[1]];
  const void* b2  = d_in[i40[2]];

  char* ws = (char*)d_ws;
  size_t off = 0;
  auto alloc = [&](size_t bytes) -> void* {
    void* p = ws + off;
    off = (off + bytes + 255) & ~(size_t)255;
    return p;
  };
  int*    flag   = (int*)alloc(256);
  int*    deg    = (int*)alloc((size_t)NNODES * 4);
  int*    rowptr = (int*)alloc((size_t)NNODES * 4);
  int*    woff   = (int*)alloc((size_t)NNODES * 4);
  int*    bsum   = (int*)alloc(256 * 4);
  int*    boff   = (int*)alloc(256 * 4);
  int*    colsrc = (int*)alloc((size_t)NEDGES * 4);
  int*    coldst = (int*)alloc((size_t)NEDGES * 4);
  float*  el1    = (float*)alloc((size_t)NNODES * HEADS * 4);
  float*  er1    = (float*)alloc((size_t)NNODES * HEADS * 4);
  float*  el2    = (float*)alloc((size_t)NNODES * 4);
  float*  er2    = (float*)alloc((size_t)NNODES * 4);
  float*  esc1   = (float*)alloc((size_t)NEDGES * HEADS * 4);  // 25.6 MB
  float*  esc2   = (float*)alloc((size_t)NEDGES * 4);          // 3.2 MB
  ushort* w1tb   = (ushort*)alloc((size_t)C1 * INF * 2);       // 64 KB
  ushort* h1b    = (ushort*)alloc((size_t)NNODES * C1 * 2);    // 25.6 MB
  ushort* out1b  = (ushort*)alloc((size_t)NNODES * C1 * 2);    // 25.6 MB
  ushort* h2b    = (ushort*)alloc((size_t)NNODES * NCLS * 2);  // 4 MB

  const int NSB = (NNODES + 1023) / 1024;

  k_detect<<<1, 256, 0, stream>>>((const ushort*)X, flag);

  hipMemsetAsync(deg, 0, (size_t)NNODES * 4, stream);
  k_hist<<<(NEDGES + 255) / 256, 256, 0, stream>>>(dst, deg);
  k_scan1<<<NSB, 1024, 0, stream>>>(deg, rowptr, bsum);
  k_scan2<<<1, 64, 0, stream>>>(bsum, boff, NSB);
  k_scan3<<<NSB, 1024, 0, stream>>>(rowptr, woff, boff);
  k_scatter<<<(NEDGES + 255) / 256, 256, 0, stream>>>(src, dst, woff, colsrc, coldst);

  k_prep<<<INF, 256, 0, stream>>>(W1, flag, w1tb);
  k_gemm1m<<<NNODES / 16, 256, 0, stream>>>(X, w1tb, flag, h1b);
  k_elr1<<<NNODES, 256, 0, stream>>>(h1b, al1, ar1, flag, el1, er1);
  k_esc1<<<(NEDGES * HEADS + 255) / 256, 256, 0, stream>>>(colsrc, coldst, el1, er1, esc1);
  k_agg1<<<(NNODES + 1) / 2, 256, 0, stream>>>(rowptr, deg, colsrc, esc1, h1b, b1,
                                               flag, out1b);

  k_gemm2<<<(NNODES + 127) / 128, 256, 0, stream>>>(out1b, W2, flag, h2b);
  k_elr2<<<(NNODES + 3) / 4, 256, 0, stream>>>(h2b, al2, ar2, flag, el2, er2);
  k_esc2<<<(NEDGES + 255) / 256, 256, 0, stream>>>(colsrc, coldst, el2, er2, esc2);
  k_agg2<<<(NNODES + 3) / 4, 256, 0, stream>>>(rowptr, deg, colsrc, esc2, h2b, b2,
                                               flag, (float*)d_out);
}

// Round 9
// 369.573 us; speedup vs baseline: 3.1782x; 1.2004x over previous
//
#include <hip/hip_runtime.h>
#include <hip/hip_bf16.h>
#include <math.h>

#define NNODES 50000
#define NEDGES 800000
#define INF    128
#define HIDD   32
#define HEADS  8
#define C1     256   // HEADS*HIDD
#define NCLS   40
#define NCP    48    // NCLS padded to 3 MFMA col-tiles

typedef unsigned int  uint;
typedef unsigned short ushort;
typedef __attribute__((ext_vector_type(8))) short short8v;   // 8 bf16 (4 VGPRs)
typedef __attribute__((ext_vector_type(4))) float f32x4;

__device__ __forceinline__ float bf2f(ushort v) {
  return __uint_as_float(((uint)v) << 16);
}
__device__ __forceinline__ ushort f2bf(float f) {
  __hip_bfloat16 b = __float2bfloat16(f);
  return *reinterpret_cast<ushort*>(&b);
}
__device__ __forceinline__ float ldv(const void* p, long i, int isf) {
  return isf ? ((const float*)p)[i] : bf2f(((const ushort*)p)[i]);
}
__device__ __forceinline__ uint packbf2(float f0, float f1) {
  return (uint)f2bf(f0) | ((uint)f2bf(f1) << 16);
}
__device__ __forceinline__ float lrelu(float x) {
  return (x >= 0.f) ? x : 0.2f * x;
}

// ---------------- dtype detection ----------------
__global__ void k_detect(const ushort* __restrict__ xr, int* __restrict__ flag) {
  __shared__ int cnt;
  const int t = threadIdx.x;
  if (t == 0) cnt = 0;
  __syncthreads();
  int c = 0;
  for (int i = t; i < 4096; i += 256) {
    const uint e = (xr[i] >> 7) & 0xFFu;
    if (e > 200u) c++;
  }
  atomicAdd(&cnt, c);
  __syncthreads();
  if (t == 0) flag[0] = (cnt > 100) ? 1 : 0;  // 1 => inputs stored as float32
}

// ---------------- CSR build ----------------
__global__ void k_hist(const int* __restrict__ dst, int* __restrict__ deg) {
  int e = blockIdx.x * 256 + threadIdx.x;
  if (e < NEDGES) {
    int d = dst[e];
    if ((uint)d < (uint)NNODES) atomicAdd(&deg[d], 1);
  }
}

__global__ __launch_bounds__(1024) void k_scan1(const int* __restrict__ deg,
                                                int* __restrict__ rowptr,
                                                int* __restrict__ bsum) {
  __shared__ int s[1024];
  int t = threadIdx.x;
  int i = blockIdx.x * 1024 + t;
  int v = (i < NNODES) ? deg[i] : 0;
  s[t] = v;
  __syncthreads();
  for (int off = 1; off < 1024; off <<= 1) {
    int u = (t >= off) ? s[t - off] : 0;
    __syncthreads();
    s[t] += u;
    __syncthreads();
  }
  if (i < NNODES) rowptr[i] = s[t] - v;   // exclusive
  if (t == 1023) bsum[blockIdx.x] = s[t];
}

__global__ __launch_bounds__(64) void k_scan2(const int* __restrict__ bsum,
                                              int* __restrict__ boff, int nb) {
  const int lane = threadIdx.x;
  const int orig = (lane < nb) ? bsum[lane] : 0;
  int v = orig;
#pragma unroll
  for (int off = 1; off < 64; off <<= 1) {
    int u = __shfl_up(v, off, 64);
    if (lane >= off) v += u;
  }
  if (lane < nb) boff[lane] = v - orig;
}

__global__ __launch_bounds__(1024) void k_scan3(int* __restrict__ rowptr,
                                                int* __restrict__ woff,
                                                const int* __restrict__ boff) {
  int i = blockIdx.x * 1024 + threadIdx.x;
  if (i < NNODES) {
    int r = rowptr[i] + boff[blockIdx.x];
    rowptr[i] = r;
    woff[i] = r;
  }
}

__global__ void k_scatter(const int* __restrict__ src, const int* __restrict__ dst,
                          int* __restrict__ woff, int* __restrict__ colsrc,
                          int* __restrict__ coldst) {
  int e = blockIdx.x * 256 + threadIdx.x;
  if (e < NEDGES) {
    int d = dst[e];
    if ((uint)d < (uint)NNODES) {
      int pos = atomicAdd(&woff[d], 1);
      if ((uint)pos < (uint)NEDGES) {
        colsrc[pos] = src[e];
        coldst[pos] = d;
      }
    }
  }
}

// -------- prep1: W1[128][256] -> w1tb[256][128] bf16 -----------------------
__global__ __launch_bounds__(256) void k_prep1(const void* __restrict__ Wr,
                                               const int* __restrict__ flag,
                                               ushort* __restrict__ w1tb) {
  const int k = blockIdx.x;      // 0..127
  const int n = threadIdx.x;     // 0..255
  const int isf = flag[0];
  w1tb[(size_t)n * INF + k] = f2bf(ldv(Wr, (long)k * C1 + n, isf));
}

// -------- prep2: W2[256][40] -> w2tb[48][256] bf16 (zero-padded) -----------
__global__ __launch_bounds__(256) void k_prep2(const void* __restrict__ Wr,
                                               const int* __restrict__ flag,
                                               ushort* __restrict__ w2tb) {
  const int n = blockIdx.x;      // 0..47
  const int k = threadIdx.x;     // 0..255
  const int isf = flag[0];
  w2tb[(size_t)n * C1 + k] = (n < NCLS) ? f2bf(ldv(Wr, (long)k * NCLS + n, isf)) : 0;
}

// -------- MFMA GEMM1 + fused elr1: h1[N,256](bf16), el1/er1[N,8] -----------
// block = 32 rows x 256 cols; wave w owns cols w*64..w*64+63 (heads 2w,2w+1)
__global__ __launch_bounds__(256) void k_gemm1m(const void* __restrict__ Xr,
                                                const ushort* __restrict__ w1tb,
                                                const void* __restrict__ alr,
                                                const void* __restrict__ arr,
                                                const int* __restrict__ flag,
                                                ushort* __restrict__ Hb,
                                                float* __restrict__ el,
                                                float* __restrict__ er) {
  __shared__ __align__(16) ushort xs[32 * 136];
  const int tid = threadIdx.x;
  const int rt  = blockIdx.x * 32;
  const int isf = flag[0];

  { // stage A: 32 rows x 128 k -> bf16 LDS
    const int r  = tid >> 4;          // 0..15
    const int c0 = (tid & 15) << 3;   // 0..120
#pragma unroll
    for (int p = 0; p < 2; ++p) {
      const int row  = r + (p << 4);
      const int grow = rt + row;
      uint4 u = make_uint4(0u, 0u, 0u, 0u);
      if (grow < NNODES) {
        if (isf) {
          const float* Xf = (const float*)Xr;
          const float4 a = *reinterpret_cast<const float4*>(Xf + (size_t)grow * INF + c0);
          const float4 b = *reinterpret_cast<const float4*>(Xf + (size_t)grow * INF + c0 + 4);
          u.x = packbf2(a.x, a.y);
          u.y = packbf2(a.z, a.w);
          u.z = packbf2(b.x, b.y);
          u.w = packbf2(b.z, b.w);
        } else {
          const ushort* Xb = (const ushort*)Xr;
          u = *reinterpret_cast<const uint4*>(Xb + (size_t)grow * INF + c0);
        }
      }
      *reinterpret_cast<uint4*>(&xs[row * 136 + c0]) = u;
    }
  }
  __syncthreads();

  const int lane = tid & 63;
  const int wv   = tid >> 6;        // 0..3
  const int n0   = wv << 6;         // wave col base
  const int col  = lane & 15;
  const int quad = lane >> 4;

  // preload all B fragments (16) and A fragments (8)
  short8v bf[16];
#pragma unroll
  for (int ct = 0; ct < 4; ++ct)
#pragma unroll
    for (int ks = 0; ks < 4; ++ks)
      bf[ct * 4 + ks] = *reinterpret_cast<const short8v*>(
          &w1tb[(size_t)(n0 + ct * 16 + col) * INF + (ks << 5) + (quad << 3)]);
  short8v af[8];
#pragma unroll
  for (int rt2 = 0; rt2 < 2; ++rt2)
#pragma unroll
    for (int ks = 0; ks < 4; ++ks)
      af[rt2 * 4 + ks] = *reinterpret_cast<const short8v*>(
          &xs[(rt2 * 16 + col) * 136 + (ks << 5) + (quad << 3)]);

  f32x4 acc[8];
#pragma unroll
  for (int i = 0; i < 8; ++i) acc[i] = (f32x4){0.f, 0.f, 0.f, 0.f};

#pragma unroll
  for (int rt2 = 0; rt2 < 2; ++rt2)
#pragma unroll
    for (int ct = 0; ct < 4; ++ct)
#pragma unroll
      for (int ks = 0; ks < 4; ++ks)
        acc[rt2 * 4 + ct] = __builtin_amdgcn_mfma_f32_16x16x32_bf16(
            af[rt2 * 4 + ks], bf[ct * 4 + ks], acc[rt2 * 4 + ct], 0, 0, 0);

  // store h1 (C layout: col=lane&15, row=quad*4+reg)
#pragma unroll
  for (int rt2 = 0; rt2 < 2; ++rt2)
#pragma unroll
    for (int ct = 0; ct < 4; ++ct)
#pragma unroll
      for (int r = 0; r < 4; ++r) {
        const int row = rt + rt2 * 16 + (quad << 2) + r;
        if (row < NNODES)
          Hb[(size_t)row * C1 + n0 + (ct << 4) + col] = f2bf(acc[rt2 * 4 + ct][r]);
      }

  // fused elr1: heads 2wv (ct 0,1) and 2wv+1 (ct 2,3); reduce over 16 cols
  float alv[4], arv[4];
#pragma unroll
  for (int ct = 0; ct < 4; ++ct) {
    alv[ct] = ldv(alr, n0 + ct * 16 + col, isf);
    arv[ct] = ldv(arr, n0 + ct * 16 + col, isf);
  }
#pragma unroll
  for (int rt2 = 0; rt2 < 2; ++rt2)
#pragma unroll
    for (int r = 0; r < 4; ++r) {
      float pl0 = acc[rt2 * 4 + 0][r] * alv[0] + acc[rt2 * 4 + 1][r] * alv[1];
      float pl1 = acc[rt2 * 4 + 2][r] * alv[2] + acc[rt2 * 4 + 3][r] * alv[3];
      float pr0 = acc[rt2 * 4 + 0][r] * arv[0] + acc[rt2 * 4 + 1][r] * arv[1];
      float pr1 = acc[rt2 * 4 + 2][r] * arv[2] + acc[rt2 * 4 + 3][r] * arv[3];
#pragma unroll
      for (int k = 1; k <= 8; k <<= 1) {
        pl0 += __shfl_xor(pl0, k, 64);
        pl1 += __shfl_xor(pl1, k, 64);
        pr0 += __shfl_xor(pr0, k, 64);
        pr1 += __shfl_xor(pr1, k, 64);
      }
      if (col == 0) {
        const int row = rt + rt2 * 16 + (quad << 2) + r;
        if (row < NNODES) {
          el[row * HEADS + 2 * wv]     = pl0;
          el[row * HEADS + 2 * wv + 1] = pl1;
          er[row * HEADS + 2 * wv]     = pr0;
          er[row * HEADS + 2 * wv + 1] = pr1;
        }
      }
    }
}

// -------- edge scores layer 1: one thread per slot, all 8 heads ------------
__global__ __launch_bounds__(256) void k_esc1(const int* __restrict__ colsrc,
                                              const int* __restrict__ coldst,
                                              const float* __restrict__ el,
                                              const float* __restrict__ er,
                                              float* __restrict__ esc) {
  const int slot = blockIdx.x * 256 + threadIdx.x;
  if (slot >= NEDGES) return;
  const int s = colsrc[slot];
  const int d = coldst[slot];
  const float4 l0 = *reinterpret_cast<const float4*>(el + (size_t)s * HEADS);
  const float4 l1 = *reinterpret_cast<const float4*>(el + (size_t)s * HEADS + 4);
  const float4 r0 = *reinterpret_cast<const float4*>(er + (size_t)d * HEADS);
  const float4 r1 = *reinterpret_cast<const float4*>(er + (size_t)d * HEADS + 4);
  float4 o0, o1;
  o0.x = __expf(lrelu(l0.x + r0.x));
  o0.y = __expf(lrelu(l0.y + r0.y));
  o0.z = __expf(lrelu(l0.z + r0.z));
  o0.w = __expf(lrelu(l0.w + r0.w));
  o1.x = __expf(lrelu(l1.x + r1.x));
  o1.y = __expf(lrelu(l1.y + r1.y));
  o1.z = __expf(lrelu(l1.z + r1.z));
  o1.w = __expf(lrelu(l1.w + r1.w));
  *reinterpret_cast<float4*>(esc + (size_t)slot * HEADS)     = o0;
  *reinterpret_cast<float4*>(esc + (size_t)slot * HEADS + 4) = o1;
}

// -------- Agg layer 1: wave per node, 4 cols/thread (uint2), 4x unroll -----
__global__ __launch_bounds__(256) void k_agg1(const int* __restrict__ rowptr,
                                              const int* __restrict__ deg,
                                              const int* __restrict__ colsrc,
                                              const float* __restrict__ esc,
                                              const ushort* __restrict__ h1b,
                                              const void* __restrict__ b1r,
                                              const int* __restrict__ flag,
                                              ushort* __restrict__ out1b) {
  const int n = blockIdx.x * 4 + (threadIdx.x >> 6);
  if (n >= NNODES) return;
  const int t  = threadIdx.x & 63;   // lane
  const int c0 = t << 2;             // 4 cols per lane
  const int h  = t >> 3;             // c0/32
  const int isf = flag[0];
  const int start = rowptr[n];
  const int cnt   = deg[n];
  const float* ep = esc + (size_t)start * HEADS + h;
  const int* cp = colsrc + start;
  float a0 = 0.f, a1 = 0.f, a2 = 0.f, a3 = 0.f, den = 0.f;
  int i = 0;
  for (; i + 4 <= cnt; i += 4) {
    const int s0 = cp[i + 0];
    const int s1 = cp[i + 1];
    const int s2 = cp[i + 2];
    const int s3 = cp[i + 3];
    const float e0 = ep[(i + 0) * HEADS];
    const float e1 = ep[(i + 1) * HEADS];
    const float e2 = ep[(i + 2) * HEADS];
    const float e3 = ep[(i + 3) * HEADS];
    const uint2 u0 = *reinterpret_cast<const uint2*>(&h1b[(size_t)s0 * C1 + c0]);
    const uint2 u1 = *reinterpret_cast<const uint2*>(&h1b[(size_t)s1 * C1 + c0]);
    const uint2 u2 = *reinterpret_cast<const uint2*>(&h1b[(size_t)s2 * C1 + c0]);
    const uint2 u3 = *reinterpret_cast<const uint2*>(&h1b[(size_t)s3 * C1 + c0]);
    den += e0 + e1 + e2 + e3;
    a0 += e0 * __uint_as_float(u0.x << 16);
    a1 += e0 * __uint_as_float(u0.x & 0xffff0000u);
    a2 += e0 * __uint_as_float(u0.y << 16);
    a3 += e0 * __uint_as_float(u0.y & 0xffff0000u);
    a0 += e1 * __uint_as_float(u1.x << 16);
    a1 += e1 * __uint_as_float(u1.x & 0xffff0000u);
    a2 += e1 * __uint_as_float(u1.y << 16);
    a3 += e1 * __uint_as_float(u1.y & 0xffff0000u);
    a0 += e2 * __uint_as_float(u2.x << 16);
    a1 += e2 * __uint_as_float(u2.x & 0xffff0000u);
    a2 += e2 * __uint_as_float(u2.y << 16);
    a3 += e2 * __uint_as_float(u2.y & 0xffff0000u);
    a0 += e3 * __uint_as_float(u3.x << 16);
    a1 += e3 * __uint_as_float(u3.x & 0xffff0000u);
    a2 += e3 * __uint_as_float(u3.y << 16);
    a3 += e3 * __uint_as_float(u3.y & 0xffff0000u);
  }
  for (; i < cnt; ++i) {
    const int s = cp[i];
    const float ex = ep[i * HEADS];
    const uint2 u = *reinterpret_cast<const uint2*>(&h1b[(size_t)s * C1 + c0]);
    den += ex;
    a0 += ex * __uint_as_float(u.x << 16);
    a1 += ex * __uint_as_float(u.x & 0xffff0000u);
    a2 += ex * __uint_as_float(u.y << 16);
    a3 += ex * __uint_as_float(u.y & 0xffff0000u);
  }
  const float inv = 1.f / fmaxf(den, 1e-9f);
  float o0 = a0 * inv + ldv(b1r, c0 + 0, isf);
  float o1 = a1 * inv + ldv(b1r, c0 + 1, isf);
  float o2 = a2 * inv + ldv(b1r, c0 + 2, isf);
  float o3 = a3 * inv + ldv(b1r, c0 + 3, isf);
  o0 = (o0 > 0.f) ? o0 : expm1f(o0);
  o1 = (o1 > 0.f) ? o1 : expm1f(o1);
  o2 = (o2 > 0.f) ? o2 : expm1f(o2);
  o3 = (o3 > 0.f) ? o3 : expm1f(o3);
  uint2 w;
  w.x = packbf2(o0, o1);
  w.y = packbf2(o2, o3);
  *reinterpret_cast<uint2*>(&out1b[(size_t)n * C1 + c0]) = w;
}

// -------- MFMA GEMM2 + fused elr2: h2[N,40](bf16), el2/er2[N] --------------
// block = 64 rows; wave w owns rows w*16..w*16+15, all 48 cols (3 col-tiles)
__global__ __launch_bounds__(256) void k_gemm2m(const ushort* __restrict__ Ab,
                                                const ushort* __restrict__ w2tb,
                                                const void* __restrict__ alr,
                                                const void* __restrict__ arr,
                                                const int* __restrict__ flag,
                                                ushort* __restrict__ Hb,
                                                float* __restrict__ el,
                                                float* __restrict__ er) {
  __shared__ __align__(16) ushort as2[64 * 264];
  const int tid = threadIdx.x;
  const int rt  = blockIdx.x * 64;
  const int isf = flag[0];

  { // stage A: 64 rows x 256 k
    const int r  = tid >> 2;           // 0..63
    const int cb = (tid & 3) << 6;     // 0,64,128,192
    const int grow = rt + r;
#pragma unroll
    for (int j = 0; j < 8; ++j) {
      uint4 u = make_uint4(0u, 0u, 0u, 0u);
      if (grow < NNODES)
        u = *reinterpret_cast<const uint4*>(Ab + (size_t)grow * C1 + cb + (j << 3));
      *reinterpret_cast<uint4*>(&as2[r * 264 + cb + (j << 3)]) = u;
    }
  }
  __syncthreads();

  const int lane = tid & 63;
  const int wv   = tid >> 6;
  const int col  = lane & 15;
  const int quad = lane >> 4;

  f32x4 acc[3];
#pragma unroll
  for (int i = 0; i < 3; ++i) acc[i] = (f32x4){0.f, 0.f, 0.f, 0.f};

#pragma unroll
  for (int ks = 0; ks < 8; ++ks) {
    const int k0 = (ks << 5) + (quad << 3);
    const short8v a = *reinterpret_cast<const short8v*>(&as2[(wv * 16 + col) * 264 + k0]);
    const short8v b0 = *reinterpret_cast<const short8v*>(&w2tb[(size_t)( 0 + col) * C1 + k0]);
    const short8v b1 = *reinterpret_cast<const short8v*>(&w2tb[(size_t)(16 + col) * C1 + k0]);
    const short8v b2 = *reinterpret_cast<const short8v*>(&w2tb[(size_t)(32 + col) * C1 + k0]);
    acc[0] = __builtin_amdgcn_mfma_f32_16x16x32_bf16(a, b0, acc[0], 0, 0, 0);
    acc[1] = __builtin_amdgcn_mfma_f32_16x16x32_bf16(a, b1, acc[1], 0, 0, 0);
    acc[2] = __builtin_amdgcn_mfma_f32_16x16x32_bf16(a, b2, acc[2], 0, 0, 0);
  }

  // store h2 (guard col < 40) + fused elr2
  float alv[3], arv[3];
#pragma unroll
  for (int ct = 0; ct < 3; ++ct) {
    const int gc = ct * 16 + col;
    alv[ct] = (gc < NCLS) ? ldv(alr, gc, isf) : 0.f;
    arv[ct] = (gc < NCLS) ? ldv(arr, gc, isf) : 0.f;
  }
#pragma unroll
  for (int r = 0; r < 4; ++r) {
    const int row = rt + wv * 16 + (quad << 2) + r;
    const bool rok = row < NNODES;
#pragma unroll
    for (int ct = 0; ct < 3; ++ct) {
      const int gc = ct * 16 + col;
      if (rok && gc < NCLS)
        Hb[(size_t)row * NCLS + gc] = f2bf(acc[ct][r]);
    }
    float pl = acc[0][r] * alv[0] + acc[1][r] * alv[1] + acc[2][r] * alv[2];
    float pr = acc[0][r] * arv[0] + acc[1][r] * arv[1] + acc[2][r] * arv[2];
#pragma unroll
    for (int k = 1; k <= 8; k <<= 1) {
      pl += __shfl_xor(pl, k, 64);
      pr += __shfl_xor(pr, k, 64);
    }
    if (col == 0 && rok) {
      el[row] = pl;
      er[row] = pr;
    }
  }
}

// -------- edge scores layer 2 ----------------------------------------------
__global__ __launch_bounds__(256) void k_esc2(const int* __restrict__ colsrc,
                                              const int* __restrict__ coldst,
                                              const float* __restrict__ el,
                                              const float* __restrict__ er,
                                              float* __restrict__ esc) {
  const int slot = blockIdx.x * 256 + threadIdx.x;
  if (slot >= NEDGES) return;
  esc[slot] = __expf(lrelu(el[colsrc[slot]] + er[coldst[slot]]));
}

// -------- Agg layer 2 (wave/node) -> f32 out -------------------------------
__global__ __launch_bounds__(256) void k_agg2(const int* __restrict__ rowptr,
                                              const int* __restrict__ deg,
                                              const int* __restrict__ colsrc,
                                              const float* __restrict__ esc,
                                              const ushort* __restrict__ h2b,
                                              const void* __restrict__ b2r,
                                              const int* __restrict__ flag,
                                              float* __restrict__ out) {
  const int t    = threadIdx.x;
  const int lane = t & 63;
  const int n    = blockIdx.x * 4 + (t >> 6);
  if (n >= NNODES) return;
  const int isf  = flag[0];
  const int start = rowptr[n];
  const int cnt   = deg[n];
  const bool act = lane < NCLS;
  float acc = 0.f, den = 0.f;
  int i = 0;
  for (; i + 4 <= cnt; i += 4) {
    const int s0 = colsrc[start + i + 0];
    const int s1 = colsrc[start + i + 1];
    const int s2 = colsrc[start + i + 2];
    const int s3 = colsrc[start + i + 3];
    const float e0 = esc[start + i + 0];
    const float e1 = esc[start + i + 1];
    const float e2 = esc[start + i + 2];
    const float e3 = esc[start + i + 3];
    const float v0 = act ? bf2f(h2b[(size_t)s0 * NCLS + lane]) : 0.f;
    const float v1 = act ? bf2f(h2b[(size_t)s1 * NCLS + lane]) : 0.f;
    const float v2 = act ? bf2f(h2b[(size_t)s2 * NCLS + lane]) : 0.f;
    const float v3 = act ? bf2f(h2b[(size_t)s3 * NCLS + lane]) : 0.f;
    den += e0 + e1 + e2 + e3;
    acc += e0 * v0 + e1 * v1 + e2 * v2 + e3 * v3;
  }
  for (; i < cnt; ++i) {
    const int s = colsrc[start + i];
    const float ex = esc[start + i];
    den += ex;
    if (act) acc += ex * bf2f(h2b[(size_t)s * NCLS + lane]);
  }
  if (act) {
    const float o = acc / fmaxf(den, 1e-9f) + ldv(b2r, lane, isf);
    out[(size_t)n * NCLS + lane] = o;
  }
}

extern "C" void kernel_launch(void* const* d_in, const int* in_sizes, int n_in,
                              void* d_out, int out_size, void* d_ws, size_t ws_size,
                              hipStream_t stream) {
  // ---- size-driven input mapping ----
  int ix = -1, iW1 = -1, iW2 = -1, e1 = -1, e2 = -1;
  int i256[3] = {-1, -1, -1}, n256 = 0;
  int i40[3]  = {-1, -1, -1}, n40 = 0;
  for (int i = 0; i < n_in; ++i) {
    switch (in_sizes[i]) {
      case 6400000: ix = i; break;
      case 800000:  if (e1 < 0) e1 = i; else e2 = i; break;
      case 32768:   iW1 = i; break;
      case 10240:   iW2 = i; break;
      case 256:     if (n256 < 3) i256[n256++] = i; break;
      case 40:      if (n40 < 3)  i40[n40++]  = i; break;
      default: break;
    }
  }
  bool mapped = (ix >= 0 && iW1 >= 0 && iW2 >= 0 && e2 >= 0 && n256 == 3 && n40 == 3);
  int isrc, idst;
  if (mapped) {
    const bool dict_order = (in_sizes[0] == 6400000);
    isrc = dict_order ? e1 : e2;
    idst = dict_order ? e2 : e1;
  } else {
    ix = 0; isrc = 1; idst = 2; iW1 = 3;
    i256[0] = 4; i256[1] = 5; i256[2] = 6;
    iW2 = 7; i40[0] = 8; i40[1] = 9; i40[2] = 10;
  }
  const void* X   = d_in[ix];
  const int*  src = (const int*)d_in[isrc];
  const int*  dst = (const int*)d_in[idst];
  const void* W1  = d_in[iW1];
  const void* al1 = d_in[i256[0]];
  const void* ar1 = d_in[i256[1]];
  const void* b1  = d_in[i256[2]];
  const void* W2  = d_in[iW2];
  const void* al2 = d_in[i40[0]];
  const void* ar2 = d_in[i40[1]];
  const void* b2  = d_in[i40[2]];

  char* ws = (char*)d_ws;
  size_t off = 0;
  auto alloc = [&](size_t bytes) -> void* {
    void* p = ws + off;
    off = (off + bytes + 255) & ~(size_t)255;
    return p;
  };
  int*    flag   = (int*)alloc(256);
  int*    deg    = (int*)alloc((size_t)NNODES * 4);
  int*    rowptr = (int*)alloc((size_t)NNODES * 4);
  int*    woff   = (int*)alloc((size_t)NNODES * 4);
  int*    bsum   = (int*)alloc(256 * 4);
  int*    boff   = (int*)alloc(256 * 4);
  int*    colsrc = (int*)alloc((size_t)NEDGES * 4);
  int*    coldst = (int*)alloc((size_t)NEDGES * 4);
  float*  el1    = (float*)alloc((size_t)NNODES * HEADS * 4);
  float*  er1    = (float*)alloc((size_t)NNODES * HEADS * 4);
  float*  el2    = (float*)alloc((size_t)NNODES * 4);
  float*  er2    = (float*)alloc((size_t)NNODES * 4);
  float*  esc1   = (float*)alloc((size_t)NEDGES * HEADS * 4);  // 25.6 MB
  float*  esc2   = (float*)alloc((size_t)NEDGES * 4);          // 3.2 MB
  ushort* w1tb   = (ushort*)alloc((size_t)C1 * INF * 2);       // 64 KB
  ushort* w2tb   = (ushort*)alloc((size_t)NCP * C1 * 2);       // 24 KB
  ushort* h1b    = (ushort*)alloc((size_t)NNODES * C1 * 2);    // 25.6 MB
  ushort* out1b  = (ushort*)alloc((size_t)NNODES * C1 * 2);    // 25.6 MB
  ushort* h2b    = (ushort*)alloc((size_t)NNODES * NCLS * 2);  // 4 MB

  const int NSB = (NNODES + 1023) / 1024;

  k_detect<<<1, 256, 0, stream>>>((const ushort*)X, flag);

  hipMemsetAsync(deg, 0, (size_t)NNODES * 4, stream);
  k_hist<<<(NEDGES + 255) / 256, 256, 0, stream>>>(dst, deg);
  k_scan1<<<NSB, 1024, 0, stream>>>(deg, rowptr, bsum);
  k_scan2<<<1, 64, 0, stream>>>(bsum, boff, NSB);
  k_scan3<<<NSB, 1024, 0, stream>>>(rowptr, woff, boff);
  k_scatter<<<(NEDGES + 255) / 256, 256, 0, stream>>>(src, dst, woff, colsrc, coldst);

  k_prep1<<<INF, 256, 0, stream>>>(W1, flag, w1tb);
  k_prep2<<<NCP, 256, 0, stream>>>(W2, flag, w2tb);

  k_gemm1m<<<(NNODES + 31) / 32, 256, 0, stream>>>(X, w1tb, al1, ar1, flag,
                                                   h1b, el1, er1);
  k_esc1<<<(NEDGES + 255) / 256, 256, 0, stream>>>(colsrc, coldst, el1, er1, esc1);
  k_agg1<<<(NNODES + 3) / 4, 256, 0, stream>>>(rowptr, deg, colsrc, esc1, h1b, b1,
                                               flag, out1b);

  k_gemm2m<<<(NNODES + 63) / 64, 256, 0, stream>>>(out1b, w2tb, al2, ar2, flag,
                                                   h2b, el2, er2);
  k_esc2<<<(NEDGES + 255) / 256, 256, 0, stream>>>(colsrc, coldst, el2, er2, esc2);
  k_agg2<<<(NNODES + 3) / 4, 256, 0, stream>>>(rowptr, deg, colsrc, esc2, h2b, b2,
                                               flag, (float*)d_out);
}

// Round 10
// 365.160 us; speedup vs baseline: 3.2166x; 1.0121x over previous
//
#include <hip/hip_runtime.h>
#include <hip/hip_bf16.h>
#include <math.h>

#define NNODES 50000
#define NEDGES 800000
#define INF    128
#define HIDD   32
#define HEADS  8
#define C1     256   // HEADS*HIDD
#define NCLS   40
#define NCP    48    // NCLS padded to 3 MFMA col-tiles

typedef unsigned int  uint;
typedef unsigned short ushort;
typedef __attribute__((ext_vector_type(8))) short short8v;   // 8 bf16 (4 VGPRs)
typedef __attribute__((ext_vector_type(4))) float f32x4;

__device__ __forceinline__ float bf2f(ushort v) {
  return __uint_as_float(((uint)v) << 16);
}
__device__ __forceinline__ ushort f2bf(float f) {
  __hip_bfloat16 b = __float2bfloat16(f);
  return *reinterpret_cast<ushort*>(&b);
}
__device__ __forceinline__ float ldv(const void* p, long i, int isf) {
  return isf ? ((const float*)p)[i] : bf2f(((const ushort*)p)[i]);
}
__device__ __forceinline__ uint packbf2(float f0, float f1) {
  return (uint)f2bf(f0) | ((uint)f2bf(f1) << 16);
}
__device__ __forceinline__ float lrelu(float x) {
  return (x >= 0.f) ? x : 0.2f * x;
}

// ---------------- dtype detection (1 wave) ----------------
__global__ __launch_bounds__(64) void k_detect(const ushort* __restrict__ xr,
                                               int* __restrict__ flag) {
  const int t = threadIdx.x;
  int c = 0;
  for (int i = t; i < 4096; i += 64) {
    const uint e = (xr[i] >> 7) & 0xFFu;
    if (e > 200u) c++;
  }
#pragma unroll
  for (int k = 32; k >= 1; k >>= 1) c += __shfl_xor(c, k, 64);
  if (t == 0) flag[0] = (c > 100) ? 1 : 0;  // 1 => inputs stored as float32
}

// ---------------- CSR build ----------------
__global__ void k_hist(const int* __restrict__ dst, int* __restrict__ deg) {
  const int e = (blockIdx.x * 256 + threadIdx.x) << 2;   // NEDGES % 4 == 0
  if (e < NEDGES) {
    const int4 d4 = *reinterpret_cast<const int4*>(dst + e);
    if ((uint)d4.x < (uint)NNODES) atomicAdd(&deg[d4.x], 1);
    if ((uint)d4.y < (uint)NNODES) atomicAdd(&deg[d4.y], 1);
    if ((uint)d4.z < (uint)NNODES) atomicAdd(&deg[d4.z], 1);
    if ((uint)d4.w < (uint)NNODES) atomicAdd(&deg[d4.w], 1);
  }
}

// wave-shuffle block scan: 2 barriers
__global__ __launch_bounds__(1024) void k_scan1(const int* __restrict__ deg,
                                                int* __restrict__ rowptr,
                                                int* __restrict__ bsum) {
  __shared__ int wsum[16];
  const int t = threadIdx.x;
  const int i = blockIdx.x * 1024 + t;
  const int lane = t & 63, wv = t >> 6;
  const int v = (i < NNODES) ? deg[i] : 0;
  int p = v;
#pragma unroll
  for (int off = 1; off < 64; off <<= 1) {
    int u = __shfl_up(p, off, 64);
    if (lane >= off) p += u;
  }
  if (lane == 63) wsum[wv] = p;   // wave totals
  __syncthreads();
  if (wv == 0) {
    int s = (lane < 16) ? wsum[lane] : 0;
#pragma unroll
    for (int off = 1; off < 16; off <<= 1) {
      int u = __shfl_up(s, off, 64);
      if (lane >= off) s += u;
    }
    if (lane < 16) wsum[lane] = s;  // inclusive wave prefix
  }
  __syncthreads();
  const int wbase = (wv > 0) ? wsum[wv - 1] : 0;
  if (i < NNODES) rowptr[i] = wbase + p - v;   // exclusive
  if (t == 1023) bsum[blockIdx.x] = wbase + p;
}

__global__ __launch_bounds__(64) void k_scan2(const int* __restrict__ bsum,
                                              int* __restrict__ boff, int nb) {
  const int lane = threadIdx.x;
  const int orig = (lane < nb) ? bsum[lane] : 0;
  int v = orig;
#pragma unroll
  for (int off = 1; off < 64; off <<= 1) {
    int u = __shfl_up(v, off, 64);
    if (lane >= off) v += u;
  }
  if (lane < nb) boff[lane] = v - orig;
}

__global__ __launch_bounds__(1024) void k_scan3(int* __restrict__ rowptr,
                                                int* __restrict__ woff,
                                                const int* __restrict__ boff) {
  int i = blockIdx.x * 1024 + threadIdx.x;
  if (i < NNODES) {
    int r = rowptr[i] + boff[blockIdx.x];
    rowptr[i] = r;
    woff[i] = r;
  }
}

__global__ void k_scatter(const int* __restrict__ src, const int* __restrict__ dst,
                          int* __restrict__ woff, int* __restrict__ colsrc,
                          int* __restrict__ coldst) {
  int e = blockIdx.x * 256 + threadIdx.x;
  if (e < NEDGES) {
    int d = dst[e];
    if ((uint)d < (uint)NNODES) {
      int pos = atomicAdd(&woff[d], 1);
      if ((uint)pos < (uint)NEDGES) {
        colsrc[pos] = src[e];
        coldst[pos] = d;
      }
    }
  }
}

// -------- prep (merged): W1 -> w1tb[256][128], W2 -> w2tb[48][256] ---------
__global__ __launch_bounds__(256) void k_prep(const void* __restrict__ W1r,
                                              const void* __restrict__ W2r,
                                              const int* __restrict__ flag,
                                              ushort* __restrict__ w1tb,
                                              ushort* __restrict__ w2tb) {
  const int b = blockIdx.x;
  const int isf = flag[0];
  if (b < INF) {
    const int k = b, n = threadIdx.x;
    w1tb[(size_t)n * INF + k] = f2bf(ldv(W1r, (long)k * C1 + n, isf));
  } else {
    const int n = b - INF, k = threadIdx.x;
    w2tb[(size_t)n * C1 + k] =
        (n < NCLS) ? f2bf(ldv(W2r, (long)k * NCLS + n, isf)) : (ushort)0;
  }
}

// -------- MFMA GEMM1 + fused elr1: h1[N,256](bf16), el1/er1[N,8] -----------
__global__ __launch_bounds__(256) void k_gemm1m(const void* __restrict__ Xr,
                                                const ushort* __restrict__ w1tb,
                                                const void* __restrict__ alr,
                                                const void* __restrict__ arr,
                                                const int* __restrict__ flag,
                                                ushort* __restrict__ Hb,
                                                float* __restrict__ el,
                                                float* __restrict__ er) {
  __shared__ __align__(16) ushort xs[32 * 136];
  const int tid = threadIdx.x;
  const int rt  = blockIdx.x * 32;
  const int isf = flag[0];

  { // stage A: 32 rows x 128 k -> bf16 LDS
    const int r  = tid >> 4;
    const int c0 = (tid & 15) << 3;
#pragma unroll
    for (int p = 0; p < 2; ++p) {
      const int row  = r + (p << 4);
      const int grow = rt + row;
      uint4 u = make_uint4(0u, 0u, 0u, 0u);
      if (grow < NNODES) {
        if (isf) {
          const float* Xf = (const float*)Xr;
          const float4 a = *reinterpret_cast<const float4*>(Xf + (size_t)grow * INF + c0);
          const float4 b = *reinterpret_cast<const float4*>(Xf + (size_t)grow * INF + c0 + 4);
          u.x = packbf2(a.x, a.y);
          u.y = packbf2(a.z, a.w);
          u.z = packbf2(b.x, b.y);
          u.w = packbf2(b.z, b.w);
        } else {
          const ushort* Xb = (const ushort*)Xr;
          u = *reinterpret_cast<const uint4*>(Xb + (size_t)grow * INF + c0);
        }
      }
      *reinterpret_cast<uint4*>(&xs[row * 136 + c0]) = u;
    }
  }
  __syncthreads();

  const int lane = tid & 63;
  const int wv   = tid >> 6;
  const int n0   = wv << 6;
  const int col  = lane & 15;
  const int quad = lane >> 4;

  short8v bf[16];
#pragma unroll
  for (int ct = 0; ct < 4; ++ct)
#pragma unroll
    for (int ks = 0; ks < 4; ++ks)
      bf[ct * 4 + ks] = *reinterpret_cast<const short8v*>(
          &w1tb[(size_t)(n0 + ct * 16 + col) * INF + (ks << 5) + (quad << 3)]);
  short8v af[8];
#pragma unroll
  for (int rt2 = 0; rt2 < 2; ++rt2)
#pragma unroll
    for (int ks = 0; ks < 4; ++ks)
      af[rt2 * 4 + ks] = *reinterpret_cast<const short8v*>(
          &xs[(rt2 * 16 + col) * 136 + (ks << 5) + (quad << 3)]);

  f32x4 acc[8];
#pragma unroll
  for (int i = 0; i < 8; ++i) acc[i] = (f32x4){0.f, 0.f, 0.f, 0.f};

#pragma unroll
  for (int rt2 = 0; rt2 < 2; ++rt2)
#pragma unroll
    for (int ct = 0; ct < 4; ++ct)
#pragma unroll
      for (int ks = 0; ks < 4; ++ks)
        acc[rt2 * 4 + ct] = __builtin_amdgcn_mfma_f32_16x16x32_bf16(
            af[rt2 * 4 + ks], bf[ct * 4 + ks], acc[rt2 * 4 + ct], 0, 0, 0);

#pragma unroll
  for (int rt2 = 0; rt2 < 2; ++rt2)
#pragma unroll
    for (int ct = 0; ct < 4; ++ct)
#pragma unroll
      for (int r = 0; r < 4; ++r) {
        const int row = rt + rt2 * 16 + (quad << 2) + r;
        if (row < NNODES)
          Hb[(size_t)row * C1 + n0 + (ct << 4) + col] = f2bf(acc[rt2 * 4 + ct][r]);
      }

  float alv[4], arv[4];
#pragma unroll
  for (int ct = 0; ct < 4; ++ct) {
    alv[ct] = ldv(alr, n0 + ct * 16 + col, isf);
    arv[ct] = ldv(arr, n0 + ct * 16 + col, isf);
  }
#pragma unroll
  for (int rt2 = 0; rt2 < 2; ++rt2)
#pragma unroll
    for (int r = 0; r < 4; ++r) {
      float pl0 = acc[rt2 * 4 + 0][r] * alv[0] + acc[rt2 * 4 + 1][r] * alv[1];
      float pl1 = acc[rt2 * 4 + 2][r] * alv[2] + acc[rt2 * 4 + 3][r] * alv[3];
      float pr0 = acc[rt2 * 4 + 0][r] * arv[0] + acc[rt2 * 4 + 1][r] * arv[1];
      float pr1 = acc[rt2 * 4 + 2][r] * arv[2] + acc[rt2 * 4 + 3][r] * arv[3];
#pragma unroll
      for (int k = 1; k <= 8; k <<= 1) {
        pl0 += __shfl_xor(pl0, k, 64);
        pl1 += __shfl_xor(pl1, k, 64);
        pr0 += __shfl_xor(pr0, k, 64);
        pr1 += __shfl_xor(pr1, k, 64);
      }
      if (col == 0) {
        const int row = rt + rt2 * 16 + (quad << 2) + r;
        if (row < NNODES) {
          el[row * HEADS + 2 * wv]     = pl0;
          el[row * HEADS + 2 * wv + 1] = pl1;
          er[row * HEADS + 2 * wv]     = pr0;
          er[row * HEADS + 2 * wv + 1] = pr1;
        }
      }
    }
}

// -------- edge scores layer 1: one thread per slot, all 8 heads ------------
__global__ __launch_bounds__(256) void k_esc1(const int* __restrict__ colsrc,
                                              const int* __restrict__ coldst,
                                              const float* __restrict__ el,
                                              const float* __restrict__ er,
                                              float* __restrict__ esc) {
  const int slot = blockIdx.x * 256 + threadIdx.x;
  if (slot >= NEDGES) return;
  const int s = colsrc[slot];
  const int d = coldst[slot];
  const float4 l0 = *reinterpret_cast<const float4*>(el + (size_t)s * HEADS);
  const float4 l1 = *reinterpret_cast<const float4*>(el + (size_t)s * HEADS + 4);
  const float4 r0 = *reinterpret_cast<const float4*>(er + (size_t)d * HEADS);
  const float4 r1 = *reinterpret_cast<const float4*>(er + (size_t)d * HEADS + 4);
  float4 o0, o1;
  o0.x = __expf(lrelu(l0.x + r0.x));
  o0.y = __expf(lrelu(l0.y + r0.y));
  o0.z = __expf(lrelu(l0.z + r0.z));
  o0.w = __expf(lrelu(l0.w + r0.w));
  o1.x = __expf(lrelu(l1.x + r1.x));
  o1.y = __expf(lrelu(l1.y + r1.y));
  o1.z = __expf(lrelu(l1.z + r1.z));
  o1.w = __expf(lrelu(l1.w + r1.w));
  *reinterpret_cast<float4*>(esc + (size_t)slot * HEADS)     = o0;
  *reinterpret_cast<float4*>(esc + (size_t)slot * HEADS + 4) = o1;
}

// -------- Agg layer 1: wave/node, 4 cols/thr, 32-bit byte offsets ----------
__global__ __launch_bounds__(256) void k_agg1(const int* __restrict__ rowptr,
                                              const int* __restrict__ deg,
                                              const int* __restrict__ colsrc,
                                              const float* __restrict__ esc,
                                              const ushort* __restrict__ h1b,
                                              const void* __restrict__ b1r,
                                              const int* __restrict__ flag,
                                              ushort* __restrict__ out1b) {
  const int n = blockIdx.x * 4 + (threadIdx.x >> 6);
  if (n >= NNODES) return;
  const int t  = threadIdx.x & 63;
  const int c0 = t << 2;             // 4 cols per lane
  const int h  = t >> 3;
  const int isf = flag[0];
  const int start = rowptr[n];
  const int cnt   = deg[n];
  const char* hp = (const char*)h1b;
  const char* ep = (const char*)esc + (uint)start * 32u + ((uint)h << 2);
  const int* cp = colsrc + start;
  const uint cb = (uint)c0 << 1;     // column byte offset within row
  float a0 = 0.f, a1 = 0.f, a2 = 0.f, a3 = 0.f, den = 0.f;
  int i = 0;
  for (; i + 4 <= cnt; i += 4) {
    const uint o0 = ((uint)cp[i + 0] << 9) | cb;
    const uint o1 = ((uint)cp[i + 1] << 9) | cb;
    const uint o2 = ((uint)cp[i + 2] << 9) | cb;
    const uint o3 = ((uint)cp[i + 3] << 9) | cb;
    const float e0 = *reinterpret_cast<const float*>(ep + (uint)(i + 0) * 32u);
    const float e1 = *reinterpret_cast<const float*>(ep + (uint)(i + 1) * 32u);
    const float e2 = *reinterpret_cast<const float*>(ep + (uint)(i + 2) * 32u);
    const float e3 = *reinterpret_cast<const float*>(ep + (uint)(i + 3) * 32u);
    const uint2 u0 = *reinterpret_cast<const uint2*>(hp + o0);
    const uint2 u1 = *reinterpret_cast<const uint2*>(hp + o1);
    const uint2 u2 = *reinterpret_cast<const uint2*>(hp + o2);
    const uint2 u3 = *reinterpret_cast<const uint2*>(hp + o3);
    den += e0 + e1 + e2 + e3;
    a0 += e0 * __uint_as_float(u0.x << 16);
    a1 += e0 * __uint_as_float(u0.x & 0xffff0000u);
    a2 += e0 * __uint_as_float(u0.y << 16);
    a3 += e0 * __uint_as_float(u0.y & 0xffff0000u);
    a0 += e1 * __uint_as_float(u1.x << 16);
    a1 += e1 * __uint_as_float(u1.x & 0xffff0000u);
    a2 += e1 * __uint_as_float(u1.y << 16);
    a3 += e1 * __uint_as_float(u1.y & 0xffff0000u);
    a0 += e2 * __uint_as_float(u2.x << 16);
    a1 += e2 * __uint_as_float(u2.x & 0xffff0000u);
    a2 += e2 * __uint_as_float(u2.y << 16);
    a3 += e2 * __uint_as_float(u2.y & 0xffff0000u);
    a0 += e3 * __uint_as_float(u3.x << 16);
    a1 += e3 * __uint_as_float(u3.x & 0xffff0000u);
    a2 += e3 * __uint_as_float(u3.y << 16);
    a3 += e3 * __uint_as_float(u3.y & 0xffff0000u);
  }
  for (; i < cnt; ++i) {
    const uint o = ((uint)cp[i] << 9) | cb;
    const float ex = *reinterpret_cast<const float*>(ep + (uint)i * 32u);
    const uint2 u = *reinterpret_cast<const uint2*>(hp + o);
    den += ex;
    a0 += ex * __uint_as_float(u.x << 16);
    a1 += ex * __uint_as_float(u.x & 0xffff0000u);
    a2 += ex * __uint_as_float(u.y << 16);
    a3 += ex * __uint_as_float(u.y & 0xffff0000u);
  }
  const float inv = 1.f / fmaxf(den, 1e-9f);
  float o0 = a0 * inv + ldv(b1r, c0 + 0, isf);
  float o1 = a1 * inv + ldv(b1r, c0 + 1, isf);
  float o2 = a2 * inv + ldv(b1r, c0 + 2, isf);
  float o3 = a3 * inv + ldv(b1r, c0 + 3, isf);
  o0 = (o0 > 0.f) ? o0 : expm1f(o0);
  o1 = (o1 > 0.f) ? o1 : expm1f(o1);
  o2 = (o2 > 0.f) ? o2 : expm1f(o2);
  o3 = (o3 > 0.f) ? o3 : expm1f(o3);
  uint2 w;
  w.x = packbf2(o0, o1);
  w.y = packbf2(o2, o3);
  *reinterpret_cast<uint2*>((char*)out1b + ((uint)n << 9) + cb) = w;
}

// -------- MFMA GEMM2 + fused elr2: h2[N,40](bf16), el2/er2[N] --------------
__global__ __launch_bounds__(256) void k_gemm2m(const ushort* __restrict__ Ab,
                                                const ushort* __restrict__ w2tb,
                                                const void* __restrict__ alr,
                                                const void* __restrict__ arr,
                                                const int* __restrict__ flag,
                                                ushort* __restrict__ Hb,
                                                float* __restrict__ el,
                                                float* __restrict__ er) {
  __shared__ __align__(16) ushort as2[64 * 264];
  const int tid = threadIdx.x;
  const int rt  = blockIdx.x * 64;
  const int isf = flag[0];

  {
    const int r  = tid >> 2;
    const int cb = (tid & 3) << 6;
    const int grow = rt + r;
#pragma unroll
    for (int j = 0; j < 8; ++j) {
      uint4 u = make_uint4(0u, 0u, 0u, 0u);
      if (grow < NNODES)
        u = *reinterpret_cast<const uint4*>(Ab + (size_t)grow * C1 + cb + (j << 3));
      *reinterpret_cast<uint4*>(&as2[r * 264 + cb + (j << 3)]) = u;
    }
  }
  __syncthreads();

  const int lane = tid & 63;
  const int wv   = tid >> 6;
  const int col  = lane & 15;
  const int quad = lane >> 4;

  f32x4 acc[3];
#pragma unroll
  for (int i = 0; i < 3; ++i) acc[i] = (f32x4){0.f, 0.f, 0.f, 0.f};

#pragma unroll
  for (int ks = 0; ks < 8; ++ks) {
    const int k0 = (ks << 5) + (quad << 3);
    const short8v a = *reinterpret_cast<const short8v*>(&as2[(wv * 16 + col) * 264 + k0]);
    const short8v b0 = *reinterpret_cast<const short8v*>(&w2tb[(size_t)( 0 + col) * C1 + k0]);
    const short8v b1 = *reinterpret_cast<const short8v*>(&w2tb[(size_t)(16 + col) * C1 + k0]);
    const short8v b2 = *reinterpret_cast<const short8v*>(&w2tb[(size_t)(32 + col) * C1 + k0]);
    acc[0] = __builtin_amdgcn_mfma_f32_16x16x32_bf16(a, b0, acc[0], 0, 0, 0);
    acc[1] = __builtin_amdgcn_mfma_f32_16x16x32_bf16(a, b1, acc[1], 0, 0, 0);
    acc[2] = __builtin_amdgcn_mfma_f32_16x16x32_bf16(a, b2, acc[2], 0, 0, 0);
  }

  float alv[3], arv[3];
#pragma unroll
  for (int ct = 0; ct < 3; ++ct) {
    const int gc = ct * 16 + col;
    alv[ct] = (gc < NCLS) ? ldv(alr, gc, isf) : 0.f;
    arv[ct] = (gc < NCLS) ? ldv(arr, gc, isf) : 0.f;
  }
#pragma unroll
  for (int r = 0; r < 4; ++r) {
    const int row = rt + wv * 16 + (quad << 2) + r;
    const bool rok = row < NNODES;
#pragma unroll
    for (int ct = 0; ct < 3; ++ct) {
      const int gc = ct * 16 + col;
      if (rok && gc < NCLS)
        Hb[(size_t)row * NCLS + gc] = f2bf(acc[ct][r]);
    }
    float pl = acc[0][r] * alv[0] + acc[1][r] * alv[1] + acc[2][r] * alv[2];
    float pr = acc[0][r] * arv[0] + acc[1][r] * arv[1] + acc[2][r] * arv[2];
#pragma unroll
    for (int k = 1; k <= 8; k <<= 1) {
      pl += __shfl_xor(pl, k, 64);
      pr += __shfl_xor(pr, k, 64);
    }
    if (col == 0 && rok) {
      el[row] = pl;
      er[row] = pr;
    }
  }
}

// -------- Agg layer 2 (wave/node, fused scores, 32-bit offsets) ------------
__global__ __launch_bounds__(256) void k_agg2(const int* __restrict__ rowptr,
                                              const int* __restrict__ deg,
                                              const int* __restrict__ colsrc,
                                              const float* __restrict__ el,
                                              const float* __restrict__ er,
                                              const ushort* __restrict__ h2b,
                                              const void* __restrict__ b2r,
                                              const int* __restrict__ flag,
                                              float* __restrict__ out) {
  const int t    = threadIdx.x;
  const int lane = t & 63;
  const int n    = blockIdx.x * 4 + (t >> 6);
  if (n >= NNODES) return;
  const int isf  = flag[0];
  const int start = rowptr[n];
  const int cnt   = deg[n];
  const float ern = er[n];
  const bool act = lane < NCLS;
  const char* hp = (const char*)h2b;
  const uint lb = (uint)lane << 1;
  const int* cp = colsrc + start;
  float acc = 0.f, den = 0.f;
  int i = 0;
  for (; i + 4 <= cnt; i += 4) {
    const int s0 = cp[i + 0];
    const int s1 = cp[i + 1];
    const int s2 = cp[i + 2];
    const int s3 = cp[i + 3];
    const float l0 = el[s0];
    const float l1 = el[s1];
    const float l2 = el[s2];
    const float l3 = el[s3];
    const float v0 = act ? bf2f(*reinterpret_cast<const ushort*>(hp + (uint)s0 * 80u + lb)) : 0.f;
    const float v1 = act ? bf2f(*reinterpret_cast<const ushort*>(hp + (uint)s1 * 80u + lb)) : 0.f;
    const float v2 = act ? bf2f(*reinterpret_cast<const ushort*>(hp + (uint)s2 * 80u + lb)) : 0.f;
    const float v3 = act ? bf2f(*reinterpret_cast<const ushort*>(hp + (uint)s3 * 80u + lb)) : 0.f;
    const float e0 = __expf(lrelu(l0 + ern));
    const float e1 = __expf(lrelu(l1 + ern));
    const float e2 = __expf(lrelu(l2 + ern));
    const float e3 = __expf(lrelu(l3 + ern));
    den += e0 + e1 + e2 + e3;
    acc += e0 * v0 + e1 * v1 + e2 * v2 + e3 * v3;
  }
  for (; i < cnt; ++i) {
    const int s = cp[i];
    const float ex = __expf(lrelu(el[s] + ern));
    den += ex;
    if (act) acc += ex * bf2f(*reinterpret_cast<const ushort*>(hp + (uint)s * 80u + lb));
  }
  if (act) {
    const float o = acc / fmaxf(den, 1e-9f) + ldv(b2r, lane, isf);
    out[(size_t)n * NCLS + lane] = o;
  }
}

extern "C" void kernel_launch(void* const* d_in, const int* in_sizes, int n_in,
                              void* d_out, int out_size, void* d_ws, size_t ws_size,
                              hipStream_t stream) {
  // ---- size-driven input mapping ----
  int ix = -1, iW1 = -1, iW2 = -1, e1 = -1, e2 = -1;
  int i256[3] = {-1, -1, -1}, n256 = 0;
  int i40[3]  = {-1, -1, -1}, n40 = 0;
  for (int i = 0; i < n_in; ++i) {
    switch (in_sizes[i]) {
      case 6400000: ix = i; break;
      case 800000:  if (e1 < 0) e1 = i; else e2 = i; break;
      case 32768:   iW1 = i; break;
      case 10240:   iW2 = i; break;
      case 256:     if (n256 < 3) i256[n256++] = i; break;
      case 40:      if (n40 < 3)  i40[n40++]  = i; break;
      default: break;
    }
  }
  bool mapped = (ix >= 0 && iW1 >= 0 && iW2 >= 0 && e2 >= 0 && n256 == 3 && n40 == 3);
  int isrc, idst;
  if (mapped) {
    const bool dict_order = (in_sizes[0] == 6400000);
    isrc = dict_order ? e1 : e2;
    idst = dict_order ? e2 : e1;
  } else {
    ix = 0; isrc = 1; idst = 2; iW1 = 3;
    i256[0] = 4; i256[1] = 5; i256[2] = 6;
    iW2 = 7; i40[0] = 8; i40[1] = 9; i40[2] = 10;
  }
  const void* X   = d_in[ix];
  const int*  src = (const int*)d_in[isrc];
  const int*  dst = (const int*)d_in[idst];
  const void* W1  = d_in[iW1];
  const void* al1 = d_in[i256[0]];
  const void* ar1 = d_in[i256[1]];
  const void* b1  = d_in[i256[2]];
  const void* W2  = d_in[iW2];
  const void* al2 = d_in[i40[0]];
  const void* ar2 = d_in[i40[1]];
  const void* b2  = d_in[i40[2]];

  char* ws = (char*)d_ws;
  size_t off = 0;
  auto alloc = [&](size_t bytes) -> void* {
    void* p = ws + off;
    off = (off + bytes + 255) & ~(size_t)255;
    return p;
  };
  int*    flag   = (int*)alloc(256);
  int*    deg    = (int*)alloc((size_t)NNODES * 4);
  int*    rowptr = (int*)alloc((size_t)NNODES * 4);
  int*    woff   = (int*)alloc((size_t)NNODES * 4);
  int*    bsum   = (int*)alloc(256 * 4);
  int*    boff   = (int*)alloc(256 * 4);
  int*    colsrc = (int*)alloc((size_t)NEDGES * 4);
  int*    coldst = (int*)alloc((size_t)NEDGES * 4);
  float*  el1    = (float*)alloc((size_t)NNODES * HEADS * 4);
  float*  er1    = (float*)alloc((size_t)NNODES * HEADS * 4);
  float*  el2    = (float*)alloc((size_t)NNODES * 4);
  float*  er2    = (float*)alloc((size_t)NNODES * 4);
  float*  esc1   = (float*)alloc((size_t)NEDGES * HEADS * 4);  // 25.6 MB
  ushort* w1tb   = (ushort*)alloc((size_t)C1 * INF * 2);
  ushort* w2tb   = (ushort*)alloc((size_t)NCP * C1 * 2);
  ushort* h1b    = (ushort*)alloc((size_t)NNODES * C1 * 2);    // 25.6 MB
  ushort* out1b  = (ushort*)alloc((size_t)NNODES * C1 * 2);    // 25.6 MB
  ushort* h2b    = (ushort*)alloc((size_t)NNODES * NCLS * 2);  // 4 MB

  const int NSB = (NNODES + 1023) / 1024;

  k_detect<<<1, 64, 0, stream>>>((const ushort*)X, flag);

  hipMemsetAsync(deg, 0, (size_t)NNODES * 4, stream);
  k_hist<<<(NEDGES / 4 + 255) / 256, 256, 0, stream>>>(dst, deg);
  k_scan1<<<NSB, 1024, 0, stream>>>(deg, rowptr, bsum);
  k_scan2<<<1, 64, 0, stream>>>(bsum, boff, NSB);
  k_scan3<<<NSB, 1024, 0, stream>>>(rowptr, woff, boff);
  k_scatter<<<(NEDGES + 255) / 256, 256, 0, stream>>>(src, dst, woff, colsrc, coldst);

  k_prep<<<INF + NCP, 256, 0, stream>>>(W1, W2, flag, w1tb, w2tb);

  k_gemm1m<<<(NNODES + 31) / 32, 256, 0, stream>>>(X, w1tb, al1, ar1, flag,
                                                   h1b, el1, er1);
  k_esc1<<<(NEDGES + 255) / 256, 256, 0, stream>>>(colsrc, coldst, el1, er1, esc1);
  k_agg1<<<(NNODES + 3) / 4, 256, 0, stream>>>(rowptr, deg, colsrc, esc1, h1b, b1,
                                               flag, out1b);

  k_gemm2m<<<(NNODES + 63) / 64, 256, 0, stream>>>(out1b, w2tb, al2, ar2, flag,
                                                   h2b, el2, er2);
  k_agg2<<<(NNODES + 3) / 4, 256, 0, stream>>>(rowptr, deg, colsrc, el2, er2, h2b, b2,
                                               flag, (float*)d_out);
}

// Round 11
// 360.808 us; speedup vs baseline: 3.2554x; 1.0121x over previous
//
#include <hip/hip_runtime.h>
#include <hip/hip_bf16.h>
#include <math.h>

#define NNODES 50000
#define NEDGES 800000
#define INF    128
#define HIDD   32
#define HEADS  8
#define C1     256   // HEADS*HIDD
#define NCLS   40
#define NCP    48    // NCLS padded to 3 MFMA col-tiles

typedef unsigned int  uint;
typedef unsigned short ushort;
typedef __attribute__((ext_vector_type(8))) short short8v;   // 8 bf16 (4 VGPRs)
typedef __attribute__((ext_vector_type(4))) float f32x4;

__device__ __forceinline__ float bf2f(ushort v) {
  return __uint_as_float(((uint)v) << 16);
}
__device__ __forceinline__ ushort f2bf(float f) {
  __hip_bfloat16 b = __float2bfloat16(f);
  return *reinterpret_cast<ushort*>(&b);
}
__device__ __forceinline__ float ldv(const void* p, long i, int isf) {
  return isf ? ((const float*)p)[i] : bf2f(((const ushort*)p)[i]);
}
__device__ __forceinline__ uint packbf2(float f0, float f1) {
  return (uint)f2bf(f0) | ((uint)f2bf(f1) << 16);
}
__device__ __forceinline__ float lrelu(float x) {
  return (x >= 0.f) ? x : 0.2f * x;
}

// ---------------- dtype detection (1 wave) ----------------
__global__ __launch_bounds__(64) void k_detect(const ushort* __restrict__ xr,
                                               int* __restrict__ flag) {
  const int t = threadIdx.x;
  int c = 0;
  for (int i = t; i < 4096; i += 64) {
    const uint e = (xr[i] >> 7) & 0xFFu;
    if (e > 200u) c++;
  }
#pragma unroll
  for (int k = 32; k >= 1; k >>= 1) c += __shfl_xor(c, k, 64);
  if (t == 0) flag[0] = (c > 100) ? 1 : 0;  // 1 => inputs stored as float32
}

// ---------------- CSR build ----------------
__global__ void k_hist(const int* __restrict__ dst, int* __restrict__ deg) {
  const int e = (blockIdx.x * 256 + threadIdx.x) << 2;   // NEDGES % 4 == 0
  if (e < NEDGES) {
    const int4 d4 = *reinterpret_cast<const int4*>(dst + e);
    if ((uint)d4.x < (uint)NNODES) atomicAdd(&deg[d4.x], 1);
    if ((uint)d4.y < (uint)NNODES) atomicAdd(&deg[d4.y], 1);
    if ((uint)d4.z < (uint)NNODES) atomicAdd(&deg[d4.z], 1);
    if ((uint)d4.w < (uint)NNODES) atomicAdd(&deg[d4.w], 1);
  }
}

// wave-shuffle block scan: 2 barriers
__global__ __launch_bounds__(1024) void k_scan1(const int* __restrict__ deg,
                                                int* __restrict__ rowptr,
                                                int* __restrict__ bsum) {
  __shared__ int wsum[16];
  const int t = threadIdx.x;
  const int i = blockIdx.x * 1024 + t;
  const int lane = t & 63, wv = t >> 6;
  const int v = (i < NNODES) ? deg[i] : 0;
  int p = v;
#pragma unroll
  for (int off = 1; off < 64; off <<= 1) {
    int u = __shfl_up(p, off, 64);
    if (lane >= off) p += u;
  }
  if (lane == 63) wsum[wv] = p;
  __syncthreads();
  if (wv == 0) {
    int s = (lane < 16) ? wsum[lane] : 0;
#pragma unroll
    for (int off = 1; off < 16; off <<= 1) {
      int u = __shfl_up(s, off, 64);
      if (lane >= off) s += u;
    }
    if (lane < 16) wsum[lane] = s;
  }
  __syncthreads();
  const int wbase = (wv > 0) ? wsum[wv - 1] : 0;
  if (i < NNODES) rowptr[i] = wbase + p - v;
  if (t == 1023) bsum[blockIdx.x] = wbase + p;
}

// scan3 with fused scan2: wave 0 re-scans block sums (nb <= 64)
__global__ __launch_bounds__(1024) void k_scan3(int* __restrict__ rowptr,
                                                int* __restrict__ woff,
                                                const int* __restrict__ bsum,
                                                int nb) {
  __shared__ int base_s;
  const int t = threadIdx.x;
  if (t < 64) {
    const int v = (t < nb) ? bsum[t] : 0;
    int p = v;
#pragma unroll
    for (int off = 1; off < 64; off <<= 1) {
      int u = __shfl_up(p, off, 64);
      if (t >= off) p += u;
    }
    if (t == (int)blockIdx.x) base_s = p - v;   // exclusive prefix
  }
  __syncthreads();
  const int i = blockIdx.x * 1024 + t;
  if (i < NNODES) {
    const int r = rowptr[i] + base_s;
    rowptr[i] = r;
    woff[i] = r;
  }
}

__global__ void k_scatter(const int* __restrict__ src, const int* __restrict__ dst,
                          int* __restrict__ woff, int* __restrict__ colsrc,
                          int* __restrict__ coldst) {
  int e = blockIdx.x * 256 + threadIdx.x;
  if (e < NEDGES) {
    int d = dst[e];
    if ((uint)d < (uint)NNODES) {
      int pos = atomicAdd(&woff[d], 1);
      if ((uint)pos < (uint)NEDGES) {
        colsrc[pos] = src[e];
        coldst[pos] = d;
      }
    }
  }
}

// -------- prep (merged): W1 -> w1tb[256][128], W2 -> w2tb[48][256] ---------
__global__ __launch_bounds__(256) void k_prep(const void* __restrict__ W1r,
                                              const void* __restrict__ W2r,
                                              const int* __restrict__ flag,
                                              ushort* __restrict__ w1tb,
                                              ushort* __restrict__ w2tb) {
  const int b = blockIdx.x;
  const int isf = flag[0];
  if (b < INF) {
    const int k = b, n = threadIdx.x;
    w1tb[(size_t)n * INF + k] = f2bf(ldv(W1r, (long)k * C1 + n, isf));
  } else {
    const int n = b - INF, k = threadIdx.x;
    w2tb[(size_t)n * C1 + k] =
        (n < NCLS) ? f2bf(ldv(W2r, (long)k * NCLS + n, isf)) : (ushort)0;
  }
}

// -------- MFMA GEMM1 + fused elr1: h1[N,256](bf16), el1/er1[N,8] -----------
__global__ __launch_bounds__(256) void k_gemm1m(const void* __restrict__ Xr,
                                                const ushort* __restrict__ w1tb,
                                                const void* __restrict__ alr,
                                                const void* __restrict__ arr,
                                                const int* __restrict__ flag,
                                                ushort* __restrict__ Hb,
                                                float* __restrict__ el,
                                                float* __restrict__ er) {
  __shared__ __align__(16) ushort xs[32 * 136];
  const int tid = threadIdx.x;
  const int rt  = blockIdx.x * 32;
  const int isf = flag[0];

  {
    const int r  = tid >> 4;
    const int c0 = (tid & 15) << 3;
#pragma unroll
    for (int p = 0; p < 2; ++p) {
      const int row  = r + (p << 4);
      const int grow = rt + row;
      uint4 u = make_uint4(0u, 0u, 0u, 0u);
      if (grow < NNODES) {
        if (isf) {
          const float* Xf = (const float*)Xr;
          const float4 a = *reinterpret_cast<const float4*>(Xf + (size_t)grow * INF + c0);
          const float4 b = *reinterpret_cast<const float4*>(Xf + (size_t)grow * INF + c0 + 4);
          u.x = packbf2(a.x, a.y);
          u.y = packbf2(a.z, a.w);
          u.z = packbf2(b.x, b.y);
          u.w = packbf2(b.z, b.w);
        } else {
          const ushort* Xb = (const ushort*)Xr;
          u = *reinterpret_cast<const uint4*>(Xb + (size_t)grow * INF + c0);
        }
      }
      *reinterpret_cast<uint4*>(&xs[row * 136 + c0]) = u;
    }
  }
  __syncthreads();

  const int lane = tid & 63;
  const int wv   = tid >> 6;
  const int n0   = wv << 6;
  const int col  = lane & 15;
  const int quad = lane >> 4;

  short8v bf[16];
#pragma unroll
  for (int ct = 0; ct < 4; ++ct)
#pragma unroll
    for (int ks = 0; ks < 4; ++ks)
      bf[ct * 4 + ks] = *reinterpret_cast<const short8v*>(
          &w1tb[(size_t)(n0 + ct * 16 + col) * INF + (ks << 5) + (quad << 3)]);
  short8v af[8];
#pragma unroll
  for (int rt2 = 0; rt2 < 2; ++rt2)
#pragma unroll
    for (int ks = 0; ks < 4; ++ks)
      af[rt2 * 4 + ks] = *reinterpret_cast<const short8v*>(
          &xs[(rt2 * 16 + col) * 136 + (ks << 5) + (quad << 3)]);

  f32x4 acc[8];
#pragma unroll
  for (int i = 0; i < 8; ++i) acc[i] = (f32x4){0.f, 0.f, 0.f, 0.f};

#pragma unroll
  for (int rt2 = 0; rt2 < 2; ++rt2)
#pragma unroll
    for (int ct = 0; ct < 4; ++ct)
#pragma unroll
      for (int ks = 0; ks < 4; ++ks)
        acc[rt2 * 4 + ct] = __builtin_amdgcn_mfma_f32_16x16x32_bf16(
            af[rt2 * 4 + ks], bf[ct * 4 + ks], acc[rt2 * 4 + ct], 0, 0, 0);

#pragma unroll
  for (int rt2 = 0; rt2 < 2; ++rt2)
#pragma unroll
    for (int ct = 0; ct < 4; ++ct)
#pragma unroll
      for (int r = 0; r < 4; ++r) {
        const int row = rt + rt2 * 16 + (quad << 2) + r;
        if (row < NNODES)
          Hb[(size_t)row * C1 + n0 + (ct << 4) + col] = f2bf(acc[rt2 * 4 + ct][r]);
      }

  float alv[4], arv[4];
#pragma unroll
  for (int ct = 0; ct < 4; ++ct) {
    alv[ct] = ldv(alr, n0 + ct * 16 + col, isf);
    arv[ct] = ldv(arr, n0 + ct * 16 + col, isf);
  }
#pragma unroll
  for (int rt2 = 0; rt2 < 2; ++rt2)
#pragma unroll
    for (int r = 0; r < 4; ++r) {
      float pl0 = acc[rt2 * 4 + 0][r] * alv[0] + acc[rt2 * 4 + 1][r] * alv[1];
      float pl1 = acc[rt2 * 4 + 2][r] * alv[2] + acc[rt2 * 4 + 3][r] * alv[3];
      float pr0 = acc[rt2 * 4 + 0][r] * arv[0] + acc[rt2 * 4 + 1][r] * arv[1];
      float pr1 = acc[rt2 * 4 + 2][r] * arv[2] + acc[rt2 * 4 + 3][r] * arv[3];
#pragma unroll
      for (int k = 1; k <= 8; k <<= 1) {
        pl0 += __shfl_xor(pl0, k, 64);
        pl1 += __shfl_xor(pl1, k, 64);
        pr0 += __shfl_xor(pr0, k, 64);
        pr1 += __shfl_xor(pr1, k, 64);
      }
      if (col == 0) {
        const int row = rt + rt2 * 16 + (quad << 2) + r;
        if (row < NNODES) {
          el[row * HEADS + 2 * wv]     = pl0;
          el[row * HEADS + 2 * wv + 1] = pl1;
          er[row * HEADS + 2 * wv]     = pr0;
          er[row * HEADS + 2 * wv + 1] = pr1;
        }
      }
    }
}

// -------- Agg layer 1: wave/node, 4 cols/thr, fused exp, 8x unroll ---------
__global__ __launch_bounds__(256) void k_agg1(const int* __restrict__ rowptr,
                                              const int* __restrict__ deg,
                                              const int* __restrict__ colsrc,
                                              const float* __restrict__ el,
                                              const float* __restrict__ er,
                                              const ushort* __restrict__ h1b,
                                              const void* __restrict__ b1r,
                                              const int* __restrict__ flag,
                                              ushort* __restrict__ out1b) {
  const int n = blockIdx.x * 4 + (threadIdx.x >> 6);
  if (n >= NNODES) return;
  const int t  = threadIdx.x & 63;
  const int c0 = t << 2;             // 4 cols per lane
  const int h  = t >> 3;
  const int isf = flag[0];
  const int start = rowptr[n];
  const int cnt   = deg[n];
  const char* hp  = (const char*)h1b;
  const char* elp = (const char*)el;
  const float ern = er[n * HEADS + h];
  const int* cp = colsrc + start;
  const uint cb = (uint)c0 << 1;
  const uint hb = (uint)h << 2;
  float a0 = 0.f, a1 = 0.f, a2 = 0.f, a3 = 0.f, den = 0.f;
  int i = 0;
  for (; i + 8 <= cnt; i += 8) {
    int s[8];
#pragma unroll
    for (int j = 0; j < 8; ++j) s[j] = cp[i + j];
    float l[8];
#pragma unroll
    for (int j = 0; j < 8; ++j)
      l[j] = *reinterpret_cast<const float*>(elp + (((uint)s[j] << 5) | hb));
    uint2 u[8];
#pragma unroll
    for (int j = 0; j < 8; ++j)
      u[j] = *reinterpret_cast<const uint2*>(hp + (((uint)s[j] << 9) | cb));
#pragma unroll
    for (int j = 0; j < 8; ++j) {
      const float e = __expf(lrelu(l[j] + ern));
      den += e;
      a0 += e * __uint_as_float(u[j].x << 16);
      a1 += e * __uint_as_float(u[j].x & 0xffff0000u);
      a2 += e * __uint_as_float(u[j].y << 16);
      a3 += e * __uint_as_float(u[j].y & 0xffff0000u);
    }
  }
  for (; i < cnt; ++i) {
    const int s = cp[i];
    const float l = *reinterpret_cast<const float*>(elp + (((uint)s << 5) | hb));
    const uint2 u = *reinterpret_cast<const uint2*>(hp + (((uint)s << 9) | cb));
    const float e = __expf(lrelu(l + ern));
    den += e;
    a0 += e * __uint_as_float(u.x << 16);
    a1 += e * __uint_as_float(u.x & 0xffff0000u);
    a2 += e * __uint_as_float(u.y << 16);
    a3 += e * __uint_as_float(u.y & 0xffff0000u);
  }
  const float inv = 1.f / fmaxf(den, 1e-9f);
  float o0 = a0 * inv + ldv(b1r, c0 + 0, isf);
  float o1 = a1 * inv + ldv(b1r, c0 + 1, isf);
  float o2 = a2 * inv + ldv(b1r, c0 + 2, isf);
  float o3 = a3 * inv + ldv(b1r, c0 + 3, isf);
  o0 = (o0 > 0.f) ? o0 : expm1f(o0);
  o1 = (o1 > 0.f) ? o1 : expm1f(o1);
  o2 = (o2 > 0.f) ? o2 : expm1f(o2);
  o3 = (o3 > 0.f) ? o3 : expm1f(o3);
  uint2 w;
  w.x = packbf2(o0, o1);
  w.y = packbf2(o2, o3);
  *reinterpret_cast<uint2*>((char*)out1b + ((uint)n << 9) + cb) = w;
}

// -------- MFMA GEMM2 + fused elr2: h2[N,40](bf16), el2/er2[N] --------------
__global__ __launch_bounds__(256) void k_gemm2m(const ushort* __restrict__ Ab,
                                                const ushort* __restrict__ w2tb,
                                                const void* __restrict__ alr,
                                                const void* __restrict__ arr,
                                                const int* __restrict__ flag,
                                                ushort* __restrict__ Hb,
                                                float* __restrict__ el,
                                                float* __restrict__ er) {
  __shared__ __align__(16) ushort as2[64 * 264];
  const int tid = threadIdx.x;
  const int rt  = blockIdx.x * 64;
  const int isf = flag[0];

  {
    const int r  = tid >> 2;
    const int cb = (tid & 3) << 6;
    const int grow = rt + r;
#pragma unroll
    for (int j = 0; j < 8; ++j) {
      uint4 u = make_uint4(0u, 0u, 0u, 0u);
      if (grow < NNODES)
        u = *reinterpret_cast<const uint4*>(Ab + (size_t)grow * C1 + cb + (j << 3));
      *reinterpret_cast<uint4*>(&as2[r * 264 + cb + (j << 3)]) = u;
    }
  }
  __syncthreads();

  const int lane = tid & 63;
  const int wv   = tid >> 6;
  const int col  = lane & 15;
  const int quad = lane >> 4;

  f32x4 acc[3];
#pragma unroll
  for (int i = 0; i < 3; ++i) acc[i] = (f32x4){0.f, 0.f, 0.f, 0.f};

#pragma unroll
  for (int ks = 0; ks < 8; ++ks) {
    const int k0 = (ks << 5) + (quad << 3);
    const short8v a = *reinterpret_cast<const short8v*>(&as2[(wv * 16 + col) * 264 + k0]);
    const short8v b0 = *reinterpret_cast<const short8v*>(&w2tb[(size_t)( 0 + col) * C1 + k0]);
    const short8v b1 = *reinterpret_cast<const short8v*>(&w2tb[(size_t)(16 + col) * C1 + k0]);
    const short8v b2 = *reinterpret_cast<const short8v*>(&w2tb[(size_t)(32 + col) * C1 + k0]);
    acc[0] = __builtin_amdgcn_mfma_f32_16x16x32_bf16(a, b0, acc[0], 0, 0, 0);
    acc[1] = __builtin_amdgcn_mfma_f32_16x16x32_bf16(a, b1, acc[1], 0, 0, 0);
    acc[2] = __builtin_amdgcn_mfma_f32_16x16x32_bf16(a, b2, acc[2], 0, 0, 0);
  }

  float alv[3], arv[3];
#pragma unroll
  for (int ct = 0; ct < 3; ++ct) {
    const int gc = ct * 16 + col;
    alv[ct] = (gc < NCLS) ? ldv(alr, gc, isf) : 0.f;
    arv[ct] = (gc < NCLS) ? ldv(arr, gc, isf) : 0.f;
  }
#pragma unroll
  for (int r = 0; r < 4; ++r) {
    const int row = rt + wv * 16 + (quad << 2) + r;
    const bool rok = row < NNODES;
#pragma unroll
    for (int ct = 0; ct < 3; ++ct) {
      const int gc = ct * 16 + col;
      if (rok && gc < NCLS)
        Hb[(size_t)row * NCLS + gc] = f2bf(acc[ct][r]);
    }
    float pl = acc[0][r] * alv[0] + acc[1][r] * alv[1] + acc[2][r] * alv[2];
    float pr = acc[0][r] * arv[0] + acc[1][r] * arv[1] + acc[2][r] * arv[2];
#pragma unroll
    for (int k = 1; k <= 8; k <<= 1) {
      pl += __shfl_xor(pl, k, 64);
      pr += __shfl_xor(pr, k, 64);
    }
    if (col == 0 && rok) {
      el[row] = pl;
      er[row] = pr;
    }
  }
}

// -------- Agg layer 2 (wave/node, fused scores, 8x unroll) -----------------
__global__ __launch_bounds__(256) void k_agg2(const int* __restrict__ rowptr,
                                              const int* __restrict__ deg,
                                              const int* __restrict__ colsrc,
                                              const float* __restrict__ el,
                                              const float* __restrict__ er,
                                              const ushort* __restrict__ h2b,
                                              const void* __restrict__ b2r,
                                              const int* __restrict__ flag,
                                              float* __restrict__ out) {
  const int t    = threadIdx.x;
  const int lane = t & 63;
  const int n    = blockIdx.x * 4 + (t >> 6);
  if (n >= NNODES) return;
  const int isf  = flag[0];
  const int start = rowptr[n];
  const int cnt   = deg[n];
  const float ern = er[n];
  const bool act = lane < NCLS;
  const char* hp = (const char*)h2b;
  const uint lb = (uint)lane << 1;
  const int* cp = colsrc + start;
  float acc = 0.f, den = 0.f;
  int i = 0;
  for (; i + 8 <= cnt; i += 8) {
    int s[8];
#pragma unroll
    for (int j = 0; j < 8; ++j) s[j] = cp[i + j];
    float l[8];
#pragma unroll
    for (int j = 0; j < 8; ++j) l[j] = el[s[j]];
    float v[8];
#pragma unroll
    for (int j = 0; j < 8; ++j)
      v[j] = act ? bf2f(*reinterpret_cast<const ushort*>(hp + (uint)s[j] * 80u + lb)) : 0.f;
#pragma unroll
    for (int j = 0; j < 8; ++j) {
      const float e = __expf(lrelu(l[j] + ern));
      den += e;
      acc += e * v[j];
    }
  }
  for (; i < cnt; ++i) {
    const int s = cp[i];
    const float ex = __expf(lrelu(el[s] + ern));
    den += ex;
    if (act) acc += ex * bf2f(*reinterpret_cast<const ushort*>(hp + (uint)s * 80u + lb));
  }
  if (act) {
    const float o = acc / fmaxf(den, 1e-9f) + ldv(b2r, lane, isf);
    out[(size_t)n * NCLS + lane] = o;
  }
}

extern "C" void kernel_launch(void* const* d_in, const int* in_sizes, int n_in,
                              void* d_out, int out_size, void* d_ws, size_t ws_size,
                              hipStream_t stream) {
  // ---- size-driven input mapping ----
  int ix = -1, iW1 = -1, iW2 = -1, e1 = -1, e2 = -1;
  int i256[3] = {-1, -1, -1}, n256 = 0;
  int i40[3]  = {-1, -1, -1}, n40 = 0;
  for (int i = 0; i < n_in; ++i) {
    switch (in_sizes[i]) {
      case 6400000: ix = i; break;
      case 800000:  if (e1 < 0) e1 = i; else e2 = i; break;
      case 32768:   iW1 = i; break;
      case 10240:   iW2 = i; break;
      case 256:     if (n256 < 3) i256[n256++] = i; break;
      case 40:      if (n40 < 3)  i40[n40++]  = i; break;
      default: break;
    }
  }
  bool mapped = (ix >= 0 && iW1 >= 0 && iW2 >= 0 && e2 >= 0 && n256 == 3 && n40 == 3);
  int isrc, idst;
  if (mapped) {
    const bool dict_order = (in_sizes[0] == 6400000);
    isrc = dict_order ? e1 : e2;
    idst = dict_order ? e2 : e1;
  } else {
    ix = 0; isrc = 1; idst = 2; iW1 = 3;
    i256[0] = 4; i256[1] = 5; i256[2] = 6;
    iW2 = 7; i40[0] = 8; i40[1] = 9; i40[2] = 10;
  }
  const void* X   = d_in[ix];
  const int*  src = (const int*)d_in[isrc];
  const int*  dst = (const int*)d_in[idst];
  const void* W1  = d_in[iW1];
  const void* al1 = d_in[i256[0]];
  const void* ar1 = d_in[i256[1]];
  const void* b1  = d_in[i256[2]];
  const void* W2  = d_in[iW2];
  const void* al2 = d_in[i40[0]];
  const void* ar2 = d_in[i40[1]];
  const void* b2  = d_in[i40[2]];

  char* ws = (char*)d_ws;
  size_t off = 0;
  auto alloc = [&](size_t bytes) -> void* {
    void* p = ws + off;
    off = (off + bytes + 255) & ~(size_t)255;
    return p;
  };
  int*    flag   = (int*)alloc(256);
  int*    deg    = (int*)alloc((size_t)NNODES * 4);
  int*    rowptr = (int*)alloc((size_t)NNODES * 4);
  int*    woff   = (int*)alloc((size_t)NNODES * 4);
  int*    bsum   = (int*)alloc(256 * 4);
  int*    colsrc = (int*)alloc((size_t)NEDGES * 4);
  int*    coldst = (int*)alloc((size_t)NEDGES * 4);
  float*  el1    = (float*)alloc((size_t)NNODES * HEADS * 4);
  float*  er1    = (float*)alloc((size_t)NNODES * HEADS * 4);
  float*  el2    = (float*)alloc((size_t)NNODES * 4);
  float*  er2    = (float*)alloc((size_t)NNODES * 4);
  ushort* w1tb   = (ushort*)alloc((size_t)C1 * INF * 2);
  ushort* w2tb   = (ushort*)alloc((size_t)NCP * C1 * 2);
  ushort* h1b    = (ushort*)alloc((size_t)NNODES * C1 * 2);    // 25.6 MB
  ushort* out1b  = (ushort*)alloc((size_t)NNODES * C1 * 2);    // 25.6 MB
  ushort* h2b    = (ushort*)alloc((size_t)NNODES * NCLS * 2);  // 4 MB

  const int NSB = (NNODES + 1023) / 1024;

  k_detect<<<1, 64, 0, stream>>>((const ushort*)X, flag);

  hipMemsetAsync(deg, 0, (size_t)NNODES * 4, stream);
  k_hist<<<(NEDGES / 4 + 255) / 256, 256, 0, stream>>>(dst, deg);
  k_scan1<<<NSB, 1024, 0, stream>>>(deg, rowptr, bsum);
  k_scan3<<<NSB, 1024, 0, stream>>>(rowptr, woff, bsum, NSB);
  k_scatter<<<(NEDGES + 255) / 256, 256, 0, stream>>>(src, dst, woff, colsrc, coldst);

  k_prep<<<INF + NCP, 256, 0, stream>>>(W1, W2, flag, w1tb, w2tb);

  k_gemm1m<<<(NNODES + 31) / 32, 256, 0, stream>>>(X, w1tb, al1, ar1, flag,
                                                   h1b, el1, er1);
  k_agg1<<<(NNODES + 3) / 4, 256, 0, stream>>>(rowptr, deg, colsrc, el1, er1,
                                               h1b, b1, flag, out1b);

  k_gemm2m<<<(NNODES + 63) / 64, 256, 0, stream>>>(out1b, w2tb, al2, ar2, flag,
                                                   h2b, el2, er2);
  k_agg2<<<(NNODES + 3) / 4, 256, 0, stream>>>(rowptr, deg, colsrc, el2, er2,
                                               h2b, b2, flag, (float*)d_out);
}

// Round 12
// 318.925 us; speedup vs baseline: 3.6830x; 1.1313x over previous
//
#include <hip/hip_runtime.h>
#include <hip/hip_bf16.h>
#include <math.h>

#define NNODES 50000
#define NEDGES 800000
#define INF    128
#define HIDD   32
#define HEADS  8
#define C1     256   // HEADS*HIDD
#define NCLS   40
#define NCP    48    // NCLS padded to 3 MFMA col-tiles

typedef unsigned int  uint;
typedef unsigned short ushort;
typedef __attribute__((ext_vector_type(8))) short short8v;   // 8 bf16 (4 VGPRs)
typedef __attribute__((ext_vector_type(4))) float f32x4;

__device__ __forceinline__ float bf2f(ushort v) {
  return __uint_as_float(((uint)v) << 16);
}
__device__ __forceinline__ ushort f2bf(float f) {
  __hip_bfloat16 b = __float2bfloat16(f);
  return *reinterpret_cast<ushort*>(&b);
}
__device__ __forceinline__ float ldv(const void* p, long i, int isf) {
  return isf ? ((const float*)p)[i] : bf2f(((const ushort*)p)[i]);
}
__device__ __forceinline__ uint packbf2(float f0, float f1) {
  return (uint)f2bf(f0) | ((uint)f2bf(f1) << 16);
}
__device__ __forceinline__ float lrelu(float x) {
  return (x >= 0.f) ? x : 0.2f * x;
}

// -------- init: zero deg + dtype detect (block 0) --------------------------
__global__ __launch_bounds__(256) void k_init(const ushort* __restrict__ xr,
                                              int* __restrict__ flag,
                                              int* __restrict__ deg) {
  const int g = blockIdx.x * 256 + threadIdx.x;
  if (g < NNODES) deg[g] = 0;
  if (blockIdx.x == 0 && threadIdx.x < 64) {
    const int t = threadIdx.x;
    int c = 0;
    for (int i = t; i < 4096; i += 64) {
      const uint e = (xr[i] >> 7) & 0xFFu;
      if (e > 200u) c++;
    }
#pragma unroll
    for (int k = 32; k >= 1; k >>= 1) c += __shfl_xor(c, k, 64);
    if (t == 0) flag[0] = (c > 100) ? 1 : 0;  // 1 => inputs stored as float32
  }
}

// -------- hist: count degrees AND record per-edge rank ---------------------
__global__ void k_hist(const int* __restrict__ dst, int* __restrict__ deg,
                       int* __restrict__ erank) {
  const int e = (blockIdx.x * 256 + threadIdx.x) << 2;   // NEDGES % 4 == 0
  if (e < NEDGES) {
    const int4 d4 = *reinterpret_cast<const int4*>(dst + e);
    int4 r4;
    r4.x = atomicAdd(&deg[d4.x], 1);
    r4.y = atomicAdd(&deg[d4.y], 1);
    r4.z = atomicAdd(&deg[d4.z], 1);
    r4.w = atomicAdd(&deg[d4.w], 1);
    *reinterpret_cast<int4*>(erank + e) = r4;
  }
}

// wave-shuffle block scan: 2 barriers
__global__ __launch_bounds__(1024) void k_scan1(const int* __restrict__ deg,
                                                int* __restrict__ rowptr,
                                                int* __restrict__ bsum) {
  __shared__ int wsum[16];
  const int t = threadIdx.x;
  const int i = blockIdx.x * 1024 + t;
  const int lane = t & 63, wv = t >> 6;
  const int v = (i < NNODES) ? deg[i] : 0;
  int p = v;
#pragma unroll
  for (int off = 1; off < 64; off <<= 1) {
    int u = __shfl_up(p, off, 64);
    if (lane >= off) p += u;
  }
  if (lane == 63) wsum[wv] = p;
  __syncthreads();
  if (wv == 0) {
    int s = (lane < 16) ? wsum[lane] : 0;
#pragma unroll
    for (int off = 1; off < 16; off <<= 1) {
      int u = __shfl_up(s, off, 64);
      if (lane >= off) s += u;
    }
    if (lane < 16) wsum[lane] = s;
  }
  __syncthreads();
  const int wbase = (wv > 0) ? wsum[wv - 1] : 0;
  if (i < NNODES) rowptr[i] = wbase + p - v;
  if (t == 1023) bsum[blockIdx.x] = wbase + p;
}

// scan3 with fused scan2: wave 0 re-scans block sums (nb <= 64)
__global__ __launch_bounds__(1024) void k_scan3(int* __restrict__ rowptr,
                                                const int* __restrict__ bsum,
                                                int nb) {
  __shared__ int base_s;
  const int t = threadIdx.x;
  if (t < 64) {
    const int v = (t < nb) ? bsum[t] : 0;
    int p = v;
#pragma unroll
    for (int off = 1; off < 64; off <<= 1) {
      int u = __shfl_up(p, off, 64);
      if (t >= off) p += u;
    }
    if (t == (int)blockIdx.x) base_s = p - v;   // exclusive prefix
  }
  __syncthreads();
  const int i = blockIdx.x * 1024 + t;
  if (i < NNODES) rowptr[i] += base_s;
}

// -------- scatter: NO atomics — slot = rowptr[dst] + erank -----------------
__global__ void k_scatter(const int* __restrict__ src, const int* __restrict__ dst,
                          const int* __restrict__ rowptr,
                          const int* __restrict__ erank,
                          int* __restrict__ colsrc) {
  const int e = (blockIdx.x * 256 + threadIdx.x) << 2;
  if (e < NEDGES) {
    const int4 s4 = *reinterpret_cast<const int4*>(src + e);
    const int4 d4 = *reinterpret_cast<const int4*>(dst + e);
    const int4 r4 = *reinterpret_cast<const int4*>(erank + e);
    colsrc[rowptr[d4.x] + r4.x] = s4.x;
    colsrc[rowptr[d4.y] + r4.y] = s4.y;
    colsrc[rowptr[d4.z] + r4.z] = s4.z;
    colsrc[rowptr[d4.w] + r4.w] = s4.w;
  }
}

// -------- prep (merged): W1 -> w1tb[256][128], W2 -> w2tb[48][256] ---------
__global__ __launch_bounds__(256) void k_prep(const void* __restrict__ W1r,
                                              const void* __restrict__ W2r,
                                              const int* __restrict__ flag,
                                              ushort* __restrict__ w1tb,
                                              ushort* __restrict__ w2tb) {
  const int b = blockIdx.x;
  const int isf = flag[0];
  if (b < INF) {
    const int k = b, n = threadIdx.x;
    w1tb[(size_t)n * INF + k] = f2bf(ldv(W1r, (long)k * C1 + n, isf));
  } else {
    const int n = b - INF, k = threadIdx.x;
    w2tb[(size_t)n * C1 + k] =
        (n < NCLS) ? f2bf(ldv(W2r, (long)k * NCLS + n, isf)) : (ushort)0;
  }
}

// -------- MFMA GEMM1 + fused elr1: h1[N,256](bf16), el1/er1[N,8] -----------
__global__ __launch_bounds__(256) void k_gemm1m(const void* __restrict__ Xr,
                                                const ushort* __restrict__ w1tb,
                                                const void* __restrict__ alr,
                                                const void* __restrict__ arr,
                                                const int* __restrict__ flag,
                                                ushort* __restrict__ Hb,
                                                float* __restrict__ el,
                                                float* __restrict__ er) {
  __shared__ __align__(16) ushort xs[32 * 136];
  const int tid = threadIdx.x;
  const int rt  = blockIdx.x * 32;
  const int isf = flag[0];

  {
    const int r  = tid >> 4;
    const int c0 = (tid & 15) << 3;
#pragma unroll
    for (int p = 0; p < 2; ++p) {
      const int row  = r + (p << 4);
      const int grow = rt + row;
      uint4 u = make_uint4(0u, 0u, 0u, 0u);
      if (grow < NNODES) {
        if (isf) {
          const float* Xf = (const float*)Xr;
          const float4 a = *reinterpret_cast<const float4*>(Xf + (size_t)grow * INF + c0);
          const float4 b = *reinterpret_cast<const float4*>(Xf + (size_t)grow * INF + c0 + 4);
          u.x = packbf2(a.x, a.y);
          u.y = packbf2(a.z, a.w);
          u.z = packbf2(b.x, b.y);
          u.w = packbf2(b.z, b.w);
        } else {
          const ushort* Xb = (const ushort*)Xr;
          u = *reinterpret_cast<const uint4*>(Xb + (size_t)grow * INF + c0);
        }
      }
      *reinterpret_cast<uint4*>(&xs[row * 136 + c0]) = u;
    }
  }
  __syncthreads();

  const int lane = tid & 63;
  const int wv   = tid >> 6;
  const int n0   = wv << 6;
  const int col  = lane & 15;
  const int quad = lane >> 4;

  short8v bf[16];
#pragma unroll
  for (int ct = 0; ct < 4; ++ct)
#pragma unroll
    for (int ks = 0; ks < 4; ++ks)
      bf[ct * 4 + ks] = *reinterpret_cast<const short8v*>(
          &w1tb[(size_t)(n0 + ct * 16 + col) * INF + (ks << 5) + (quad << 3)]);
  short8v af[8];
#pragma unroll
  for (int rt2 = 0; rt2 < 2; ++rt2)
#pragma unroll
    for (int ks = 0; ks < 4; ++ks)
      af[rt2 * 4 + ks] = *reinterpret_cast<const short8v*>(
          &xs[(rt2 * 16 + col) * 136 + (ks << 5) + (quad << 3)]);

  f32x4 acc[8];
#pragma unroll
  for (int i = 0; i < 8; ++i) acc[i] = (f32x4){0.f, 0.f, 0.f, 0.f};

#pragma unroll
  for (int rt2 = 0; rt2 < 2; ++rt2)
#pragma unroll
    for (int ct = 0; ct < 4; ++ct)
#pragma unroll
      for (int ks = 0; ks < 4; ++ks)
        acc[rt2 * 4 + ct] = __builtin_amdgcn_mfma_f32_16x16x32_bf16(
            af[rt2 * 4 + ks], bf[ct * 4 + ks], acc[rt2 * 4 + ct], 0, 0, 0);

#pragma unroll
  for (int rt2 = 0; rt2 < 2; ++rt2)
#pragma unroll
    for (int ct = 0; ct < 4; ++ct)
#pragma unroll
      for (int r = 0; r < 4; ++r) {
        const int row = rt + rt2 * 16 + (quad << 2) + r;
        if (row < NNODES)
          Hb[(size_t)row * C1 + n0 + (ct << 4) + col] = f2bf(acc[rt2 * 4 + ct][r]);
      }

  float alv[4], arv[4];
#pragma unroll
  for (int ct = 0; ct < 4; ++ct) {
    alv[ct] = ldv(alr, n0 + ct * 16 + col, isf);
    arv[ct] = ldv(arr, n0 + ct * 16 + col, isf);
  }
#pragma unroll
  for (int rt2 = 0; rt2 < 2; ++rt2)
#pragma unroll
    for (int r = 0; r < 4; ++r) {
      float pl0 = acc[rt2 * 4 + 0][r] * alv[0] + acc[rt2 * 4 + 1][r] * alv[1];
      float pl1 = acc[rt2 * 4 + 2][r] * alv[2] + acc[rt2 * 4 + 3][r] * alv[3];
      float pr0 = acc[rt2 * 4 + 0][r] * arv[0] + acc[rt2 * 4 + 1][r] * arv[1];
      float pr1 = acc[rt2 * 4 + 2][r] * arv[2] + acc[rt2 * 4 + 3][r] * arv[3];
#pragma unroll
      for (int k = 1; k <= 8; k <<= 1) {
        pl0 += __shfl_xor(pl0, k, 64);
        pl1 += __shfl_xor(pl1, k, 64);
        pr0 += __shfl_xor(pr0, k, 64);
        pr1 += __shfl_xor(pr1, k, 64);
      }
      if (col == 0) {
        const int row = rt + rt2 * 16 + (quad << 2) + r;
        if (row < NNODES) {
          el[row * HEADS + 2 * wv]     = pl0;
          el[row * HEADS + 2 * wv + 1] = pl1;
          er[row * HEADS + 2 * wv]     = pr0;
          er[row * HEADS + 2 * wv + 1] = pr1;
        }
      }
    }
}

// -------- Agg layer 1: wave/node, 4 cols/thr, fused exp, 8x unroll ---------
__global__ __launch_bounds__(256) void k_agg1(const int* __restrict__ rowptr,
                                              const int* __restrict__ deg,
                                              const int* __restrict__ colsrc,
                                              const float* __restrict__ el,
                                              const float* __restrict__ er,
                                              const ushort* __restrict__ h1b,
                                              const void* __restrict__ b1r,
                                              const int* __restrict__ flag,
                                              ushort* __restrict__ out1b) {
  const int n = blockIdx.x * 4 + (threadIdx.x >> 6);
  if (n >= NNODES) return;
  const int t  = threadIdx.x & 63;
  const int c0 = t << 2;             // 4 cols per lane
  const int h  = t >> 3;
  const int isf = flag[0];
  const int start = rowptr[n];
  const int cnt   = deg[n];
  const char* hp  = (const char*)h1b;
  const char* elp = (const char*)el;
  const float ern = er[n * HEADS + h];
  const int* cp = colsrc + start;
  const uint cb = (uint)c0 << 1;
  const uint hb = (uint)h << 2;
  float a0 = 0.f, a1 = 0.f, a2 = 0.f, a3 = 0.f, den = 0.f;
  int i = 0;
  for (; i + 8 <= cnt; i += 8) {
    int s[8];
#pragma unroll
    for (int j = 0; j < 8; ++j) s[j] = cp[i + j];
    float l[8];
#pragma unroll
    for (int j = 0; j < 8; ++j)
      l[j] = *reinterpret_cast<const float*>(elp + (((uint)s[j] << 5) | hb));
    uint2 u[8];
#pragma unroll
    for (int j = 0; j < 8; ++j)
      u[j] = *reinterpret_cast<const uint2*>(hp + (((uint)s[j] << 9) | cb));
#pragma unroll
    for (int j = 0; j < 8; ++j) {
      const float e = __expf(lrelu(l[j] + ern));
      den += e;
      a0 += e * __uint_as_float(u[j].x << 16);
      a1 += e * __uint_as_float(u[j].x & 0xffff0000u);
      a2 += e * __uint_as_float(u[j].y << 16);
      a3 += e * __uint_as_float(u[j].y & 0xffff0000u);
    }
  }
  for (; i < cnt; ++i) {
    const int s = cp[i];
    const float l = *reinterpret_cast<const float*>(elp + (((uint)s << 5) | hb));
    const uint2 u = *reinterpret_cast<const uint2*>(hp + (((uint)s << 9) | cb));
    const float e = __expf(lrelu(l + ern));
    den += e;
    a0 += e * __uint_as_float(u.x << 16);
    a1 += e * __uint_as_float(u.x & 0xffff0000u);
    a2 += e * __uint_as_float(u.y << 16);
    a3 += e * __uint_as_float(u.y & 0xffff0000u);
  }
  const float inv = 1.f / fmaxf(den, 1e-9f);
  float o0 = a0 * inv + ldv(b1r, c0 + 0, isf);
  float o1 = a1 * inv + ldv(b1r, c0 + 1, isf);
  float o2 = a2 * inv + ldv(b1r, c0 + 2, isf);
  float o3 = a3 * inv + ldv(b1r, c0 + 3, isf);
  o0 = (o0 > 0.f) ? o0 : expm1f(o0);
  o1 = (o1 > 0.f) ? o1 : expm1f(o1);
  o2 = (o2 > 0.f) ? o2 : expm1f(o2);
  o3 = (o3 > 0.f) ? o3 : expm1f(o3);
  uint2 w;
  w.x = packbf2(o0, o1);
  w.y = packbf2(o2, o3);
  *reinterpret_cast<uint2*>((char*)out1b + ((uint)n << 9) + cb) = w;
}

// -------- MFMA GEMM2 + fused elr2: h2[N,40](bf16), el2/er2[N] --------------
__global__ __launch_bounds__(256) void k_gemm2m(const ushort* __restrict__ Ab,
                                                const ushort* __restrict__ w2tb,
                                                const void* __restrict__ alr,
                                                const void* __restrict__ arr,
                                                const int* __restrict__ flag,
                                                ushort* __restrict__ Hb,
                                                float* __restrict__ el,
                                                float* __restrict__ er) {
  __shared__ __align__(16) ushort as2[64 * 264];
  const int tid = threadIdx.x;
  const int rt  = blockIdx.x * 64;
  const int isf = flag[0];

  {
    const int r  = tid >> 2;
    const int cb = (tid & 3) << 6;
    const int grow = rt + r;
#pragma unroll
    for (int j = 0; j < 8; ++j) {
      uint4 u = make_uint4(0u, 0u, 0u, 0u);
      if (grow < NNODES)
        u = *reinterpret_cast<const uint4*>(Ab + (size_t)grow * C1 + cb + (j << 3));
      *reinterpret_cast<uint4*>(&as2[r * 264 + cb + (j << 3)]) = u;
    }
  }
  __syncthreads();

  const int lane = tid & 63;
  const int wv   = tid >> 6;
  const int col  = lane & 15;
  const int quad = lane >> 4;

  f32x4 acc[3];
#pragma unroll
  for (int i = 0; i < 3; ++i) acc[i] = (f32x4){0.f, 0.f, 0.f, 0.f};

#pragma unroll
  for (int ks = 0; ks < 8; ++ks) {
    const int k0 = (ks << 5) + (quad << 3);
    const short8v a = *reinterpret_cast<const short8v*>(&as2[(wv * 16 + col) * 264 + k0]);
    const short8v b0 = *reinterpret_cast<const short8v*>(&w2tb[(size_t)( 0 + col) * C1 + k0]);
    const short8v b1 = *reinterpret_cast<const short8v*>(&w2tb[(size_t)(16 + col) * C1 + k0]);
    const short8v b2 = *reinterpret_cast<const short8v*>(&w2tb[(size_t)(32 + col) * C1 + k0]);
    acc[0] = __builtin_amdgcn_mfma_f32_16x16x32_bf16(a, b0, acc[0], 0, 0, 0);
    acc[1] = __builtin_amdgcn_mfma_f32_16x16x32_bf16(a, b1, acc[1], 0, 0, 0);
    acc[2] = __builtin_amdgcn_mfma_f32_16x16x32_bf16(a, b2, acc[2], 0, 0, 0);
  }

  float alv[3], arv[3];
#pragma unroll
  for (int ct = 0; ct < 3; ++ct) {
    const int gc = ct * 16 + col;
    alv[ct] = (gc < NCLS) ? ldv(alr, gc, isf) : 0.f;
    arv[ct] = (gc < NCLS) ? ldv(arr, gc, isf) : 0.f;
  }
#pragma unroll
  for (int r = 0; r < 4; ++r) {
    const int row = rt + wv * 16 + (quad << 2) + r;
    const bool rok = row < NNODES;
#pragma unroll
    for (int ct = 0; ct < 3; ++ct) {
      const int gc = ct * 16 + col;
      if (rok && gc < NCLS)
        Hb[(size_t)row * NCLS + gc] = f2bf(acc[ct][r]);
    }
    float pl = acc[0][r] * alv[0] + acc[1][r] * alv[1] + acc[2][r] * alv[2];
    float pr = acc[0][r] * arv[0] + acc[1][r] * arv[1] + acc[2][r] * arv[2];
#pragma unroll
    for (int k = 1; k <= 8; k <<= 1) {
      pl += __shfl_xor(pl, k, 64);
      pr += __shfl_xor(pr, k, 64);
    }
    if (col == 0 && rok) {
      el[row] = pl;
      er[row] = pr;
    }
  }
}

// -------- Agg layer 2 (wave/node, fused scores, 8x unroll) -----------------
__global__ __launch_bounds__(256) void k_agg2(const int* __restrict__ rowptr,
                                              const int* __restrict__ deg,
                                              const int* __restrict__ colsrc,
                                              const float* __restrict__ el,
                                              const float* __restrict__ er,
                                              const ushort* __restrict__ h2b,
                                              const void* __restrict__ b2r,
                                              const int* __restrict__ flag,
                                              float* __restrict__ out) {
  const int t    = threadIdx.x;
  const int lane = t & 63;
  const int n    = blockIdx.x * 4 + (t >> 6);
  if (n >= NNODES) return;
  const int isf  = flag[0];
  const int start = rowptr[n];
  const int cnt   = deg[n];
  const float ern = er[n];
  const bool act = lane < NCLS;
  const char* hp = (const char*)h2b;
  const uint lb = (uint)lane << 1;
  const int* cp = colsrc + start;
  float acc = 0.f, den = 0.f;
  int i = 0;
  for (; i + 8 <= cnt; i += 8) {
    int s[8];
#pragma unroll
    for (int j = 0; j < 8; ++j) s[j] = cp[i + j];
    float l[8];
#pragma unroll
    for (int j = 0; j < 8; ++j) l[j] = el[s[j]];
    float v[8];
#pragma unroll
    for (int j = 0; j < 8; ++j)
      v[j] = act ? bf2f(*reinterpret_cast<const ushort*>(hp + (uint)s[j] * 80u + lb)) : 0.f;
#pragma unroll
    for (int j = 0; j < 8; ++j) {
      const float e = __expf(lrelu(l[j] + ern));
      den += e;
      acc += e * v[j];
    }
  }
  for (; i < cnt; ++i) {
    const int s = cp[i];
    const float ex = __expf(lrelu(el[s] + ern));
    den += ex;
    if (act) acc += ex * bf2f(*reinterpret_cast<const ushort*>(hp + (uint)s * 80u + lb));
  }
  if (act) {
    const float o = acc / fmaxf(den, 1e-9f) + ldv(b2r, lane, isf);
    out[(size_t)n * NCLS + lane] = o;
  }
}

extern "C" void kernel_launch(void* const* d_in, const int* in_sizes, int n_in,
                              void* d_out, int out_size, void* d_ws, size_t ws_size,
                              hipStream_t stream) {
  // ---- size-driven input mapping ----
  int ix = -1, iW1 = -1, iW2 = -1, e1 = -1, e2 = -1;
  int i256[3] = {-1, -1, -1}, n256 = 0;
  int i40[3]  = {-1, -1, -1}, n40 = 0;
  for (int i = 0; i < n_in; ++i) {
    switch (in_sizes[i]) {
      case 6400000: ix = i; break;
      case 800000:  if (e1 < 0) e1 = i; else e2 = i; break;
      case 32768:   iW1 = i; break;
      case 10240:   iW2 = i; break;
      case 256:     if (n256 < 3) i256[n256++] = i; break;
      case 40:      if (n40 < 3)  i40[n40++]  = i; break;
      default: break;
    }
  }
  bool mapped = (ix >= 0 && iW1 >= 0 && iW2 >= 0 && e2 >= 0 && n256 == 3 && n40 == 3);
  int isrc, idst;
  if (mapped) {
    const bool dict_order = (in_sizes[0] == 6400000);
    isrc = dict_order ? e1 : e2;
    idst = dict_order ? e2 : e1;
  } else {
    ix = 0; isrc = 1; idst = 2; iW1 = 3;
    i256[0] = 4; i256[1] = 5; i256[2] = 6;
    iW2 = 7; i40[0] = 8; i40[1] = 9; i40[2] = 10;
  }
  const void* X   = d_in[ix];
  const int*  src = (const int*)d_in[isrc];
  const int*  dst = (const int*)d_in[idst];
  const void* W1  = d_in[iW1];
  const void* al1 = d_in[i256[0]];
  const void* ar1 = d_in[i256[1]];
  const void* b1  = d_in[i256[2]];
  const void* W2  = d_in[iW2];
  const void* al2 = d_in[i40[0]];
  const void* ar2 = d_in[i40[1]];
  const void* b2  = d_in[i40[2]];

  char* ws = (char*)d_ws;
  size_t off = 0;
  auto alloc = [&](size_t bytes) -> void* {
    void* p = ws + off;
    off = (off + bytes + 255) & ~(size_t)255;
    return p;
  };
  int*    flag   = (int*)alloc(256);
  int*    deg    = (int*)alloc((size_t)NNODES * 4);
  int*    rowptr = (int*)alloc((size_t)NNODES * 4);
  int*    bsum   = (int*)alloc(256 * 4);
  int*    erank  = (int*)alloc((size_t)NEDGES * 4);
  int*    colsrc = (int*)alloc((size_t)NEDGES * 4);
  float*  el1    = (float*)alloc((size_t)NNODES * HEADS * 4);
  float*  er1    = (float*)alloc((size_t)NNODES * HEADS * 4);
  float*  el2    = (float*)alloc((size_t)NNODES * 4);
  float*  er2    = (float*)alloc((size_t)NNODES * 4);
  ushort* w1tb   = (ushort*)alloc((size_t)C1 * INF * 2);
  ushort* w2tb   = (ushort*)alloc((size_t)NCP * C1 * 2);
  ushort* h1b    = (ushort*)alloc((size_t)NNODES * C1 * 2);    // 25.6 MB
  ushort* out1b  = (ushort*)alloc((size_t)NNODES * C1 * 2);    // 25.6 MB
  ushort* h2b    = (ushort*)alloc((size_t)NNODES * NCLS * 2);  // 4 MB

  const int NSB = (NNODES + 1023) / 1024;

  k_init<<<(NNODES + 255) / 256, 256, 0, stream>>>((const ushort*)X, flag, deg);
  k_hist<<<(NEDGES / 4 + 255) / 256, 256, 0, stream>>>(dst, deg, erank);
  k_scan1<<<NSB, 1024, 0, stream>>>(deg, rowptr, bsum);
  k_scan3<<<NSB, 1024, 0, stream>>>(rowptr, bsum, NSB);
  k_scatter<<<(NEDGES / 4 + 255) / 256, 256, 0, stream>>>(src, dst, rowptr, erank, colsrc);

  k_prep<<<INF + NCP, 256, 0, stream>>>(W1, W2, flag, w1tb, w2tb);

  k_gemm1m<<<(NNODES + 31) / 32, 256, 0, stream>>>(X, w1tb, al1, ar1, flag,
                                                   h1b, el1, er1);
  k_agg1<<<(NNODES + 3) / 4, 256, 0, stream>>>(rowptr, deg, colsrc, el1, er1,
                                               h1b, b1, flag, out1b);

  k_gemm2m<<<(NNODES + 63) / 64, 256, 0, stream>>>(out1b, w2tb, al2, ar2, flag,
                                                   h2b, el2, er2);
  k_agg2<<<(NNODES + 3) / 4, 256, 0, stream>>>(rowptr, deg, colsrc, el2, er2,
                                               h2b, b2, flag, (float*)d_out);
}

// Round 13
// 293.158 us; speedup vs baseline: 4.0067x; 1.0879x over previous
//
#include <hip/hip_runtime.h>
#include <hip/hip_bf16.h>
#include <math.h>

#define NNODES 50000
#define NEDGES 800000
#define INF    128
#define HIDD   32
#define HEADS  8
#define C1     256   // HEADS*HIDD
#define NCLS   40
#define NCP    48    // NCLS padded to 3 MFMA col-tiles
#define NSB    49    // scan blocks: ceil(50000/1024)
#define SCB    ((NEDGES / 4 + 255) / 256)   // scatter blocks

typedef unsigned int  uint;
typedef unsigned short ushort;
typedef __attribute__((ext_vector_type(8))) short short8v;   // 8 bf16 (4 VGPRs)
typedef __attribute__((ext_vector_type(4))) float f32x4;

__device__ __forceinline__ float bf2f(ushort v) {
  return __uint_as_float(((uint)v) << 16);
}
__device__ __forceinline__ ushort f2bf(float f) {
  __hip_bfloat16 b = __float2bfloat16(f);
  return *reinterpret_cast<ushort*>(&b);
}
__device__ __forceinline__ float ldv(const void* p, long i, int isf) {
  return isf ? ((const float*)p)[i] : bf2f(((const ushort*)p)[i]);
}
__device__ __forceinline__ uint packbf2(float f0, float f1) {
  return (uint)f2bf(f0) | ((uint)f2bf(f1) << 16);
}
__device__ __forceinline__ float lrelu(float x) {
  return fmaxf(x, 0.2f * x);   // exact for all x (slope<1)
}

// -------- init: zero deg + scan flags + dtype detect -----------------------
__global__ __launch_bounds__(256) void k_init(const ushort* __restrict__ xr,
                                              int* __restrict__ flag,
                                              int* __restrict__ deg,
                                              int* __restrict__ aggf) {
  const int g = blockIdx.x * 256 + threadIdx.x;
  if (g < NNODES) deg[g] = 0;
  if (g < 64) aggf[g] = 0;
  if (blockIdx.x == 0 && threadIdx.x < 64) {
    const int t = threadIdx.x;
    int c = 0;
    for (int i = t; i < 4096; i += 64) {
      const uint e = (xr[i] >> 7) & 0xFFu;
      if (e > 200u) c++;
    }
#pragma unroll
    for (int k = 32; k >= 1; k >>= 1) c += __shfl_xor(c, k, 64);
    if (t == 0) flag[0] = (c > 100) ? 1 : 0;  // 1 => inputs stored as float32
  }
}

// -------- hist: count degrees AND record per-edge rank ---------------------
__global__ void k_hist(const int* __restrict__ dst, int* __restrict__ deg,
                       int* __restrict__ erank) {
  const int e = (blockIdx.x * 256 + threadIdx.x) << 2;   // NEDGES % 4 == 0
  if (e < NEDGES) {
    const int4 d4 = *reinterpret_cast<const int4*>(dst + e);
    int4 r4;
    r4.x = atomicAdd(&deg[d4.x], 1);
    r4.y = atomicAdd(&deg[d4.y], 1);
    r4.z = atomicAdd(&deg[d4.z], 1);
    r4.w = atomicAdd(&deg[d4.w], 1);
    *reinterpret_cast<int4*>(erank + e) = r4;
  }
}

// -------- single-pass scan: publish aggregates, lookback-sum ---------------
// All NSB=49 blocks are co-resident (49 << 256 CUs) => no deadlock.
__global__ __launch_bounds__(1024) void k_scan(const int* __restrict__ deg,
                                               int* __restrict__ rowptr,
                                               int* __restrict__ aggf) {
  __shared__ int wsum[16];
  __shared__ int base_s;
  const int b = blockIdx.x, t = threadIdx.x;
  const int i = b * 1024 + t;
  const int lane = t & 63, wv = t >> 6;
  const int v = (i < NNODES) ? deg[i] : 0;
  int p = v;
#pragma unroll
  for (int off = 1; off < 64; off <<= 1) {
    int u = __shfl_up(p, off, 64);
    if (lane >= off) p += u;
  }
  if (lane == 63) wsum[wv] = p;
  __syncthreads();
  if (wv == 0) {
    int s = (lane < 16) ? wsum[lane] : 0;
#pragma unroll
    for (int off = 1; off < 16; off <<= 1) {
      int u = __shfl_up(s, off, 64);
      if (lane >= off) s += u;
    }
    if (lane < 16) wsum[lane] = s;
  }
  __syncthreads();
  if (t == 0) atomicExch(&aggf[b], wsum[15] + 1);   // publish total (+1 sentinel)
  if (t < 64) {
    int sum = 0;
    for (int j = lane; j < b; j += 64) {
      int a;
      while ((a = atomicAdd(&aggf[j], 0)) == 0) __builtin_amdgcn_s_sleep(8);
      sum += a - 1;
    }
#pragma unroll
    for (int k = 32; k >= 1; k >>= 1) sum += __shfl_xor(sum, k, 64);
    if (lane == 0) base_s = sum;
  }
  __syncthreads();
  const int wbase = (wv > 0) ? wsum[wv - 1] : 0;
  if (i < NNODES) rowptr[i] = base_s + wbase + p - v;   // exclusive
}

// -------- scatter (atomic-free) ∥ prep (weight transpose), role-split ------
__global__ __launch_bounds__(256) void k_scatprep(
    const int* __restrict__ src, const int* __restrict__ dst,
    const int* __restrict__ rowptr, const int* __restrict__ erank,
    int* __restrict__ colsrc,
    const void* __restrict__ W1r, const void* __restrict__ W2r,
    const int* __restrict__ flag,
    ushort* __restrict__ w1tb, ushort* __restrict__ w2tb) {
  const int b = blockIdx.x;
  if (b < SCB) {
    const int e = (b * 256 + threadIdx.x) << 2;
    if (e < NEDGES) {
      const int4 s4 = *reinterpret_cast<const int4*>(src + e);
      const int4 d4 = *reinterpret_cast<const int4*>(dst + e);
      const int4 r4 = *reinterpret_cast<const int4*>(erank + e);
      colsrc[rowptr[d4.x] + r4.x] = s4.x;
      colsrc[rowptr[d4.y] + r4.y] = s4.y;
      colsrc[rowptr[d4.z] + r4.z] = s4.z;
      colsrc[rowptr[d4.w] + r4.w] = s4.w;
    }
  } else {
    const int pb = b - SCB;
    const int isf = flag[0];
    if (pb < INF) {
      const int k = pb, n = threadIdx.x;
      w1tb[(size_t)n * INF + k] = f2bf(ldv(W1r, (long)k * C1 + n, isf));
    } else {
      const int n = pb - INF, k = threadIdx.x;
      w2tb[(size_t)n * C1 + k] =
          (n < NCLS) ? f2bf(ldv(W2r, (long)k * NCLS + n, isf)) : (ushort)0;
    }
  }
}

// -------- MFMA GEMM1 + fused elr1: h1[N,256](bf16), el1/er1[N,8] -----------
__global__ __launch_bounds__(256) void k_gemm1m(const void* __restrict__ Xr,
                                                const ushort* __restrict__ w1tb,
                                                const void* __restrict__ alr,
                                                const void* __restrict__ arr,
                                                const int* __restrict__ flag,
                                                ushort* __restrict__ Hb,
                                                float* __restrict__ el,
                                                float* __restrict__ er) {
  __shared__ __align__(16) ushort xs[32 * 136];
  const int tid = threadIdx.x;
  const int rt  = blockIdx.x * 32;
  const int isf = flag[0];

  {
    const int r  = tid >> 4;
    const int c0 = (tid & 15) << 3;
#pragma unroll
    for (int p = 0; p < 2; ++p) {
      const int row  = r + (p << 4);
      const int grow = rt + row;
      uint4 u = make_uint4(0u, 0u, 0u, 0u);
      if (grow < NNODES) {
        if (isf) {
          const float* Xf = (const float*)Xr;
          const float4 a = *reinterpret_cast<const float4*>(Xf + (size_t)grow * INF + c0);
          const float4 b = *reinterpret_cast<const float4*>(Xf + (size_t)grow * INF + c0 + 4);
          u.x = packbf2(a.x, a.y);
          u.y = packbf2(a.z, a.w);
          u.z = packbf2(b.x, b.y);
          u.w = packbf2(b.z, b.w);
        } else {
          const ushort* Xb = (const ushort*)Xr;
          u = *reinterpret_cast<const uint4*>(Xb + (size_t)grow * INF + c0);
        }
      }
      *reinterpret_cast<uint4*>(&xs[row * 136 + c0]) = u;
    }
  }
  __syncthreads();

  const int lane = tid & 63;
  const int wv   = tid >> 6;
  const int n0   = wv << 6;
  const int col  = lane & 15;
  const int quad = lane >> 4;

  short8v bf[16];
#pragma unroll
  for (int ct = 0; ct < 4; ++ct)
#pragma unroll
    for (int ks = 0; ks < 4; ++ks)
      bf[ct * 4 + ks] = *reinterpret_cast<const short8v*>(
          &w1tb[(size_t)(n0 + ct * 16 + col) * INF + (ks << 5) + (quad << 3)]);
  short8v af[8];
#pragma unroll
  for (int rt2 = 0; rt2 < 2; ++rt2)
#pragma unroll
    for (int ks = 0; ks < 4; ++ks)
      af[rt2 * 4 + ks] = *reinterpret_cast<const short8v*>(
          &xs[(rt2 * 16 + col) * 136 + (ks << 5) + (quad << 3)]);

  f32x4 acc[8];
#pragma unroll
  for (int i = 0; i < 8; ++i) acc[i] = (f32x4){0.f, 0.f, 0.f, 0.f};

#pragma unroll
  for (int rt2 = 0; rt2 < 2; ++rt2)
#pragma unroll
    for (int ct = 0; ct < 4; ++ct)
#pragma unroll
      for (int ks = 0; ks < 4; ++ks)
        acc[rt2 * 4 + ct] = __builtin_amdgcn_mfma_f32_16x16x32_bf16(
            af[rt2 * 4 + ks], bf[ct * 4 + ks], acc[rt2 * 4 + ct], 0, 0, 0);

#pragma unroll
  for (int rt2 = 0; rt2 < 2; ++rt2)
#pragma unroll
    for (int ct = 0; ct < 4; ++ct)
#pragma unroll
      for (int r = 0; r < 4; ++r) {
        const int row = rt + rt2 * 16 + (quad << 2) + r;
        if (row < NNODES)
          Hb[(size_t)row * C1 + n0 + (ct << 4) + col] = f2bf(acc[rt2 * 4 + ct][r]);
      }

  float alv[4], arv[4];
#pragma unroll
  for (int ct = 0; ct < 4; ++ct) {
    alv[ct] = ldv(alr, n0 + ct * 16 + col, isf);
    arv[ct] = ldv(arr, n0 + ct * 16 + col, isf);
  }
#pragma unroll
  for (int rt2 = 0; rt2 < 2; ++rt2)
#pragma unroll
    for (int r = 0; r < 4; ++r) {
      float pl0 = acc[rt2 * 4 + 0][r] * alv[0] + acc[rt2 * 4 + 1][r] * alv[1];
      float pl1 = acc[rt2 * 4 + 2][r] * alv[2] + acc[rt2 * 4 + 3][r] * alv[3];
      float pr0 = acc[rt2 * 4 + 0][r] * arv[0] + acc[rt2 * 4 + 1][r] * arv[1];
      float pr1 = acc[rt2 * 4 + 2][r] * arv[2] + acc[rt2 * 4 + 3][r] * arv[3];
#pragma unroll
      for (int k = 1; k <= 8; k <<= 1) {
        pl0 += __shfl_xor(pl0, k, 64);
        pl1 += __shfl_xor(pl1, k, 64);
        pr0 += __shfl_xor(pr0, k, 64);
        pr1 += __shfl_xor(pr1, k, 64);
      }
      if (col == 0) {
        const int row = rt + rt2 * 16 + (quad << 2) + r;
        if (row < NNODES) {
          el[row * HEADS + 2 * wv]     = pl0;
          el[row * HEADS + 2 * wv + 1] = pl1;
          er[row * HEADS + 2 * wv]     = pr0;
          er[row * HEADS + 2 * wv + 1] = pr1;
        }
      }
    }
}

// -------- Agg layer 1: HALF-WAVE per node, 8 cols/lane (uint4), unroll 6 ---
__global__ __launch_bounds__(256) void k_agg1(const int* __restrict__ rowptr,
                                              const int* __restrict__ deg,
                                              const int* __restrict__ colsrc,
                                              const float* __restrict__ el,
                                              const float* __restrict__ er,
                                              const ushort* __restrict__ h1b,
                                              const void* __restrict__ b1r,
                                              const int* __restrict__ flag,
                                              ushort* __restrict__ out1b) {
  const int n = blockIdx.x * 8 + (threadIdx.x >> 5);
  if (n >= NNODES) return;
  const int t  = threadIdx.x & 31;   // half-wave lane
  const int c0 = t << 3;             // 8 cols per lane
  const int h  = t >> 2;
  const int isf = flag[0];
  const int start = rowptr[n];
  const int cnt   = deg[n];
  const char* hp  = (const char*)h1b;
  const char* elp = (const char*)el;
  const float ern = er[n * HEADS + h];
  const int* cp = colsrc + start;
  const uint cb = (uint)c0 << 1;     // 16 B per lane within row
  const uint hb = (uint)h << 2;
  float a[8];
#pragma unroll
  for (int k = 0; k < 8; ++k) a[k] = 0.f;
  float den = 0.f;
  int i = 0;
  for (; i + 6 <= cnt; i += 6) {
    int s[6];
#pragma unroll
    for (int j = 0; j < 6; ++j) s[j] = cp[i + j];
    float l[6];
#pragma unroll
    for (int j = 0; j < 6; ++j)
      l[j] = *reinterpret_cast<const float*>(elp + (((uint)s[j] << 5) | hb));
    uint4 u[6];
#pragma unroll
    for (int j = 0; j < 6; ++j)
      u[j] = *reinterpret_cast<const uint4*>(hp + (((uint)s[j] << 9) | cb));
#pragma unroll
    for (int j = 0; j < 6; ++j) {
      const float e = __expf(lrelu(l[j] + ern));
      den += e;
      a[0] += e * __uint_as_float(u[j].x << 16);
      a[1] += e * __uint_as_float(u[j].x & 0xffff0000u);
      a[2] += e * __uint_as_float(u[j].y << 16);
      a[3] += e * __uint_as_float(u[j].y & 0xffff0000u);
      a[4] += e * __uint_as_float(u[j].z << 16);
      a[5] += e * __uint_as_float(u[j].z & 0xffff0000u);
      a[6] += e * __uint_as_float(u[j].w << 16);
      a[7] += e * __uint_as_float(u[j].w & 0xffff0000u);
    }
  }
  for (; i < cnt; ++i) {
    const int s = cp[i];
    const float l = *reinterpret_cast<const float*>(elp + (((uint)s << 5) | hb));
    const uint4 u = *reinterpret_cast<const uint4*>(hp + (((uint)s << 9) | cb));
    const float e = __expf(lrelu(l + ern));
    den += e;
    a[0] += e * __uint_as_float(u.x << 16);
    a[1] += e * __uint_as_float(u.x & 0xffff0000u);
    a[2] += e * __uint_as_float(u.y << 16);
    a[3] += e * __uint_as_float(u.y & 0xffff0000u);
    a[4] += e * __uint_as_float(u.z << 16);
    a[5] += e * __uint_as_float(u.z & 0xffff0000u);
    a[6] += e * __uint_as_float(u.w << 16);
    a[7] += e * __uint_as_float(u.w & 0xffff0000u);
  }
  const float inv = 1.f / fmaxf(den, 1e-9f);
  float o[8];
#pragma unroll
  for (int k = 0; k < 8; ++k) {
    float v = a[k] * inv + ldv(b1r, c0 + k, isf);
    o[k] = (v > 0.f) ? v : expm1f(v);   // ELU
  }
  uint4 w;
  w.x = packbf2(o[0], o[1]);
  w.y = packbf2(o[2], o[3]);
  w.z = packbf2(o[4], o[5]);
  w.w = packbf2(o[6], o[7]);
  *reinterpret_cast<uint4*>((char*)out1b + ((uint)n << 9) + cb) = w;
}

// -------- MFMA GEMM2 + fused elr2: h2[N,40](bf16), el2/er2[N] --------------
__global__ __launch_bounds__(256) void k_gemm2m(const ushort* __restrict__ Ab,
                                                const ushort* __restrict__ w2tb,
                                                const void* __restrict__ alr,
                                                const void* __restrict__ arr,
                                                const int* __restrict__ flag,
                                                ushort* __restrict__ Hb,
                                                float* __restrict__ el,
                                                float* __restrict__ er) {
  __shared__ __align__(16) ushort as2[64 * 264];
  const int tid = threadIdx.x;
  const int rt  = blockIdx.x * 64;
  const int isf = flag[0];

  {
    const int r  = tid >> 2;
    const int cb = (tid & 3) << 6;
    const int grow = rt + r;
#pragma unroll
    for (int j = 0; j < 8; ++j) {
      uint4 u = make_uint4(0u, 0u, 0u, 0u);
      if (grow < NNODES)
        u = *reinterpret_cast<const uint4*>(Ab + (size_t)grow * C1 + cb + (j << 3));
      *reinterpret_cast<uint4*>(&as2[r * 264 + cb + (j << 3)]) = u;
    }
  }
  __syncthreads();

  const int lane = tid & 63;
  const int wv   = tid >> 6;
  const int col  = lane & 15;
  const int quad = lane >> 4;

  f32x4 acc[3];
#pragma unroll
  for (int i = 0; i < 3; ++i) acc[i] = (f32x4){0.f, 0.f, 0.f, 0.f};

#pragma unroll
  for (int ks = 0; ks < 8; ++ks) {
    const int k0 = (ks << 5) + (quad << 3);
    const short8v a = *reinterpret_cast<const short8v*>(&as2[(wv * 16 + col) * 264 + k0]);
    const short8v b0 = *reinterpret_cast<const short8v*>(&w2tb[(size_t)( 0 + col) * C1 + k0]);
    const short8v b1 = *reinterpret_cast<const short8v*>(&w2tb[(size_t)(16 + col) * C1 + k0]);
    const short8v b2 = *reinterpret_cast<const short8v*>(&w2tb[(size_t)(32 + col) * C1 + k0]);
    acc[0] = __builtin_amdgcn_mfma_f32_16x16x32_bf16(a, b0, acc[0], 0, 0, 0);
    acc[1] = __builtin_amdgcn_mfma_f32_16x16x32_bf16(a, b1, acc[1], 0, 0, 0);
    acc[2] = __builtin_amdgcn_mfma_f32_16x16x32_bf16(a, b2, acc[2], 0, 0, 0);
  }

  float alv[3], arv[3];
#pragma unroll
  for (int ct = 0; ct < 3; ++ct) {
    const int gc = ct * 16 + col;
    alv[ct] = (gc < NCLS) ? ldv(alr, gc, isf) : 0.f;
    arv[ct] = (gc < NCLS) ? ldv(arr, gc, isf) : 0.f;
  }
#pragma unroll
  for (int r = 0; r < 4; ++r) {
    const int row = rt + wv * 16 + (quad << 2) + r;
    const bool rok = row < NNODES;
#pragma unroll
    for (int ct = 0; ct < 3; ++ct) {
      const int gc = ct * 16 + col;
      if (rok && gc < NCLS)
        Hb[(size_t)row * NCLS + gc] = f2bf(acc[ct][r]);
    }
    float pl = acc[0][r] * alv[0] + acc[1][r] * alv[1] + acc[2][r] * alv[2];
    float pr = acc[0][r] * arv[0] + acc[1][r] * arv[1] + acc[2][r] * arv[2];
#pragma unroll
    for (int k = 1; k <= 8; k <<= 1) {
      pl += __shfl_xor(pl, k, 64);
      pr += __shfl_xor(pr, k, 64);
    }
    if (col == 0 && rok) {
      el[row] = pl;
      er[row] = pr;
    }
  }
}

// -------- Agg layer 2: HALF-WAVE per node, 2 cols/lane, unroll 8 -----------
__global__ __launch_bounds__(256) void k_agg2(const int* __restrict__ rowptr,
                                              const int* __restrict__ deg,
                                              const int* __restrict__ colsrc,
                                              const float* __restrict__ el,
                                              const float* __restrict__ er,
                                              const ushort* __restrict__ h2b,
                                              const void* __restrict__ b2r,
                                              const int* __restrict__ flag,
                                              float* __restrict__ out) {
  const int n = blockIdx.x * 8 + (threadIdx.x >> 5);
  if (n >= NNODES) return;
  const int t  = threadIdx.x & 31;
  const int c0 = t << 1;             // 2 cols per lane
  const bool act = c0 < NCLS;
  const int isf  = flag[0];
  const int start = rowptr[n];
  const int cnt   = deg[n];
  const float ern = er[n];
  const char* hp = (const char*)h2b;
  const uint cb = (uint)c0 << 1;
  const int* cp = colsrc + start;
  float a0 = 0.f, a1 = 0.f, den = 0.f;
  int i = 0;
  for (; i + 8 <= cnt; i += 8) {
    int s[8];
#pragma unroll
    for (int j = 0; j < 8; ++j) s[j] = cp[i + j];
    float l[8];
#pragma unroll
    for (int j = 0; j < 8; ++j) l[j] = el[s[j]];
    uint u[8];
#pragma unroll
    for (int j = 0; j < 8; ++j)
      u[j] = act ? *reinterpret_cast<const uint*>(hp + (uint)s[j] * 80u + cb) : 0u;
#pragma unroll
    for (int j = 0; j < 8; ++j) {
      const float e = __expf(lrelu(l[j] + ern));
      den += e;
      a0 += e * __uint_as_float(u[j] << 16);
      a1 += e * __uint_as_float(u[j] & 0xffff0000u);
    }
  }
  for (; i < cnt; ++i) {
    const int s = cp[i];
    const float e = __expf(lrelu(el[s] + ern));
    den += e;
    const uint u = act ? *reinterpret_cast<const uint*>(hp + (uint)s * 80u + cb) : 0u;
    a0 += e * __uint_as_float(u << 16);
    a1 += e * __uint_as_float(u & 0xffff0000u);
  }
  if (act) {
    const float inv = 1.f / fmaxf(den, 1e-9f);
    float2 o;
    o.x = a0 * inv + ldv(b2r, c0 + 0, isf);
    o.y = a1 * inv + ldv(b2r, c0 + 1, isf);
    *reinterpret_cast<float2*>(out + (size_t)n * NCLS + c0) = o;
  }
}

extern "C" void kernel_launch(void* const* d_in, const int* in_sizes, int n_in,
                              void* d_out, int out_size, void* d_ws, size_t ws_size,
                              hipStream_t stream) {
  // ---- size-driven input mapping ----
  int ix = -1, iW1 = -1, iW2 = -1, e1 = -1, e2 = -1;
  int i256[3] = {-1, -1, -1}, n256 = 0;
  int i40[3]  = {-1, -1, -1}, n40 = 0;
  for (int i = 0; i < n_in; ++i) {
    switch (in_sizes[i]) {
      case 6400000: ix = i; break;
      case 800000:  if (e1 < 0) e1 = i; else e2 = i; break;
      case 32768:   iW1 = i; break;
      case 10240:   iW2 = i; break;
      case 256:     if (n256 < 3) i256[n256++] = i; break;
      case 40:      if (n40 < 3)  i40[n40++]  = i; break;
      default: break;
    }
  }
  bool mapped = (ix >= 0 && iW1 >= 0 && iW2 >= 0 && e2 >= 0 && n256 == 3 && n40 == 3);
  int isrc, idst;
  if (mapped) {
    const bool dict_order = (in_sizes[0] == 6400000);
    isrc = dict_order ? e1 : e2;
    idst = dict_order ? e2 : e1;
  } else {
    ix = 0; isrc = 1; idst = 2; iW1 = 3;
    i256[0] = 4; i256[1] = 5; i256[2] = 6;
    iW2 = 7; i40[0] = 8; i40[1] = 9; i40[2] = 10;
  }
  const void* X   = d_in[ix];
  const int*  src = (const int*)d_in[isrc];
  const int*  dst = (const int*)d_in[idst];
  const void* W1  = d_in[iW1];
  const void* al1 = d_in[i256[0]];
  const void* ar1 = d_in[i256[1]];
  const void* b1  = d_in[i256[2]];
  const void* W2  = d_in[iW2];
  const void* al2 = d_in[i40[0]];
  const void* ar2 = d_in[i40[1]];
  const void* b2  = d_in[i40[2]];

  char* ws = (char*)d_ws;
  size_t off = 0;
  auto alloc = [&](size_t bytes) -> void* {
    void* p = ws + off;
    off = (off + bytes + 255) & ~(size_t)255;
    return p;
  };
  int*    flag   = (int*)alloc(256);
  int*    aggf   = (int*)alloc(64 * 4);
  int*    deg    = (int*)alloc((size_t)NNODES * 4);
  int*    rowptr = (int*)alloc((size_t)NNODES * 4);
  int*    erank  = (int*)alloc((size_t)NEDGES * 4);
  int*    colsrc = (int*)alloc((size_t)NEDGES * 4);
  float*  el1    = (float*)alloc((size_t)NNODES * HEADS * 4);
  float*  er1    = (float*)alloc((size_t)NNODES * HEADS * 4);
  float*  el2    = (float*)alloc((size_t)NNODES * 4);
  float*  er2    = (float*)alloc((size_t)NNODES * 4);
  ushort* w1tb   = (ushort*)alloc((size_t)C1 * INF * 2);
  ushort* w2tb   = (ushort*)alloc((size_t)NCP * C1 * 2);
  ushort* h1b    = (ushort*)alloc((size_t)NNODES * C1 * 2);    // 25.6 MB
  ushort* out1b  = (ushort*)alloc((size_t)NNODES * C1 * 2);    // 25.6 MB
  ushort* h2b    = (ushort*)alloc((size_t)NNODES * NCLS * 2);  // 4 MB

  k_init<<<(NNODES + 255) / 256, 256, 0, stream>>>((const ushort*)X, flag, deg, aggf);
  k_hist<<<(NEDGES / 4 + 255) / 256, 256, 0, stream>>>(dst, deg, erank);
  k_scan<<<NSB, 1024, 0, stream>>>(deg, rowptr, aggf);
  k_scatprep<<<SCB + INF + NCP, 256, 0, stream>>>(src, dst, rowptr, erank, colsrc,
                                                  W1, W2, flag, w1tb, w2tb);

  k_gemm1m<<<(NNODES + 31) / 32, 256, 0, stream>>>(X, w1tb, al1, ar1, flag,
                                                   h1b, el1, er1);
  k_agg1<<<(NNODES + 7) / 8, 256, 0, stream>>>(rowptr, deg, colsrc, el1, er1,
                                               h1b, b1, flag, out1b);

  k_gemm2m<<<(NNODES + 63) / 64, 256, 0, stream>>>(out1b, w2tb, al2, ar2, flag,
                                                   h2b, el2, er2);
  k_agg2<<<(NNODES + 7) / 8, 256, 0, stream>>>(rowptr, deg, colsrc, el2, er2,
                                               h2b, b2, flag, (float*)d_out);
}

// Round 14
// 281.575 us; speedup vs baseline: 4.1715x; 1.0411x over previous
//
#include <hip/hip_runtime.h>
#include <hip/hip_bf16.h>
#include <math.h>

#define NNODES 50000
#define NEDGES 800000
#define INF    128
#define HIDD   32
#define HEADS  8
#define C1     256   // HEADS*HIDD
#define NCLS   40
#define NCP    48    // NCLS padded to 3 MFMA col-tiles
#define NSB    49    // scan blocks: ceil(50000/1024)
#define SCB    ((NEDGES / 4 + 255) / 256)   // scatter blocks

typedef unsigned int  uint;
typedef unsigned short ushort;
typedef __attribute__((ext_vector_type(8))) short short8v;   // 8 bf16 (4 VGPRs)
typedef __attribute__((ext_vector_type(4))) float f32x4;

__device__ __forceinline__ float bf2f(ushort v) {
  return __uint_as_float(((uint)v) << 16);
}
__device__ __forceinline__ ushort f2bf(float f) {
  __hip_bfloat16 b = __float2bfloat16(f);
  return *reinterpret_cast<ushort*>(&b);
}
__device__ __forceinline__ float ldv(const void* p, long i, int isf) {
  return isf ? ((const float*)p)[i] : bf2f(((const ushort*)p)[i]);
}
__device__ __forceinline__ uint packbf2(float f0, float f1) {
  return (uint)f2bf(f0) | ((uint)f2bf(f1) << 16);
}
__device__ __forceinline__ float lrelu(float x) {
  return fmaxf(x, 0.2f * x);   // exact for all x (slope<1)
}

// -------- init: zero deg + scan flags + dtype detect -----------------------
__global__ __launch_bounds__(256) void k_init(const ushort* __restrict__ xr,
                                              int* __restrict__ flag,
                                              int* __restrict__ deg,
                                              int* __restrict__ aggf) {
  const int g = blockIdx.x * 256 + threadIdx.x;
  if (g < NNODES) deg[g] = 0;
  if (g < 64) aggf[g] = 0;
  if (blockIdx.x == 0 && threadIdx.x < 64) {
    const int t = threadIdx.x;
    int c = 0;
    for (int i = t; i < 4096; i += 64) {
      const uint e = (xr[i] >> 7) & 0xFFu;
      if (e > 200u) c++;
    }
#pragma unroll
    for (int k = 32; k >= 1; k >>= 1) c += __shfl_xor(c, k, 64);
    if (t == 0) flag[0] = (c > 100) ? 1 : 0;  // 1 => inputs stored as float32
  }
}

// -------- hist: count degrees AND record per-edge rank ---------------------
__global__ void k_hist(const int* __restrict__ dst, int* __restrict__ deg,
                       int* __restrict__ erank) {
  const int e = (blockIdx.x * 256 + threadIdx.x) << 2;   // NEDGES % 4 == 0
  if (e < NEDGES) {
    const int4 d4 = *reinterpret_cast<const int4*>(dst + e);
    int4 r4;
    r4.x = atomicAdd(&deg[d4.x], 1);
    r4.y = atomicAdd(&deg[d4.y], 1);
    r4.z = atomicAdd(&deg[d4.z], 1);
    r4.w = atomicAdd(&deg[d4.w], 1);
    *reinterpret_cast<int4*>(erank + e) = r4;
  }
}

// -------- single-pass scan: publish aggregates, lookback-sum ---------------
// All NSB=49 blocks are co-resident (49 << 256 CUs) => no deadlock.
__global__ __launch_bounds__(1024) void k_scan(const int* __restrict__ deg,
                                               int* __restrict__ rowptr,
                                               int* __restrict__ aggf) {
  __shared__ int wsum[16];
  __shared__ int base_s;
  const int b = blockIdx.x, t = threadIdx.x;
  const int i = b * 1024 + t;
  const int lane = t & 63, wv = t >> 6;
  const int v = (i < NNODES) ? deg[i] : 0;
  int p = v;
#pragma unroll
  for (int off = 1; off < 64; off <<= 1) {
    int u = __shfl_up(p, off, 64);
    if (lane >= off) p += u;
  }
  if (lane == 63) wsum[wv] = p;
  __syncthreads();
  if (wv == 0) {
    int s = (lane < 16) ? wsum[lane] : 0;
#pragma unroll
    for (int off = 1; off < 16; off <<= 1) {
      int u = __shfl_up(s, off, 64);
      if (lane >= off) s += u;
    }
    if (lane < 16) wsum[lane] = s;
  }
  __syncthreads();
  if (t == 0) atomicExch(&aggf[b], wsum[15] + 1);   // publish total (+1 sentinel)
  if (t < 64) {
    int sum = 0;
    for (int j = lane; j < b; j += 64) {
      int a;
      while ((a = atomicAdd(&aggf[j], 0)) == 0) __builtin_amdgcn_s_sleep(8);
      sum += a - 1;
    }
#pragma unroll
    for (int k = 32; k >= 1; k >>= 1) sum += __shfl_xor(sum, k, 64);
    if (lane == 0) base_s = sum;
  }
  __syncthreads();
  const int wbase = (wv > 0) ? wsum[wv - 1] : 0;
  if (i < NNODES) rowptr[i] = base_s + wbase + p - v;   // exclusive
}

// -------- scatter (atomic-free) ∥ prep (weight transpose), role-split ------
__global__ __launch_bounds__(256) void k_scatprep(
    const int* __restrict__ src, const int* __restrict__ dst,
    const int* __restrict__ rowptr, const int* __restrict__ erank,
    int* __restrict__ colsrc,
    const void* __restrict__ W1r, const void* __restrict__ W2r,
    const int* __restrict__ flag,
    ushort* __restrict__ w1tb, ushort* __restrict__ w2tb) {
  const int b = blockIdx.x;
  if (b < SCB) {
    const int e = (b * 256 + threadIdx.x) << 2;
    if (e < NEDGES) {
      const int4 s4 = *reinterpret_cast<const int4*>(src + e);
      const int4 d4 = *reinterpret_cast<const int4*>(dst + e);
      const int4 r4 = *reinterpret_cast<const int4*>(erank + e);
      colsrc[rowptr[d4.x] + r4.x] = s4.x;
      colsrc[rowptr[d4.y] + r4.y] = s4.y;
      colsrc[rowptr[d4.z] + r4.z] = s4.z;
      colsrc[rowptr[d4.w] + r4.w] = s4.w;
    }
  } else {
    const int pb = b - SCB;
    const int isf = flag[0];
    if (pb < INF) {
      const int k = pb, n = threadIdx.x;
      w1tb[(size_t)n * INF + k] = f2bf(ldv(W1r, (long)k * C1 + n, isf));
    } else {
      const int n = pb - INF, k = threadIdx.x;
      w2tb[(size_t)n * C1 + k] =
          (n < NCLS) ? f2bf(ldv(W2r, (long)k * NCLS + n, isf)) : (ushort)0;
    }
  }
}

// -------- MFMA GEMM1 + fused elr1: h1[N,256](bf16), el1/er1[N,8] -----------
__global__ __launch_bounds__(256) void k_gemm1m(const void* __restrict__ Xr,
                                                const ushort* __restrict__ w1tb,
                                                const void* __restrict__ alr,
                                                const void* __restrict__ arr,
                                                const int* __restrict__ flag,
                                                ushort* __restrict__ Hb,
                                                float* __restrict__ el,
                                                float* __restrict__ er) {
  __shared__ __align__(16) ushort xs[32 * 136];
  const int tid = threadIdx.x;
  const int rt  = blockIdx.x * 32;
  const int isf = flag[0];

  {
    const int r  = tid >> 4;
    const int c0 = (tid & 15) << 3;
#pragma unroll
    for (int p = 0; p < 2; ++p) {
      const int row  = r + (p << 4);
      const int grow = rt + row;
      uint4 u = make_uint4(0u, 0u, 0u, 0u);
      if (grow < NNODES) {
        if (isf) {
          const float* Xf = (const float*)Xr;
          const float4 a = *reinterpret_cast<const float4*>(Xf + (size_t)grow * INF + c0);
          const float4 b = *reinterpret_cast<const float4*>(Xf + (size_t)grow * INF + c0 + 4);
          u.x = packbf2(a.x, a.y);
          u.y = packbf2(a.z, a.w);
          u.z = packbf2(b.x, b.y);
          u.w = packbf2(b.z, b.w);
        } else {
          const ushort* Xb = (const ushort*)Xr;
          u = *reinterpret_cast<const uint4*>(Xb + (size_t)grow * INF + c0);
        }
      }
      *reinterpret_cast<uint4*>(&xs[row * 136 + c0]) = u;
    }
  }
  __syncthreads();

  const int lane = tid & 63;
  const int wv   = tid >> 6;
  const int n0   = wv << 6;
  const int col  = lane & 15;
  const int quad = lane >> 4;

  short8v bf[16];
#pragma unroll
  for (int ct = 0; ct < 4; ++ct)
#pragma unroll
    for (int ks = 0; ks < 4; ++ks)
      bf[ct * 4 + ks] = *reinterpret_cast<const short8v*>(
          &w1tb[(size_t)(n0 + ct * 16 + col) * INF + (ks << 5) + (quad << 3)]);
  short8v af[8];
#pragma unroll
  for (int rt2 = 0; rt2 < 2; ++rt2)
#pragma unroll
    for (int ks = 0; ks < 4; ++ks)
      af[rt2 * 4 + ks] = *reinterpret_cast<const short8v*>(
          &xs[(rt2 * 16 + col) * 136 + (ks << 5) + (quad << 3)]);

  f32x4 acc[8];
#pragma unroll
  for (int i = 0; i < 8; ++i) acc[i] = (f32x4){0.f, 0.f, 0.f, 0.f};

#pragma unroll
  for (int rt2 = 0; rt2 < 2; ++rt2)
#pragma unroll
    for (int ct = 0; ct < 4; ++ct)
#pragma unroll
      for (int ks = 0; ks < 4; ++ks)
        acc[rt2 * 4 + ct] = __builtin_amdgcn_mfma_f32_16x16x32_bf16(
            af[rt2 * 4 + ks], bf[ct * 4 + ks], acc[rt2 * 4 + ct], 0, 0, 0);

#pragma unroll
  for (int rt2 = 0; rt2 < 2; ++rt2)
#pragma unroll
    for (int ct = 0; ct < 4; ++ct)
#pragma unroll
      for (int r = 0; r < 4; ++r) {
        const int row = rt + rt2 * 16 + (quad << 2) + r;
        if (row < NNODES)
          Hb[(size_t)row * C1 + n0 + (ct << 4) + col] = f2bf(acc[rt2 * 4 + ct][r]);
      }

  float alv[4], arv[4];
#pragma unroll
  for (int ct = 0; ct < 4; ++ct) {
    alv[ct] = ldv(alr, n0 + ct * 16 + col, isf);
    arv[ct] = ldv(arr, n0 + ct * 16 + col, isf);
  }
#pragma unroll
  for (int rt2 = 0; rt2 < 2; ++rt2)
#pragma unroll
    for (int r = 0; r < 4; ++r) {
      float pl0 = acc[rt2 * 4 + 0][r] * alv[0] + acc[rt2 * 4 + 1][r] * alv[1];
      float pl1 = acc[rt2 * 4 + 2][r] * alv[2] + acc[rt2 * 4 + 3][r] * alv[3];
      float pr0 = acc[rt2 * 4 + 0][r] * arv[0] + acc[rt2 * 4 + 1][r] * arv[1];
      float pr1 = acc[rt2 * 4 + 2][r] * arv[2] + acc[rt2 * 4 + 3][r] * arv[3];
#pragma unroll
      for (int k = 1; k <= 8; k <<= 1) {
        pl0 += __shfl_xor(pl0, k, 64);
        pl1 += __shfl_xor(pl1, k, 64);
        pr0 += __shfl_xor(pr0, k, 64);
        pr1 += __shfl_xor(pr1, k, 64);
      }
      if (col == 0) {
        const int row = rt + rt2 * 16 + (quad << 2) + r;
        if (row < NNODES) {
          el[row * HEADS + 2 * wv]     = pl0;
          el[row * HEADS + 2 * wv + 1] = pl1;
          er[row * HEADS + 2 * wv]     = pr0;
          er[row * HEADS + 2 * wv + 1] = pr1;
        }
      }
    }
}

// -------- Agg layer 1: FULL wave/node, 4 cols/lane (uint2), unroll 8 -------
__global__ __launch_bounds__(256) void k_agg1(const int* __restrict__ rowptr,
                                              const int* __restrict__ deg,
                                              const int* __restrict__ colsrc,
                                              const float* __restrict__ el,
                                              const float* __restrict__ er,
                                              const ushort* __restrict__ h1b,
                                              const void* __restrict__ b1r,
                                              const int* __restrict__ flag,
                                              ushort* __restrict__ out1b) {
  const int n = blockIdx.x * 4 + (threadIdx.x >> 6);
  if (n >= NNODES) return;
  const int t  = threadIdx.x & 63;
  const int c0 = t << 2;             // 4 cols per lane
  const int h  = t >> 3;
  const int isf = flag[0];
  const int start = rowptr[n];
  const int cnt   = deg[n];
  const char* hp  = (const char*)h1b;
  const char* elp = (const char*)el;
  const float ern = er[n * HEADS + h];
  const int* cp = colsrc + start;
  const uint cb = (uint)c0 << 1;
  const uint hb = (uint)h << 2;
  float a0 = 0.f, a1 = 0.f, a2 = 0.f, a3 = 0.f, den = 0.f;
  int i = 0;
  for (; i + 8 <= cnt; i += 8) {
    int s[8];
#pragma unroll
    for (int j = 0; j < 8; ++j) s[j] = cp[i + j];
    float l[8];
#pragma unroll
    for (int j = 0; j < 8; ++j)
      l[j] = *reinterpret_cast<const float*>(elp + (((uint)s[j] << 5) | hb));
    uint2 u[8];
#pragma unroll
    for (int j = 0; j < 8; ++j)
      u[j] = *reinterpret_cast<const uint2*>(hp + (((uint)s[j] << 9) | cb));
#pragma unroll
    for (int j = 0; j < 8; ++j) {
      const float e = __expf(lrelu(l[j] + ern));
      den += e;
      a0 += e * __uint_as_float(u[j].x << 16);
      a1 += e * __uint_as_float(u[j].x & 0xffff0000u);
      a2 += e * __uint_as_float(u[j].y << 16);
      a3 += e * __uint_as_float(u[j].y & 0xffff0000u);
    }
  }
  for (; i < cnt; ++i) {
    const int s = cp[i];
    const float l = *reinterpret_cast<const float*>(elp + (((uint)s << 5) | hb));
    const uint2 u = *reinterpret_cast<const uint2*>(hp + (((uint)s << 9) | cb));
    const float e = __expf(lrelu(l + ern));
    den += e;
    a0 += e * __uint_as_float(u.x << 16);
    a1 += e * __uint_as_float(u.x & 0xffff0000u);
    a2 += e * __uint_as_float(u.y << 16);
    a3 += e * __uint_as_float(u.y & 0xffff0000u);
  }
  const float inv = 1.f / fmaxf(den, 1e-9f);
  float o0 = a0 * inv + ldv(b1r, c0 + 0, isf);
  float o1 = a1 * inv + ldv(b1r, c0 + 1, isf);
  float o2 = a2 * inv + ldv(b1r, c0 + 2, isf);
  float o3 = a3 * inv + ldv(b1r, c0 + 3, isf);
  o0 = (o0 > 0.f) ? o0 : expm1f(o0);
  o1 = (o1 > 0.f) ? o1 : expm1f(o1);
  o2 = (o2 > 0.f) ? o2 : expm1f(o2);
  o3 = (o3 > 0.f) ? o3 : expm1f(o3);
  uint2 w;
  w.x = packbf2(o0, o1);
  w.y = packbf2(o2, o3);
  *reinterpret_cast<uint2*>((char*)out1b + ((uint)n << 9) + cb) = w;
}

// -------- MFMA GEMM2 + fused elr2: h2[N,40](bf16), el2/er2[N] --------------
__global__ __launch_bounds__(256) void k_gemm2m(const ushort* __restrict__ Ab,
                                                const ushort* __restrict__ w2tb,
                                                const void* __restrict__ alr,
                                                const void* __restrict__ arr,
                                                const int* __restrict__ flag,
                                                ushort* __restrict__ Hb,
                                                float* __restrict__ el,
                                                float* __restrict__ er) {
  __shared__ __align__(16) ushort as2[64 * 264];
  const int tid = threadIdx.x;
  const int rt  = blockIdx.x * 64;
  const int isf = flag[0];

  {
    const int r  = tid >> 2;
    const int cb = (tid & 3) << 6;
    const int grow = rt + r;
#pragma unroll
    for (int j = 0; j < 8; ++j) {
      uint4 u = make_uint4(0u, 0u, 0u, 0u);
      if (grow < NNODES)
        u = *reinterpret_cast<const uint4*>(Ab + (size_t)grow * C1 + cb + (j << 3));
      *reinterpret_cast<uint4*>(&as2[r * 264 + cb + (j << 3)]) = u;
    }
  }
  __syncthreads();

  const int lane = tid & 63;
  const int wv   = tid >> 6;
  const int col  = lane & 15;
  const int quad = lane >> 4;

  f32x4 acc[3];
#pragma unroll
  for (int i = 0; i < 3; ++i) acc[i] = (f32x4){0.f, 0.f, 0.f, 0.f};

#pragma unroll
  for (int ks = 0; ks < 8; ++ks) {
    const int k0 = (ks << 5) + (quad << 3);
    const short8v a = *reinterpret_cast<const short8v*>(&as2[(wv * 16 + col) * 264 + k0]);
    const short8v b0 = *reinterpret_cast<const short8v*>(&w2tb[(size_t)( 0 + col) * C1 + k0]);
    const short8v b1 = *reinterpret_cast<const short8v*>(&w2tb[(size_t)(16 + col) * C1 + k0]);
    const short8v b2 = *reinterpret_cast<const short8v*>(&w2tb[(size_t)(32 + col) * C1 + k0]);
    acc[0] = __builtin_amdgcn_mfma_f32_16x16x32_bf16(a, b0, acc[0], 0, 0, 0);
    acc[1] = __builtin_amdgcn_mfma_f32_16x16x32_bf16(a, b1, acc[1], 0, 0, 0);
    acc[2] = __builtin_amdgcn_mfma_f32_16x16x32_bf16(a, b2, acc[2], 0, 0, 0);
  }

  float alv[3], arv[3];
#pragma unroll
  for (int ct = 0; ct < 3; ++ct) {
    const int gc = ct * 16 + col;
    alv[ct] = (gc < NCLS) ? ldv(alr, gc, isf) : 0.f;
    arv[ct] = (gc < NCLS) ? ldv(arr, gc, isf) : 0.f;
  }
#pragma unroll
  for (int r = 0; r < 4; ++r) {
    const int row = rt + wv * 16 + (quad << 2) + r;
    const bool rok = row < NNODES;
#pragma unroll
    for (int ct = 0; ct < 3; ++ct) {
      const int gc = ct * 16 + col;
      if (rok && gc < NCLS)
        Hb[(size_t)row * NCLS + gc] = f2bf(acc[ct][r]);
    }
    float pl = acc[0][r] * alv[0] + acc[1][r] * alv[1] + acc[2][r] * alv[2];
    float pr = acc[0][r] * arv[0] + acc[1][r] * arv[1] + acc[2][r] * arv[2];
#pragma unroll
    for (int k = 1; k <= 8; k <<= 1) {
      pl += __shfl_xor(pl, k, 64);
      pr += __shfl_xor(pr, k, 64);
    }
    if (col == 0 && rok) {
      el[row] = pl;
      er[row] = pr;
    }
  }
}

// -------- Agg layer 2: HALF-WAVE per node, 2 cols/lane, unroll 8 -----------
__global__ __launch_bounds__(256) void k_agg2(const int* __restrict__ rowptr,
                                              const int* __restrict__ deg,
                                              const int* __restrict__ colsrc,
                                              const float* __restrict__ el,
                                              const float* __restrict__ er,
                                              const ushort* __restrict__ h2b,
                                              const void* __restrict__ b2r,
                                              const int* __restrict__ flag,
                                              float* __restrict__ out) {
  const int n = blockIdx.x * 8 + (threadIdx.x >> 5);
  if (n >= NNODES) return;
  const int t  = threadIdx.x & 31;
  const int c0 = t << 1;             // 2 cols per lane
  const bool act = c0 < NCLS;
  const int isf  = flag[0];
  const int start = rowptr[n];
  const int cnt   = deg[n];
  const float ern = er[n];
  const char* hp = (const char*)h2b;
  const uint cb = (uint)c0 << 1;
  const int* cp = colsrc + start;
  float a0 = 0.f, a1 = 0.f, den = 0.f;
  int i = 0;
  for (; i + 8 <= cnt; i += 8) {
    int s[8];
#pragma unroll
    for (int j = 0; j < 8; ++j) s[j] = cp[i + j];
    float l[8];
#pragma unroll
    for (int j = 0; j < 8; ++j) l[j] = el[s[j]];
    uint u[8];
#pragma unroll
    for (int j = 0; j < 8; ++j)
      u[j] = act ? *reinterpret_cast<const uint*>(hp + (uint)s[j] * 80u + cb) : 0u;
#pragma unroll
    for (int j = 0; j < 8; ++j) {
      const float e = __expf(lrelu(l[j] + ern));
      den += e;
      a0 += e * __uint_as_float(u[j] << 16);
      a1 += e * __uint_as_float(u[j] & 0xffff0000u);
    }
  }
  for (; i < cnt; ++i) {
    const int s = cp[i];
    const float e = __expf(lrelu(el[s] + ern));
    den += e;
    const uint u = act ? *reinterpret_cast<const uint*>(hp + (uint)s * 80u + cb) : 0u;
    a0 += e * __uint_as_float(u << 16);
    a1 += e * __uint_as_float(u & 0xffff0000u);
  }
  if (act) {
    const float inv = 1.f / fmaxf(den, 1e-9f);
    float2 o;
    o.x = a0 * inv + ldv(b2r, c0 + 0, isf);
    o.y = a1 * inv + ldv(b2r, c0 + 1, isf);
    *reinterpret_cast<float2*>(out + (size_t)n * NCLS + c0) = o;
  }
}

extern "C" void kernel_launch(void* const* d_in, const int* in_sizes, int n_in,
                              void* d_out, int out_size, void* d_ws, size_t ws_size,
                              hipStream_t stream) {
  // ---- size-driven input mapping ----
  int ix = -1, iW1 = -1, iW2 = -1, e1 = -1, e2 = -1;
  int i256[3] = {-1, -1, -1}, n256 = 0;
  int i40[3]  = {-1, -1, -1}, n40 = 0;
  for (int i = 0; i < n_in; ++i) {
    switch (in_sizes[i]) {
      case 6400000: ix = i; break;
      case 800000:  if (e1 < 0) e1 = i; else e2 = i; break;
      case 32768:   iW1 = i; break;
      case 10240:   iW2 = i; break;
      case 256:     if (n256 < 3) i256[n256++] = i; break;
      case 40:      if (n40 < 3)  i40[n40++]  = i; break;
      default: break;
    }
  }
  bool mapped = (ix >= 0 && iW1 >= 0 && iW2 >= 0 && e2 >= 0 && n256 == 3 && n40 == 3);
  int isrc, idst;
  if (mapped) {
    const bool dict_order = (in_sizes[0] == 6400000);
    isrc = dict_order ? e1 : e2;
    idst = dict_order ? e2 : e1;
  } else {
    ix = 0; isrc = 1; idst = 2; iW1 = 3;
    i256[0] = 4; i256[1] = 5; i256[2] = 6;
    iW2 = 7; i40[0] = 8; i40[1] = 9; i40[2] = 10;
  }
  const void* X   = d_in[ix];
  const int*  src = (const int*)d_in[isrc];
  const int*  dst = (const int*)d_in[idst];
  const void* W1  = d_in[iW1];
  const void* al1 = d_in[i256[0]];
  const void* ar1 = d_in[i256[1]];
  const void* b1  = d_in[i256[2]];
  const void* W2  = d_in[iW2];
  const void* al2 = d_in[i40[0]];
  const void* ar2 = d_in[i40[1]];
  const void* b2  = d_in[i40[2]];

  char* ws = (char*)d_ws;
  size_t off = 0;
  auto alloc = [&](size_t bytes) -> void* {
    void* p = ws + off;
    off = (off + bytes + 255) & ~(size_t)255;
    return p;
  };
  int*    flag   = (int*)alloc(256);
  int*    aggf   = (int*)alloc(64 * 4);
  int*    deg    = (int*)alloc((size_t)NNODES * 4);
  int*    rowptr = (int*)alloc((size_t)NNODES * 4);
  int*    erank  = (int*)alloc((size_t)NEDGES * 4);
  int*    colsrc = (int*)alloc((size_t)NEDGES * 4);
  float*  el1    = (float*)alloc((size_t)NNODES * HEADS * 4);
  float*  er1    = (float*)alloc((size_t)NNODES * HEADS * 4);
  float*  el2    = (float*)alloc((size_t)NNODES * 4);
  float*  er2    = (float*)alloc((size_t)NNODES * 4);
  ushort* w1tb   = (ushort*)alloc((size_t)C1 * INF * 2);
  ushort* w2tb   = (ushort*)alloc((size_t)NCP * C1 * 2);
  ushort* h1b    = (ushort*)alloc((size_t)NNODES * C1 * 2);    // 25.6 MB
  ushort* out1b  = (ushort*)alloc((size_t)NNODES * C1 * 2);    // 25.6 MB
  ushort* h2b    = (ushort*)alloc((size_t)NNODES * NCLS * 2);  // 4 MB

  k_init<<<(NNODES + 255) / 256, 256, 0, stream>>>((const ushort*)X, flag, deg, aggf);
  k_hist<<<(NEDGES / 4 + 255) / 256, 256, 0, stream>>>(dst, deg, erank);
  k_scan<<<NSB, 1024, 0, stream>>>(deg, rowptr, aggf);
  k_scatprep<<<SCB + INF + NCP, 256, 0, stream>>>(src, dst, rowptr, erank, colsrc,
                                                  W1, W2, flag, w1tb, w2tb);

  k_gemm1m<<<(NNODES + 31) / 32, 256, 0, stream>>>(X, w1tb, al1, ar1, flag,
                                                   h1b, el1, er1);
  k_agg1<<<(NNODES + 3) / 4, 256, 0, stream>>>(rowptr, deg, colsrc, el1, er1,
                                               h1b, b1, flag, out1b);

  k_gemm2m<<<(NNODES + 63) / 64, 256, 0, stream>>>(out1b, w2tb, al2, ar2, flag,
                                                   h2b, el2, er2);
  k_agg2<<<(NNODES + 7) / 8, 256, 0, stream>>>(rowptr, deg, colsrc, el2, er2,
                                               h2b, b2, flag, (float*)d_out);
}

// Round 15
// 279.536 us; speedup vs baseline: 4.2019x; 1.0073x over previous
//
#include <hip/hip_runtime.h>
#include <hip/hip_bf16.h>
#include <math.h>

#define NNODES 50000
#define NEDGES 800000
#define INF    128
#define HIDD   32
#define HEADS  8
#define C1     256   // HEADS*HIDD
#define NCLS   40
#define NCP    48    // NCLS padded to 3 MFMA col-tiles
#define NSB    49    // scan blocks: ceil(50000/1024)
#define EB     ((NEDGES / 4 + 255) / 256)   // edge blocks (4 edges/thread)
#define G1B    ((NNODES + 31) / 32)         // gemm1 blocks

typedef unsigned int  uint;
typedef unsigned short ushort;
typedef __attribute__((ext_vector_type(8))) short short8v;   // 8 bf16 (4 VGPRs)
typedef __attribute__((ext_vector_type(4))) float f32x4;

__device__ __forceinline__ float bf2f(ushort v) {
  return __uint_as_float(((uint)v) << 16);
}
__device__ __forceinline__ ushort f2bf(float f) {
  __hip_bfloat16 b = __float2bfloat16(f);
  return *reinterpret_cast<ushort*>(&b);
}
__device__ __forceinline__ float ldv(const void* p, long i, int isf) {
  return isf ? ((const float*)p)[i] : bf2f(((const ushort*)p)[i]);
}
__device__ __forceinline__ uint packbf2(float f0, float f1) {
  return (uint)f2bf(f0) | ((uint)f2bf(f1) << 16);
}
__device__ __forceinline__ float lrelu(float x) {
  return fmaxf(x, 0.2f * x);   // exact for all x (slope<1)
}

// -------- init: zero deg + scan flags + dtype detect -----------------------
__global__ __launch_bounds__(256) void k_init(const ushort* __restrict__ xr,
                                              int* __restrict__ flag,
                                              int* __restrict__ deg,
                                              int* __restrict__ aggf) {
  const int g = blockIdx.x * 256 + threadIdx.x;
  if (g < NNODES) deg[g] = 0;
  if (g < 64) aggf[g] = 0;
  if (blockIdx.x == 0 && threadIdx.x < 64) {
    const int t = threadIdx.x;
    int c = 0;
    for (int i = t; i < 4096; i += 64) {
      const uint e = (xr[i] >> 7) & 0xFFu;
      if (e > 200u) c++;
    }
#pragma unroll
    for (int k = 32; k >= 1; k >>= 1) c += __shfl_xor(c, k, 64);
    if (t == 0) flag[0] = (c > 100) ? 1 : 0;  // 1 => inputs stored as float32
  }
}

// -------- hist (degree+rank) ∥ prep (weight transpose), role-split ---------
__global__ __launch_bounds__(256) void k_histprep(
    const int* __restrict__ dst, int* __restrict__ deg, int* __restrict__ erank,
    const void* __restrict__ W1r, const void* __restrict__ W2r,
    const int* __restrict__ flag,
    ushort* __restrict__ w1tb, ushort* __restrict__ w2tb) {
  const int b = blockIdx.x;
  if (b < EB) {
    const int e = (b * 256 + threadIdx.x) << 2;   // NEDGES % 4 == 0
    if (e < NEDGES) {
      const int4 d4 = *reinterpret_cast<const int4*>(dst + e);
      int4 r4;
      r4.x = atomicAdd(&deg[d4.x], 1);
      r4.y = atomicAdd(&deg[d4.y], 1);
      r4.z = atomicAdd(&deg[d4.z], 1);
      r4.w = atomicAdd(&deg[d4.w], 1);
      *reinterpret_cast<int4*>(erank + e) = r4;
    }
  } else {
    const int pb = b - EB;
    const int isf = flag[0];
    if (pb < INF) {
      const int k = pb, n = threadIdx.x;
      w1tb[(size_t)n * INF + k] = f2bf(ldv(W1r, (long)k * C1 + n, isf));
    } else {
      const int n = pb - INF, k = threadIdx.x;
      w2tb[(size_t)n * C1 + k] =
          (n < NCLS) ? f2bf(ldv(W2r, (long)k * NCLS + n, isf)) : (ushort)0;
    }
  }
}

// -------- single-pass scan: publish aggregates, lookback-sum ---------------
// All NSB=49 blocks are co-resident (49 << 256 CUs) => no deadlock.
__global__ __launch_bounds__(1024) void k_scan(const int* __restrict__ deg,
                                               int* __restrict__ rowptr,
                                               int* __restrict__ aggf) {
  __shared__ int wsum[16];
  __shared__ int base_s;
  const int b = blockIdx.x, t = threadIdx.x;
  const int i = b * 1024 + t;
  const int lane = t & 63, wv = t >> 6;
  const int v = (i < NNODES) ? deg[i] : 0;
  int p = v;
#pragma unroll
  for (int off = 1; off < 64; off <<= 1) {
    int u = __shfl_up(p, off, 64);
    if (lane >= off) p += u;
  }
  if (lane == 63) wsum[wv] = p;
  __syncthreads();
  if (wv == 0) {
    int s = (lane < 16) ? wsum[lane] : 0;
#pragma unroll
    for (int off = 1; off < 16; off <<= 1) {
      int u = __shfl_up(s, off, 64);
      if (lane >= off) s += u;
    }
    if (lane < 16) wsum[lane] = s;
  }
  __syncthreads();
  if (t == 0) atomicExch(&aggf[b], wsum[15] + 1);   // publish total (+1 sentinel)
  if (t < 64) {
    int sum = 0;
    for (int j = lane; j < b; j += 64) {
      int a;
      while ((a = atomicAdd(&aggf[j], 0)) == 0) __builtin_amdgcn_s_sleep(8);
      sum += a - 1;
    }
#pragma unroll
    for (int k = 32; k >= 1; k >>= 1) sum += __shfl_xor(sum, k, 64);
    if (lane == 0) base_s = sum;
  }
  __syncthreads();
  const int wbase = (wv > 0) ? wsum[wv - 1] : 0;
  if (i < NNODES) rowptr[i] = base_s + wbase + p - v;   // exclusive
}

// -------- scatter (atomic-free) ∥ MFMA GEMM1 + fused elr1, role-split ------
__global__ __launch_bounds__(256) void k_scatgemm1(
    const int* __restrict__ src, const int* __restrict__ dst,
    const int* __restrict__ rowptr, const int* __restrict__ erank,
    int* __restrict__ colsrc,
    const void* __restrict__ Xr, const ushort* __restrict__ w1tb,
    const void* __restrict__ alr, const void* __restrict__ arr,
    const int* __restrict__ flag,
    ushort* __restrict__ Hb, float* __restrict__ el, float* __restrict__ er) {
  __shared__ __align__(16) ushort xs[32 * 136];
  const int b = blockIdx.x;
  if (b < EB) {   // ---- scatter role ----
    const int e = (b * 256 + threadIdx.x) << 2;
    if (e < NEDGES) {
      const int4 s4 = *reinterpret_cast<const int4*>(src + e);
      const int4 d4 = *reinterpret_cast<const int4*>(dst + e);
      const int4 r4 = *reinterpret_cast<const int4*>(erank + e);
      colsrc[rowptr[d4.x] + r4.x] = s4.x;
      colsrc[rowptr[d4.y] + r4.y] = s4.y;
      colsrc[rowptr[d4.z] + r4.z] = s4.z;
      colsrc[rowptr[d4.w] + r4.w] = s4.w;
    }
    return;
  }
  // ---- gemm1m role ----
  const int tid = threadIdx.x;
  const int rt  = (b - EB) * 32;
  const int isf = flag[0];

  {
    const int r  = tid >> 4;
    const int c0 = (tid & 15) << 3;
#pragma unroll
    for (int p = 0; p < 2; ++p) {
      const int row  = r + (p << 4);
      const int grow = rt + row;
      uint4 u = make_uint4(0u, 0u, 0u, 0u);
      if (grow < NNODES) {
        if (isf) {
          const float* Xf = (const float*)Xr;
          const float4 a = *reinterpret_cast<const float4*>(Xf + (size_t)grow * INF + c0);
          const float4 b2 = *reinterpret_cast<const float4*>(Xf + (size_t)grow * INF + c0 + 4);
          u.x = packbf2(a.x, a.y);
          u.y = packbf2(a.z, a.w);
          u.z = packbf2(b2.x, b2.y);
          u.w = packbf2(b2.z, b2.w);
        } else {
          const ushort* Xb = (const ushort*)Xr;
          u = *reinterpret_cast<const uint4*>(Xb + (size_t)grow * INF + c0);
        }
      }
      *reinterpret_cast<uint4*>(&xs[row * 136 + c0]) = u;
    }
  }
  __syncthreads();

  const int lane = tid & 63;
  const int wv   = tid >> 6;
  const int n0   = wv << 6;
  const int col  = lane & 15;
  const int quad = lane >> 4;

  short8v bf[16];
#pragma unroll
  for (int ct = 0; ct < 4; ++ct)
#pragma unroll
    for (int ks = 0; ks < 4; ++ks)
      bf[ct * 4 + ks] = *reinterpret_cast<const short8v*>(
          &w1tb[(size_t)(n0 + ct * 16 + col) * INF + (ks << 5) + (quad << 3)]);
  short8v af[8];
#pragma unroll
  for (int rt2 = 0; rt2 < 2; ++rt2)
#pragma unroll
    for (int ks = 0; ks < 4; ++ks)
      af[rt2 * 4 + ks] = *reinterpret_cast<const short8v*>(
          &xs[(rt2 * 16 + col) * 136 + (ks << 5) + (quad << 3)]);

  f32x4 acc[8];
#pragma unroll
  for (int i = 0; i < 8; ++i) acc[i] = (f32x4){0.f, 0.f, 0.f, 0.f};

#pragma unroll
  for (int rt2 = 0; rt2 < 2; ++rt2)
#pragma unroll
    for (int ct = 0; ct < 4; ++ct)
#pragma unroll
      for (int ks = 0; ks < 4; ++ks)
        acc[rt2 * 4 + ct] = __builtin_amdgcn_mfma_f32_16x16x32_bf16(
            af[rt2 * 4 + ks], bf[ct * 4 + ks], acc[rt2 * 4 + ct], 0, 0, 0);

#pragma unroll
  for (int rt2 = 0; rt2 < 2; ++rt2)
#pragma unroll
    for (int ct = 0; ct < 4; ++ct)
#pragma unroll
      for (int r = 0; r < 4; ++r) {
        const int row = rt + rt2 * 16 + (quad << 2) + r;
        if (row < NNODES)
          Hb[(size_t)row * C1 + n0 + (ct << 4) + col] = f2bf(acc[rt2 * 4 + ct][r]);
      }

  float alv[4], arv[4];
#pragma unroll
  for (int ct = 0; ct < 4; ++ct) {
    alv[ct] = ldv(alr, n0 + ct * 16 + col, isf);
    arv[ct] = ldv(arr, n0 + ct * 16 + col, isf);
  }
#pragma unroll
  for (int rt2 = 0; rt2 < 2; ++rt2)
#pragma unroll
    for (int r = 0; r < 4; ++r) {
      float pl0 = acc[rt2 * 4 + 0][r] * alv[0] + acc[rt2 * 4 + 1][r] * alv[1];
      float pl1 = acc[rt2 * 4 + 2][r] * alv[2] + acc[rt2 * 4 + 3][r] * alv[3];
      float pr0 = acc[rt2 * 4 + 0][r] * arv[0] + acc[rt2 * 4 + 1][r] * arv[1];
      float pr1 = acc[rt2 * 4 + 2][r] * arv[2] + acc[rt2 * 4 + 3][r] * arv[3];
#pragma unroll
      for (int k = 1; k <= 8; k <<= 1) {
        pl0 += __shfl_xor(pl0, k, 64);
        pl1 += __shfl_xor(pl1, k, 64);
        pr0 += __shfl_xor(pr0, k, 64);
        pr1 += __shfl_xor(pr1, k, 64);
      }
      if (col == 0) {
        const int row = rt + rt2 * 16 + (quad << 2) + r;
        if (row < NNODES) {
          el[row * HEADS + 2 * wv]     = pl0;
          el[row * HEADS + 2 * wv + 1] = pl1;
          er[row * HEADS + 2 * wv]     = pr0;
          er[row * HEADS + 2 * wv + 1] = pr1;
        }
      }
    }
}

// -------- Agg layer 1: FULL wave/node, 4 cols/lane (uint2), unroll 8 -------
__global__ __launch_bounds__(256) void k_agg1(const int* __restrict__ rowptr,
                                              const int* __restrict__ deg,
                                              const int* __restrict__ colsrc,
                                              const float* __restrict__ el,
                                              const float* __restrict__ er,
                                              const ushort* __restrict__ h1b,
                                              const void* __restrict__ b1r,
                                              const int* __restrict__ flag,
                                              ushort* __restrict__ out1b) {
  const int n = blockIdx.x * 4 + (threadIdx.x >> 6);
  if (n >= NNODES) return;
  const int t  = threadIdx.x & 63;
  const int c0 = t << 2;             // 4 cols per lane
  const int h  = t >> 3;
  const int isf = flag[0];
  const int start = rowptr[n];
  const int cnt   = deg[n];
  const char* hp  = (const char*)h1b;
  const char* elp = (const char*)el;
  const float ern = er[n * HEADS + h];
  const int* cp = colsrc + start;
  const uint cb = (uint)c0 << 1;
  const uint hb = (uint)h << 2;
  float a0 = 0.f, a1 = 0.f, a2 = 0.f, a3 = 0.f, den = 0.f;
  int i = 0;
  for (; i + 8 <= cnt; i += 8) {
    int s[8];
#pragma unroll
    for (int j = 0; j < 8; ++j) s[j] = cp[i + j];
    float l[8];
#pragma unroll
    for (int j = 0; j < 8; ++j)
      l[j] = *reinterpret_cast<const float*>(elp + (((uint)s[j] << 5) | hb));
    uint2 u[8];
#pragma unroll
    for (int j = 0; j < 8; ++j)
      u[j] = *reinterpret_cast<const uint2*>(hp + (((uint)s[j] << 9) | cb));
#pragma unroll
    for (int j = 0; j < 8; ++j) {
      const float e = __expf(lrelu(l[j] + ern));
      den += e;
      a0 += e * __uint_as_float(u[j].x << 16);
      a1 += e * __uint_as_float(u[j].x & 0xffff0000u);
      a2 += e * __uint_as_float(u[j].y << 16);
      a3 += e * __uint_as_float(u[j].y & 0xffff0000u);
    }
  }
  for (; i < cnt; ++i) {
    const int s = cp[i];
    const float l = *reinterpret_cast<const float*>(elp + (((uint)s << 5) | hb));
    const uint2 u = *reinterpret_cast<const uint2*>(hp + (((uint)s << 9) | cb));
    const float e = __expf(lrelu(l + ern));
    den += e;
    a0 += e * __uint_as_float(u.x << 16);
    a1 += e * __uint_as_float(u.x & 0xffff0000u);
    a2 += e * __uint_as_float(u.y << 16);
    a3 += e * __uint_as_float(u.y & 0xffff0000u);
  }
  const float inv = 1.f / fmaxf(den, 1e-9f);
  float o0 = a0 * inv + ldv(b1r, c0 + 0, isf);
  float o1 = a1 * inv + ldv(b1r, c0 + 1, isf);
  float o2 = a2 * inv + ldv(b1r, c0 + 2, isf);
  float o3 = a3 * inv + ldv(b1r, c0 + 3, isf);
  o0 = (o0 > 0.f) ? o0 : expm1f(o0);
  o1 = (o1 > 0.f) ? o1 : expm1f(o1);
  o2 = (o2 > 0.f) ? o2 : expm1f(o2);
  o3 = (o3 > 0.f) ? o3 : expm1f(o3);
  uint2 w;
  w.x = packbf2(o0, o1);
  w.y = packbf2(o2, o3);
  *reinterpret_cast<uint2*>((char*)out1b + ((uint)n << 9) + cb) = w;
}

// -------- MFMA GEMM2 + fused elr2: h2[N,40](bf16), el2/er2[N] --------------
__global__ __launch_bounds__(256) void k_gemm2m(const ushort* __restrict__ Ab,
                                                const ushort* __restrict__ w2tb,
                                                const void* __restrict__ alr,
                                                const void* __restrict__ arr,
                                                const int* __restrict__ flag,
                                                ushort* __restrict__ Hb,
                                                float* __restrict__ el,
                                                float* __restrict__ er) {
  __shared__ __align__(16) ushort as2[64 * 264];
  const int tid = threadIdx.x;
  const int rt  = blockIdx.x * 64;
  const int isf = flag[0];

  {
    const int r  = tid >> 2;
    const int cb = (tid & 3) << 6;
    const int grow = rt + r;
#pragma unroll
    for (int j = 0; j < 8; ++j) {
      uint4 u = make_uint4(0u, 0u, 0u, 0u);
      if (grow < NNODES)
        u = *reinterpret_cast<const uint4*>(Ab + (size_t)grow * C1 + cb + (j << 3));
      *reinterpret_cast<uint4*>(&as2[r * 264 + cb + (j << 3)]) = u;
    }
  }
  __syncthreads();

  const int lane = tid & 63;
  const int wv   = tid >> 6;
  const int col  = lane & 15;
  const int quad = lane >> 4;

  f32x4 acc[3];
#pragma unroll
  for (int i = 0; i < 3; ++i) acc[i] = (f32x4){0.f, 0.f, 0.f, 0.f};

#pragma unroll
  for (int ks = 0; ks < 8; ++ks) {
    const int k0 = (ks << 5) + (quad << 3);
    const short8v a = *reinterpret_cast<const short8v*>(&as2[(wv * 16 + col) * 264 + k0]);
    const short8v b0 = *reinterpret_cast<const short8v*>(&w2tb[(size_t)( 0 + col) * C1 + k0]);
    const short8v b1 = *reinterpret_cast<const short8v*>(&w2tb[(size_t)(16 + col) * C1 + k0]);
    const short8v b2 = *reinterpret_cast<const short8v*>(&w2tb[(size_t)(32 + col) * C1 + k0]);
    acc[0] = __builtin_amdgcn_mfma_f32_16x16x32_bf16(a, b0, acc[0], 0, 0, 0);
    acc[1] = __builtin_amdgcn_mfma_f32_16x16x32_bf16(a, b1, acc[1], 0, 0, 0);
    acc[2] = __builtin_amdgcn_mfma_f32_16x16x32_bf16(a, b2, acc[2], 0, 0, 0);
  }

  float alv[3], arv[3];
#pragma unroll
  for (int ct = 0; ct < 3; ++ct) {
    const int gc = ct * 16 + col;
    alv[ct] = (gc < NCLS) ? ldv(alr, gc, isf) : 0.f;
    arv[ct] = (gc < NCLS) ? ldv(arr, gc, isf) : 0.f;
  }
#pragma unroll
  for (int r = 0; r < 4; ++r) {
    const int row = rt + wv * 16 + (quad << 2) + r;
    const bool rok = row < NNODES;
#pragma unroll
    for (int ct = 0; ct < 3; ++ct) {
      const int gc = ct * 16 + col;
      if (rok && gc < NCLS)
        Hb[(size_t)row * NCLS + gc] = f2bf(acc[ct][r]);
    }
    float pl = acc[0][r] * alv[0] + acc[1][r] * alv[1] + acc[2][r] * alv[2];
    float pr = acc[0][r] * arv[0] + acc[1][r] * arv[1] + acc[2][r] * arv[2];
#pragma unroll
    for (int k = 1; k <= 8; k <<= 1) {
      pl += __shfl_xor(pl, k, 64);
      pr += __shfl_xor(pr, k, 64);
    }
    if (col == 0 && rok) {
      el[row] = pl;
      er[row] = pr;
    }
  }
}

// -------- Agg layer 2: HALF-WAVE per node, 2 cols/lane, unroll 8 -----------
__global__ __launch_bounds__(256) void k_agg2(const int* __restrict__ rowptr,
                                              const int* __restrict__ deg,
                                              const int* __restrict__ colsrc,
                                              const float* __restrict__ el,
                                              const float* __restrict__ er,
                                              const ushort* __restrict__ h2b,
                                              const void* __restrict__ b2r,
                                              const int* __restrict__ flag,
                                              float* __restrict__ out) {
  const int n = blockIdx.x * 8 + (threadIdx.x >> 5);
  if (n >= NNODES) return;
  const int t  = threadIdx.x & 31;
  const int c0 = t << 1;             // 2 cols per lane
  const bool act = c0 < NCLS;
  const int isf  = flag[0];
  const int start = rowptr[n];
  const int cnt   = deg[n];
  const float ern = er[n];
  const char* hp = (const char*)h2b;
  const uint cb = (uint)c0 << 1;
  const int* cp = colsrc + start;
  float a0 = 0.f, a1 = 0.f, den = 0.f;
  int i = 0;
  for (; i + 8 <= cnt; i += 8) {
    int s[8];
#pragma unroll
    for (int j = 0; j < 8; ++j) s[j] = cp[i + j];
    float l[8];
#pragma unroll
    for (int j = 0; j < 8; ++j) l[j] = el[s[j]];
    uint u[8];
#pragma unroll
    for (int j = 0; j < 8; ++j)
      u[j] = act ? *reinterpret_cast<const uint*>(hp + (uint)s[j] * 80u + cb) : 0u;
#pragma unroll
    for (int j = 0; j < 8; ++j) {
      const float e = __expf(lrelu(l[j] + ern));
      den += e;
      a0 += e * __uint_as_float(u[j] << 16);
      a1 += e * __uint_as_float(u[j] & 0xffff0000u);
    }
  }
  for (; i < cnt; ++i) {
    const int s = cp[i];
    const float e = __expf(lrelu(el[s] + ern));
    den += e;
    const uint u = act ? *reinterpret_cast<const uint*>(hp + (uint)s * 80u + cb) : 0u;
    a0 += e * __uint_as_float(u << 16);
    a1 += e * __uint_as_float(u & 0xffff0000u);
  }
  if (act) {
    const float inv = 1.f / fmaxf(den, 1e-9f);
    float2 o;
    o.x = a0 * inv + ldv(b2r, c0 + 0, isf);
    o.y = a1 * inv + ldv(b2r, c0 + 1, isf);
    *reinterpret_cast<float2*>(out + (size_t)n * NCLS + c0) = o;
  }
}

extern "C" void kernel_launch(void* const* d_in, const int* in_sizes, int n_in,
                              void* d_out, int out_size, void* d_ws, size_t ws_size,
                              hipStream_t stream) {
  // ---- size-driven input mapping ----
  int ix = -1, iW1 = -1, iW2 = -1, e1 = -1, e2 = -1;
  int i256[3] = {-1, -1, -1}, n256 = 0;
  int i40[3]  = {-1, -1, -1}, n40 = 0;
  for (int i = 0; i < n_in; ++i) {
    switch (in_sizes[i]) {
      case 6400000: ix = i; break;
      case 800000:  if (e1 < 0) e1 = i; else e2 = i; break;
      case 32768:   iW1 = i; break;
      case 10240:   iW2 = i; break;
      case 256:     if (n256 < 3) i256[n256++] = i; break;
      case 40:      if (n40 < 3)  i40[n40++]  = i; break;
      default: break;
    }
  }
  bool mapped = (ix >= 0 && iW1 >= 0 && iW2 >= 0 && e2 >= 0 && n256 == 3 && n40 == 3);
  int isrc, idst;
  if (mapped) {
    const bool dict_order = (in_sizes[0] == 6400000);
    isrc = dict_order ? e1 : e2;
    idst = dict_order ? e2 : e1;
  } else {
    ix = 0; isrc = 1; idst = 2; iW1 = 3;
    i256[0] = 4; i256[1] = 5; i256[2] = 6;
    iW2 = 7; i40[0] = 8; i40[1] = 9; i40[2] = 10;
  }
  const void* X   = d_in[ix];
  const int*  src = (const int*)d_in[isrc];
  const int*  dst = (const int*)d_in[idst];
  const void* W1  = d_in[iW1];
  const void* al1 = d_in[i256[0]];
  const void* ar1 = d_in[i256[1]];
  const void* b1  = d_in[i256[2]];
  const void* W2  = d_in[iW2];
  const void* al2 = d_in[i40[0]];
  const void* ar2 = d_in[i40[1]];
  const void* b2  = d_in[i40[2]];

  char* ws = (char*)d_ws;
  size_t off = 0;
  auto alloc = [&](size_t bytes) -> void* {
    void* p = ws + off;
    off = (off + bytes + 255) & ~(size_t)255;
    return p;
  };
  int*    flag   = (int*)alloc(256);
  int*    aggf   = (int*)alloc(64 * 4);
  int*    deg    = (int*)alloc((size_t)NNODES * 4);
  int*    rowptr = (int*)alloc((size_t)NNODES * 4);
  int*    erank  = (int*)alloc((size_t)NEDGES * 4);
  int*    colsrc = (int*)alloc((size_t)NEDGES * 4);
  float*  el1    = (float*)alloc((size_t)NNODES * HEADS * 4);
  float*  er1    = (float*)alloc((size_t)NNODES * HEADS * 4);
  float*  el2    = (float*)alloc((size_t)NNODES * 4);
  float*  er2    = (float*)alloc((size_t)NNODES * 4);
  ushort* w1tb   = (ushort*)alloc((size_t)C1 * INF * 2);
  ushort* w2tb   = (ushort*)alloc((size_t)NCP * C1 * 2);
  ushort* h1b    = (ushort*)alloc((size_t)NNODES * C1 * 2);    // 25.6 MB
  ushort* out1b  = (ushort*)alloc((size_t)NNODES * C1 * 2);    // 25.6 MB
  ushort* h2b    = (ushort*)alloc((size_t)NNODES * NCLS * 2);  // 4 MB

  k_init<<<(NNODES + 255) / 256, 256, 0, stream>>>((const ushort*)X, flag, deg, aggf);
  k_histprep<<<EB + INF + NCP, 256, 0, stream>>>(dst, deg, erank, W1, W2, flag,
                                                 w1tb, w2tb);
  k_scan<<<NSB, 1024, 0, stream>>>(deg, rowptr, aggf);
  k_scatgemm1<<<EB + G1B, 256, 0, stream>>>(src, dst, rowptr, erank, colsrc,
                                            X, w1tb, al1, ar1, flag,
                                            h1b, el1, er1);

  k_agg1<<<(NNODES + 3) / 4, 256, 0, stream>>>(rowptr, deg, colsrc, el1, er1,
                                               h1b, b1, flag, out1b);

  k_gemm2m<<<(NNODES + 63) / 64, 256, 0, stream>>>(out1b, w2tb, al2, ar2, flag,
                                                   h2b, el2, er2);
  k_agg2<<<(NNODES + 7) / 8, 256, 0, stream>>>(rowptr, deg, colsrc, el2, er2,
                                               h2b, b2, flag, (float*)d_out);
}